// Round 1
// baseline (2664.328 us; speedup 1.0000x reference)
//
#include <hip/hip_runtime.h>

#define EPSBN 1e-5f

// ---------------- adjacency: A = adp(nv1,nv2), plus column sums sA ----------------
__global__ void k_adj(const float* __restrict__ nv1, const float* __restrict__ nv2,
                      float* __restrict__ A, float* __restrict__ sA) {
  __shared__ float M[16][16];
  int tid = threadIdx.x;           // 256 threads
  int i = tid >> 4, j = tid & 15;
  float acc = 0.f;
  #pragma unroll
  for (int k = 0; k < 64; ++k) acc += nv1[i*64+k] * nv2[k*16+j];
  M[i][j] = fmaxf(acc, 0.f);
  __syncthreads();
  if (tid < 16) {
    float m = -1e30f;
    for (int c = 0; c < 16; ++c) m = fmaxf(m, M[tid][c]);
    float e[16]; float s = 0.f;
    for (int c = 0; c < 16; ++c) { e[c] = expf(M[tid][c] - m); s += e[c]; }
    float inv = 1.f / s;
    float t1 = -1e30f, t2 = -1e30f;
    for (int c = 0; c < 16; ++c) {
      float a = e[c] * inv; e[c] = a;
      if (a > t1) { t2 = t1; t1 = a; }
      else if (a > t2) t2 = a;
    }
    for (int c = 0; c < 16; ++c) {
      bool keep = (e[c] > (1.0f/16.0f)) && (e[c] > t2);   // strict, matches ref
      M[tid][c] = keep ? e[c] : 0.f;
    }
  }
  __syncthreads();
  A[tid] = M[tid>>4][tid&15];
  if (tid < 16) {
    float s = 0.f;
    for (int v = 0; v < 16; ++v) s += M[v][tid];
    sA[tid] = s;
  }
}

// ---------------- graph aggregation: out[...,t,w] = sum_v in[...,t,v] * A[v,w] ----------------
__global__ __launch_bounds__(256) void k_agg(const float* __restrict__ in,
                                             const float* __restrict__ Am,
                                             float* __restrict__ out) {
  __shared__ float sA[256];
  __shared__ float ti[16*258];
  __shared__ float to[16*258];
  int tid = threadIdx.x;
  sA[tid] = Am[tid];
  long base = (long)blockIdx.x * 4096;
  #pragma unroll
  for (int k = 0; k < 16; ++k) {
    int idx = k*256 + tid;
    ti[(idx & 15)*258 + (idx >> 4)] = in[base + idx];
  }
  __syncthreads();
  float o[16];
  #pragma unroll
  for (int w = 0; w < 16; ++w) o[w] = 0.f;
  #pragma unroll
  for (int v = 0; v < 16; ++v) {
    float xv = ti[v*258 + tid];
    #pragma unroll
    for (int w = 0; w < 16; ++w) o[w] += xv * sA[v*16 + w];
  }
  #pragma unroll
  for (int w = 0; w < 16; ++w) to[w*258 + tid] = o[w];
  __syncthreads();
  #pragma unroll
  for (int k = 0; k < 16; ++k) {
    int idx = k*256 + tid;
    out[base + idx] = to[(idx & 15)*258 + (idx >> 4)];
  }
}

// ---------------- channel-mixing 1x1 conv over 128 channels ----------------
// layout (G, 128, L): in/out[(g*128+c)*L + pos]. Block: one g, 64 positions, all channels.
// IN_BN: apply scale/shift to input (index c, or (g%16)*128+c if GROUPED_BN).
// BIAS: add gb[o]*sA[pos&15] (dynamic gconv absorbed through graph aggregation).
template<int IN_BN, int GROUPED_BN, int BIAS>
__global__ __launch_bounds__(256) void k_cconv(
    const float* __restrict__ in, const float* __restrict__ W,
    float* __restrict__ out, int L,
    const float* __restrict__ isc, const float* __restrict__ ish,
    const float* __restrict__ gb, const float* __restrict__ sAv)
{
  __shared__ float ti[128*64];
  int tid = threadIdx.x;
  int bpg = L >> 6;
  int g = blockIdx.x / bpg;
  int pos0 = (blockIdx.x % bpg) << 6;
  const float* ing = in + (long)g*128*L + pos0;
  for (int idx = tid; idx < 8192; idx += 256) {
    int c = idx >> 6, p = idx & 63;
    float v = ing[(long)c*L + p];
    if (IN_BN) {
      int ci = GROUPED_BN ? ((g & 15)*128 + c) : c;
      v = v * isc[ci] + ish[ci];
    }
    ti[idx] = v;
  }
  __syncthreads();
  int obase = (tid >> 4) * 8;
  int pbase = (tid & 15) * 4;
  float acc[8][4];
  #pragma unroll
  for (int i = 0; i < 8; ++i)
    #pragma unroll
    for (int q = 0; q < 4; ++q) acc[i][q] = 0.f;
  #pragma unroll 2
  for (int c = 0; c < 128; ++c) {
    float4 xv = *(const float4*)&ti[c*64 + pbase];
    float w[8];
    #pragma unroll
    for (int i = 0; i < 8; ++i) w[i] = W[(obase+i)*128 + c];
    #pragma unroll
    for (int i = 0; i < 8; ++i) {
      acc[i][0] += w[i]*xv.x;
      acc[i][1] += w[i]*xv.y;
      acc[i][2] += w[i]*xv.z;
      acc[i][3] += w[i]*xv.w;
    }
  }
  float* og = out + (long)g*128*L + pos0;
  #pragma unroll
  for (int i = 0; i < 8; ++i) {
    int o = obase + i;
    float b0 = 0.f, b1 = 0.f, b2 = 0.f, b3 = 0.f;
    if (BIAS) {
      float gbo = gb[o];
      b0 = gbo * sAv[(pbase+0) & 15];
      b1 = gbo * sAv[(pbase+1) & 15];
      b2 = gbo * sAv[(pbase+2) & 15];
      b3 = gbo * sAv[(pbase+3) & 15];
    }
    float4 r;
    r.x = acc[i][0]+b0; r.y = acc[i][1]+b1; r.z = acc[i][2]+b2; r.w = acc[i][3]+b3;
    *(float4*)(og + (long)o*L + pbase) = r;
  }
}

// ---------------- temporal conv, kernel 3, taps at pos +/- HALO, zero-pad in [0,L) ----------------
// Input gets BN scale/shift (per channel c) and optional relu. GROUPED: weights per p=g%16.
template<int HALO, int GROUPED>
__global__ __launch_bounds__(256) void k_tconv(
    const float* __restrict__ in, const float* __restrict__ W,
    float* __restrict__ out, int L, int relu_in,
    const float* __restrict__ isc, const float* __restrict__ ish)
{
  constexpr int TWd = 64 + 2*HALO;
  __shared__ float ti[128*TWd];
  int tid = threadIdx.x;
  int bpg = L >> 6;
  int g = blockIdx.x / bpg;
  int pos0 = (blockIdx.x % bpg) << 6;
  const float* ing = in + (long)g*128*L;
  for (int idx = tid; idx < 128*TWd; idx += 256) {
    int c = idx / TWd, j = idx - c*TWd;
    int gp = pos0 + j - HALO;
    float v = 0.f;
    if (gp >= 0 && gp < L) {
      v = ing[(long)c*L + gp] * isc[c] + ish[c];
      if (relu_in) v = fmaxf(v, 0.f);
    }
    ti[c*TWd + j] = v;
  }
  __syncthreads();
  int obase = (tid >> 4) * 8;
  int pbase = (tid & 15) * 4;
  float acc[8][4];
  #pragma unroll
  for (int i = 0; i < 8; ++i)
    #pragma unroll
    for (int q = 0; q < 4; ++q) acc[i][q] = 0.f;
  const float* Wb = GROUPED ? (W + (long)(g & 15)*128*128*3) : W;
  #pragma unroll
  for (int k = 0; k < 3; ++k) {
    int jb = pbase + k*HALO;
    for (int c = 0; c < 128; ++c) {
      float x0 = ti[c*TWd + jb + 0];
      float x1 = ti[c*TWd + jb + 1];
      float x2 = ti[c*TWd + jb + 2];
      float x3 = ti[c*TWd + jb + 3];
      float w[8];
      #pragma unroll
      for (int i = 0; i < 8; ++i) w[i] = Wb[((obase+i)*128 + c)*3 + k];
      #pragma unroll
      for (int i = 0; i < 8; ++i) {
        acc[i][0] += w[i]*x0;
        acc[i][1] += w[i]*x1;
        acc[i][2] += w[i]*x2;
        acc[i][3] += w[i]*x3;
      }
    }
  }
  float* og = out + (long)g*128*L + pos0;
  #pragma unroll
  for (int i = 0; i < 8; ++i) {
    float4 r;
    r.x = acc[i][0]; r.y = acc[i][1]; r.z = acc[i][2]; r.w = acc[i][3];
    *(float4*)(og + (long)(obase+i)*L + pbase) = r;
  }
}

// ---------------- train-mode BN stats -> fused scale/shift, one block per channel ----------------
// layout (G, Cn, L) with L = 1<<Lsh; channel ch elements at ((g*Cn+ch)<<Lsh)+pos
__global__ __launch_bounds__(256) void k_bnstats(
    const float* __restrict__ in, int G, int Cn, int Lsh,
    const float* __restrict__ gamma, const float* __restrict__ beta,
    float* __restrict__ scale, float* __restrict__ shift)
{
  int ch = blockIdx.x;
  int tid = threadIdx.x;
  int L = 1 << Lsh;
  int total = G << Lsh;
  float s1 = 0.f, s2 = 0.f;
  for (int idx = tid; idx < total; idx += 256) {
    int gg = idx >> Lsh, pos = idx & (L-1);
    float v = in[(long)(gg*Cn + ch)*L + pos];
    s1 += v; s2 += v*v;
  }
  __shared__ float r1[256], r2[256];
  r1[tid] = s1; r2[tid] = s2;
  __syncthreads();
  for (int st = 128; st > 0; st >>= 1) {
    if (tid < st) { r1[tid] += r1[tid+st]; r2[tid] += r2[tid+st]; }
    __syncthreads();
  }
  if (tid == 0) {
    float invN = 1.f / (float)total;
    float mean = r1[0]*invN;
    float var  = r2[0]*invN - mean*mean;
    float sc = gamma[ch] * rsqrtf(var + EPSBN);
    scale[ch] = sc;
    shift[ch] = beta[ch] - mean*sc;
  }
}

// ---------------- r = relu(bn(z) + res), dynamic layout (n,c,4096) ----------------
__global__ __launch_bounds__(256) void k_combine(
    const float* __restrict__ z, const float* __restrict__ res,
    const float* __restrict__ sc, const float* __restrict__ sh,
    float* __restrict__ out)
{
  long i4 = ((long)blockIdx.x*256 + threadIdx.x)*4;
  int c = (int)((i4 >> 12) & 127);
  float4 zv = *(const float4*)(z + i4);
  float4 rv = *(const float4*)(res + i4);
  float s = sc[c], b = sh[c];
  float4 r;
  r.x = fmaxf(zv.x*s + b + rv.x, 0.f);
  r.y = fmaxf(zv.y*s + b + rv.y, 0.f);
  r.z = fmaxf(zv.z*s + b + rv.z, 0.f);
  r.w = fmaxf(zv.w*s + b + rv.w, 0.f);
  *(float4*)(out + i4) = r;
}

// ---------------- dynamic tail: out[n,o,v] = max_t relu(bn(z)+res) ----------------
__global__ __launch_bounds__(256) void k_maxdyn(
    const float* __restrict__ z, const float* __restrict__ res,
    const float* __restrict__ sc, const float* __restrict__ sh,
    float* __restrict__ out)
{
  int no = blockIdx.x;        // n*128+o
  int o = no & 127;
  int t = threadIdx.x;        // 256 = T
  const float* zr = z   + (long)no*4096 + t*16;
  const float* rr = res + (long)no*4096 + t*16;
  float s = sc[o], b = sh[o];
  __shared__ float red[256*17];
  #pragma unroll
  for (int q = 0; q < 4; ++q) {
    float4 zv = *(const float4*)(zr + q*4);
    float4 rv = *(const float4*)(rr + q*4);
    red[t*17 + q*4+0] = fmaxf(zv.x*s + b + rv.x, 0.f);
    red[t*17 + q*4+1] = fmaxf(zv.y*s + b + rv.y, 0.f);
    red[t*17 + q*4+2] = fmaxf(zv.z*s + b + rv.z, 0.f);
    red[t*17 + q*4+3] = fmaxf(zv.w*s + b + rv.w, 0.f);
  }
  __syncthreads();
  for (int st = 128; st > 0; st >>= 1) {
    if (t < st) {
      #pragma unroll
      for (int j = 0; j < 16; ++j)
        red[t*17+j] = fmaxf(red[t*17+j], red[(t+st)*17+j]);
    }
    __syncthreads();
  }
  if (t < 16) out[(long)(no >> 7)*4096 + o*32 + t] = red[t];
}

// ---------------- static tail: out[n,o,16+p] = max_s bn(z2[n,p,o,s]) ----------------
__global__ void k_maxstat(const float* __restrict__ z,
                          const float* __restrict__ sc, const float* __restrict__ sh,
                          float* __restrict__ out)
{
  int b = blockIdx.x;              // ((n*16+p)*128+o)
  int o = b & 127, p = (b >> 7) & 15, n = b >> 11;
  int lane = threadIdx.x;          // 64
  const float* row = z + (long)b*256;
  float s = sc[p*128+o], bb = sh[p*128+o];
  float4 v = ((const float4*)row)[lane];
  float m = fmaxf(fmaxf(v.x*s+bb, v.y*s+bb), fmaxf(v.z*s+bb, v.w*s+bb));
  for (int off = 32; off > 0; off >>= 1) m = fmaxf(m, __shfl_down(m, off));
  if (lane == 0) out[(long)n*4096 + o*32 + 16 + p] = m;
}

// ---------------- transpose x (n,c,t,v) -> xT (n,v,c,t) ----------------
__global__ __launch_bounds__(256) void k_txpose(const float* __restrict__ x,
                                                float* __restrict__ xT)
{
  __shared__ float tile[64*17];
  int b = blockIdx.x;               // (n, c, tchunk)
  int tc = b & 3, c = (b >> 2) & 127, n = b >> 9;
  int t0 = tc*64;
  int tid = threadIdx.x;
  long inbase = ((long)(n*128+c)*256 + t0)*16;
  for (int idx = tid; idx < 1024; idx += 256) {
    int t = idx >> 4, v = idx & 15;
    tile[t*17+v] = x[inbase + idx];
  }
  __syncthreads();
  for (int idx = tid; idx < 1024; idx += 256) {
    int v = idx >> 6, t = idx & 63;
    xT[((long)(n*16+v)*128 + c)*256 + t0 + t] = tile[t*17+v];
  }
}

extern "C" void kernel_launch(void* const* d_in, const int* in_sizes, int n_in,
                              void* d_out, int out_size, void* d_ws, size_t ws_size,
                              hipStream_t stream) {
  (void)in_sizes; (void)n_in; (void)out_size; (void)ws_size;
  const float* x     = (const float*)d_in[0];
  const float* nv1   = (const float*)d_in[1];
  const float* nv2   = (const float*)d_in[2];
  const float* d1gw  = (const float*)d_in[3];
  const float* d1gb  = (const float*)d_in[4];
  const float* d1b1g = (const float*)d_in[5];
  const float* d1b1b = (const float*)d_in[6];
  const float* d1tw  = (const float*)d_in[7];
  // d_in[8] = d1tb: conv bias, constant per-channel over BN axes -> cancels in BN2
  const float* d1b2g = (const float*)d_in[9];
  const float* d1b2b = (const float*)d_in[10];
  const float* d2gw  = (const float*)d_in[11];
  const float* d2gb  = (const float*)d_in[12];
  const float* d2b1g = (const float*)d_in[13];
  const float* d2b1b = (const float*)d_in[14];
  const float* d2tw  = (const float*)d_in[15];
  // d_in[16] = d2tb: cancels
  const float* d2b2g = (const float*)d_in[17];
  const float* d2b2b = (const float*)d_in[18];
  const float* s1pw  = (const float*)d_in[19];
  const float* s1pg  = (const float*)d_in[20];
  const float* s1pb  = (const float*)d_in[21];
  const float* s1tw  = (const float*)d_in[22];
  const float* s1tg  = (const float*)d_in[23];
  const float* s1tb  = (const float*)d_in[24];
  const float* s2pw  = (const float*)d_in[25];
  const float* s2pg  = (const float*)d_in[26];
  const float* s2pb  = (const float*)d_in[27];
  const float* s2tw  = (const float*)d_in[28];
  const float* s2tg  = (const float*)d_in[29];
  const float* s2tb  = (const float*)d_in[30];

  float* ws   = (float*)d_ws;
  float* Am   = ws;            // 256
  float* sAv  = ws + 256;      // 16
  float* bnA_s = ws + 512;   float* bnA_h = ws + 640;
  float* bnB_s = ws + 768;   float* bnB_h = ws + 896;
  float* bnC_s = ws + 1024;  float* bnC_h = ws + 1152;
  float* bnD_s = ws + 1280;  float* bnD_h = ws + 1408;
  float* bnE_s = ws + 1536;  float* bnE_h = ws + 1664;
  float* bnG_s = ws + 1792;  float* bnG_h = ws + 1920;
  float* bnF_s = ws + 2048;  float* bnF_h = ws + 4096;   // 2048 each
  float* bnH_s = ws + 6144;  float* bnH_h = ws + 8192;   // 2048 each
  float* b0 = ws + 16384;             // 64 MB buffers
  float* b1 = b0 + 16777216;
  float* b2 = b1 + 16777216;
  float* outp = (float*)d_out;

  // ---- dynamic branch ----
  k_adj<<<1, 256, 0, stream>>>(nv1, nv2, Am, sAv);
  k_agg<<<4096, 256, 0, stream>>>(x, Am, b0);
  k_cconv<0,0,1><<<2048, 256, 0, stream>>>(b0, d1gw, b1, 4096, nullptr, nullptr, d1gb, sAv);
  k_bnstats<<<128, 256, 0, stream>>>(b1, 32, 128, 12, d1b1g, d1b1b, bnA_s, bnA_h);
  k_tconv<16,0><<<2048, 256, 0, stream>>>(b1, d1tw, b2, 4096, 1, bnA_s, bnA_h);
  k_bnstats<<<128, 256, 0, stream>>>(b2, 32, 128, 12, d1b2g, d1b2b, bnB_s, bnB_h);
  k_combine<<<16384, 256, 0, stream>>>(b2, x, bnB_s, bnB_h, b0);       // b0 = r2
  k_agg<<<4096, 256, 0, stream>>>(b0, Am, b1);
  k_cconv<0,0,1><<<2048, 256, 0, stream>>>(b1, d2gw, b2, 4096, nullptr, nullptr, d2gb, sAv);
  k_bnstats<<<128, 256, 0, stream>>>(b2, 32, 128, 12, d2b1g, d2b1b, bnC_s, bnC_h);
  k_tconv<16,0><<<2048, 256, 0, stream>>>(b2, d2tw, b1, 4096, 1, bnC_s, bnC_h);
  k_bnstats<<<128, 256, 0, stream>>>(b1, 32, 128, 12, d2b2g, d2b2b, bnD_s, bnD_h);
  k_maxdyn<<<4096, 256, 0, stream>>>(b1, b0, bnD_s, bnD_h, outp);

  // ---- static branch ----
  k_txpose<<<16384, 256, 0, stream>>>(x, b0);                           // b0 = xT (n,v,c,t)
  k_cconv<0,0,0><<<2048, 256, 0, stream>>>(b0, s1pw, b1, 256, nullptr, nullptr, nullptr, nullptr);
  k_bnstats<<<128, 256, 0, stream>>>(b1, 512, 128, 8, s1pg, s1pb, bnE_s, bnE_h);
  k_tconv<1,1><<<2048, 256, 0, stream>>>(b1, s1tw, b2, 256, 0, bnE_s, bnE_h);
  k_bnstats<<<2048, 256, 0, stream>>>(b2, 32, 2048, 8, s1tg, s1tb, bnF_s, bnF_h);
  k_cconv<1,1,0><<<2048, 256, 0, stream>>>(b2, s2pw, b0, 256, bnF_s, bnF_h, nullptr, nullptr);
  k_bnstats<<<128, 256, 0, stream>>>(b0, 512, 128, 8, s2pg, s2pb, bnG_s, bnG_h);
  k_tconv<1,1><<<2048, 256, 0, stream>>>(b0, s2tw, b1, 256, 0, bnG_s, bnG_h);
  k_bnstats<<<2048, 256, 0, stream>>>(b1, 32, 2048, 8, s2tg, s2tb, bnH_s, bnH_h);
  k_maxstat<<<65536, 64, 0, stream>>>(b1, bnH_s, bnH_h, outp);
}

// Round 5
// 912.638 us; speedup vs baseline: 2.9194x; 2.9194x over previous
//
#include <hip/hip_runtime.h>

#define EPSBN 1e-5f

typedef __attribute__((ext_vector_type(8))) __bf16 bf16x8;
typedef __attribute__((ext_vector_type(4))) float f32x4;

__device__ inline unsigned short f2bf(float f) {
  unsigned u = __float_as_uint(f);
  u = (u + 0x7fffu + ((u >> 16) & 1u)) >> 16;
  return (unsigned short)u;
}
__device__ inline float bf2f(unsigned short h) {
  return __uint_as_float(((unsigned)h) << 16);
}

// ---------------- adjacency: A = adp(nv1,nv2), plus column sums sA ----------------
__global__ void k_adj(const float* __restrict__ nv1, const float* __restrict__ nv2,
                      float* __restrict__ A, float* __restrict__ sA) {
  __shared__ float M[16][16];
  int tid = threadIdx.x;           // 256 threads
  int i = tid >> 4, j = tid & 15;
  float acc = 0.f;
  #pragma unroll
  for (int k = 0; k < 64; ++k) acc += nv1[i*64+k] * nv2[k*16+j];
  M[i][j] = fmaxf(acc, 0.f);
  __syncthreads();
  if (tid < 16) {
    float m = -1e30f;
    for (int c = 0; c < 16; ++c) m = fmaxf(m, M[tid][c]);
    float e[16]; float s = 0.f;
    for (int c = 0; c < 16; ++c) { e[c] = expf(M[tid][c] - m); s += e[c]; }
    float inv = 1.f / s;
    float t1 = -1e30f, t2 = -1e30f;
    for (int c = 0; c < 16; ++c) {
      float a = e[c] * inv; e[c] = a;
      if (a > t1) { t2 = t1; t1 = a; }
      else if (a > t2) t2 = a;
    }
    for (int c = 0; c < 16; ++c) {
      bool keep = (e[c] > (1.0f/16.0f)) && (e[c] > t2);
      M[tid][c] = keep ? e[c] : 0.f;
    }
  }
  __syncthreads();
  A[tid] = M[tid>>4][tid&15];
  if (tid < 16) {
    float s = 0.f;
    for (int v = 0; v < 16; ++v) s += M[v][tid];
    sA[tid] = s;
  }
}

// ---------------- weight converts to bf16 ----------------
__global__ __launch_bounds__(256) void k_cvt_cw(const float* __restrict__ w,
                                                unsigned short* __restrict__ o) {
  int idx = blockIdx.x*256 + threadIdx.x;
  if (idx < 16384) o[idx] = f2bf(w[idx]);
}
// temporal conv weights: in [oo][c][tap] -> out [oo][tap][c]; nOut = 128 or 2048
__global__ __launch_bounds__(256) void k_cvt_tw(const float* __restrict__ w,
                                                unsigned short* __restrict__ o, int nOut) {
  int idx = blockIdx.x*256 + threadIdx.x;
  if (idx >= nOut*384) return;
  int oo = idx / 384;
  int r = idx - oo*384;
  int tap = r >> 7, c = r & 127;
  o[idx] = f2bf(w[(oo*128 + c)*3 + tap]);
}

// ---------------- transpose x (n,c,t,v) -> pos-major ----------------
// WP: xP[n][t][v][c]   WS: xS[(n,v)][t][c]
template<int WP, int WS>
__global__ __launch_bounds__(256) void k_xpose(const float* __restrict__ x,
                                               float* __restrict__ xP,
                                               float* __restrict__ xS) {
  __shared__ float tl[128*65];
  int b = blockIdx.x; int n = b >> 6; int t0q = b & 63;   // 64 flat (t,v) per block
  int tid = threadIdx.x;
  const float* xb = x + (long)n*128*4096 + t0q*64;
  for (int idx = tid; idx < 2048; idx += 256) {
    int c = idx >> 4, q = idx & 15;
    float4 v = *(const float4*)(xb + (long)c*4096 + q*4);
    float* d = &tl[c*65 + q*4];
    d[0]=v.x; d[1]=v.y; d[2]=v.z; d[3]=v.w;
  }
  __syncthreads();
  for (int idx = tid; idx < 2048; idx += 256) {
    int pos = idx >> 5;
    int c0 = (idx & 31) << 2;
    float4 v;
    v.x = tl[(c0+0)*65 + pos]; v.y = tl[(c0+1)*65 + pos];
    v.z = tl[(c0+2)*65 + pos]; v.w = tl[(c0+3)*65 + pos];
    if (WP) *(float4*)(xP + ((long)n*4096 + t0q*64 + pos)*128 + c0) = v;
    if (WS) {
      int vv = pos & 15, tt = pos >> 4;
      *(float4*)(xS + ((long)(n*16+vv)*256 + t0q*4 + tt)*128 + c0) = v;
    }
  }
}

// ---------------- graph aggregation, pos-major ----------------
__global__ __launch_bounds__(256) void k_aggP(const float* __restrict__ in,
                                              const float* __restrict__ Am,
                                              float* __restrict__ out) {
  __shared__ float Asm[256];
  __shared__ float tl[4*16*128];
  int b = blockIdx.x; int n = b >> 6; int t0 = (b & 63) << 2;
  int tid = threadIdx.x;
  Asm[tid] = Am[tid];
  const float* ib = in + ((long)n*4096 + t0*16)*128;
  for (int idx = tid; idx < 2048; idx += 256)
    ((float4*)tl)[idx] = ((const float4*)ib)[idx];
  __syncthreads();
  float* ob = out + ((long)n*4096 + t0*16)*128;
  for (int idx = tid; idx < 2048; idx += 256) {
    int tt = idx >> 9, w = (idx >> 5) & 15, c4 = (idx & 31) << 2;
    float4 s = {0.f,0.f,0.f,0.f};
    #pragma unroll
    for (int v = 0; v < 16; ++v) {
      float a = Asm[v*16 + w];
      const float* r = &tl[(tt*16 + v)*128 + c4];
      s.x += a*r[0]; s.y += a*r[1]; s.z += a*r[2]; s.w += a*r[3];
    }
    ((float4*)ob)[idx] = s;
  }
}

// ---------------- MFMA conv with split-bf16 activations (hi+lo) ----------------
// NOTE: BN/ReLU are applied ONLY to in-range positions; zero-padding stays
// exactly zero (reference pads the already-BN'd tensor).
template<int HALO, int TAPS, int GROUPED_W, int IN_BN, int GROUPED_BN, int RELU_IN, int BIAS>
__global__ __launch_bounds__(256) void k_conv(
    const float* __restrict__ in, const unsigned short* __restrict__ Wb,
    float* __restrict__ out, int L,
    const float* __restrict__ isc, const float* __restrict__ ish,
    const float* __restrict__ gb, const float* __restrict__ sAv)
{
  constexpr int TW = 64 + 2*HALO;
  constexpr int KT = TAPS*128;
  __shared__ __align__(16) unsigned short Th[TW*128];
  __shared__ __align__(16) unsigned short Tlo[TW*128];
  int tid = threadIdx.x;
  int bpg = L >> 6;
  int g = blockIdx.x / bpg;
  int pos0 = (blockIdx.x - g*bpg) << 6;
  const float* ing = in + (long)g*L*128;

  int cbase = (IN_BN && GROUPED_BN) ? ((g & 15) << 7) : 0;
  for (int idx = tid; idx < TW*32; idx += 256) {
    int row = idx >> 5;
    int c4 = (idx & 31) << 2;
    int gp = pos0 + row - HALO;
    float4 v = {0.f,0.f,0.f,0.f};
    if (gp >= 0 && gp < L) {
      v = *(const float4*)(ing + (long)gp*128 + c4);
      if (IN_BN) {
        int ci = cbase + c4;
        v.x = v.x*isc[ci+0] + ish[ci+0];
        v.y = v.y*isc[ci+1] + ish[ci+1];
        v.z = v.z*isc[ci+2] + ish[ci+2];
        v.w = v.w*isc[ci+3] + ish[ci+3];
        if (RELU_IN) {
          v.x = fmaxf(v.x,0.f); v.y = fmaxf(v.y,0.f);
          v.z = fmaxf(v.z,0.f); v.w = fmaxf(v.w,0.f);
        }
      }
    }
    ushort4 h, l;
    h.x = f2bf(v.x); l.x = f2bf(v.x - bf2f(h.x));
    h.y = f2bf(v.y); l.y = f2bf(v.y - bf2f(h.y));
    h.z = f2bf(v.z); l.z = f2bf(v.z - bf2f(h.z));
    h.w = f2bf(v.w); l.w = f2bf(v.w - bf2f(h.w));
    int byteoff = (row << 8) + (c4 << 1);
    byteoff ^= ((row & 7) << 4);
    *(ushort4*)((char*)Th  + byteoff) = h;
    *(ushort4*)((char*)Tlo + byteoff) = l;
  }
  __syncthreads();

  int wv = tid >> 6;
  int lane = tid & 63;
  int l15 = lane & 15;
  int lhi = lane >> 4;
  int o0 = wv << 5;

  f32x4 zz = {0.f,0.f,0.f,0.f};
  f32x4 acc[2][4];
  #pragma unroll
  for (int i = 0; i < 2; ++i)
    #pragma unroll
    for (int q = 0; q < 4; ++q) acc[i][q] = zz;

  const unsigned short* Wg = Wb + (GROUPED_W ? (long)(g & 15)*128*KT : 0);
  const unsigned short* wr0 = Wg + (long)(o0 + l15)*KT + lhi*8;
  const unsigned short* wr1 = wr0 + 16*KT;

  #pragma unroll
  for (int tap = 0; tap < TAPS; ++tap) {
    #pragma unroll
    for (int kk = 0; kk < 4; ++kk) {
      int kc = kk*32 + lhi*8;
      bf16x8 a0 = *(const bf16x8*)(wr0 + tap*128 + kk*32);
      bf16x8 a1 = *(const bf16x8*)(wr1 + tap*128 + kk*32);
      #pragma unroll
      for (int pf = 0; pf < 4; ++pf) {
        int row = pf*16 + l15 + tap*HALO;
        int byteoff = (row << 8) + (kc << 1);
        byteoff ^= ((row & 7) << 4);
        bf16x8 bh = *(const bf16x8*)((const char*)Th  + byteoff);
        bf16x8 bl = *(const bf16x8*)((const char*)Tlo + byteoff);
        acc[0][pf] = __builtin_amdgcn_mfma_f32_16x16x32_bf16(a0, bh, acc[0][pf], 0, 0, 0);
        acc[0][pf] = __builtin_amdgcn_mfma_f32_16x16x32_bf16(a0, bl, acc[0][pf], 0, 0, 0);
        acc[1][pf] = __builtin_amdgcn_mfma_f32_16x16x32_bf16(a1, bh, acc[1][pf], 0, 0, 0);
        acc[1][pf] = __builtin_amdgcn_mfma_f32_16x16x32_bf16(a1, bl, acc[1][pf], 0, 0, 0);
      }
    }
  }

  float* og = out + ((long)g*L + pos0)*128;
  #pragma unroll
  for (int of = 0; of < 2; ++of) {
    int oc = o0 + of*16 + lhi*4;
    #pragma unroll
    for (int pf = 0; pf < 4; ++pf) {
      int pos = pf*16 + l15;
      f32x4 r = acc[of][pf];
      if (BIAS) {
        float s = sAv[l15];
        r.x += gb[oc+0]*s; r.y += gb[oc+1]*s;
        r.z += gb[oc+2]*s; r.w += gb[oc+3]*s;
      }
      *(f32x4*)(og + (long)pos*128 + oc) = r;
    }
  }
}

// ---------------- BN stats phase 1: partial sums over 256 rows per block ----------------
__global__ __launch_bounds__(256) void k_bnpart(const float* __restrict__ in,
                                                float* __restrict__ part) {
  int b = blockIdx.x, tid = threadIdx.x;
  int c = tid & 127, h = tid >> 7;
  const float* base = in + (long)b*256*128;
  float s1 = 0.f, s2 = 0.f;
  for (int r = h; r < 256; r += 2) {
    float v = base[r*128 + c];
    s1 += v; s2 += v*v;
  }
  __shared__ float l1[256], l2[256];
  l1[tid] = s1; l2[tid] = s2;
  __syncthreads();
  if (tid < 128) {
    part[b*256 + c]       = l1[tid] + l1[tid+128];
    part[b*256 + 128 + c] = l2[tid] + l2[tid+128];
  }
}

// ---------------- BN finalize: 128 channels (sum all 512 blocks) ----------------
__global__ void k_bnfin128(const float* __restrict__ part,
                           const float* __restrict__ gamma, const float* __restrict__ beta,
                           float* __restrict__ sc, float* __restrict__ sh, float invN) {
  int c = threadIdx.x;
  float s1 = 0.f, s2 = 0.f;
  for (int b = 0; b < 512; ++b) { s1 += part[b*256 + c]; s2 += part[b*256 + 128 + c]; }
  float mean = s1*invN;
  float var  = s2*invN - mean*mean;
  float s = gamma[c] * rsqrtf(var + EPSBN);
  sc[c] = s;
  sh[c] = beta[c] - mean*s;
}

// ---------------- BN finalize: 2048 channels (v,c), sum 32 blocks g=n*16+v ----------------
__global__ __launch_bounds__(256) void k_bnfin2048(const float* __restrict__ part,
                           const float* __restrict__ gamma, const float* __restrict__ beta,
                           float* __restrict__ sc, float* __restrict__ sh, float invN) {
  int ch = blockIdx.x*256 + threadIdx.x;   // (v,c)
  int v = ch >> 7, c = ch & 127;
  float s1 = 0.f, s2 = 0.f;
  for (int n = 0; n < 32; ++n) {
    s1 += part[(n*16+v)*256 + c];
    s2 += part[(n*16+v)*256 + 128 + c];
  }
  float mean = s1*invN;
  float var  = s2*invN - mean*mean;
  float s = gamma[ch] * rsqrtf(var + EPSBN);
  sc[ch] = s;
  sh[ch] = beta[ch] - mean*s;
}

// ---------------- r = relu(bn(z) + res), pos-major ----------------
__global__ __launch_bounds__(256) void k_combine(
    const float* __restrict__ z, const float* __restrict__ res,
    const float* __restrict__ sc, const float* __restrict__ sh,
    float* __restrict__ out)
{
  long i4 = (long)blockIdx.x*256 + threadIdx.x;
  int c0 = ((int)i4 & 31) << 2;
  float4 zv = ((const float4*)z)[i4];
  float4 rv = ((const float4*)res)[i4];
  float4 r;
  r.x = fmaxf(zv.x*sc[c0+0] + sh[c0+0] + rv.x, 0.f);
  r.y = fmaxf(zv.y*sc[c0+1] + sh[c0+1] + rv.y, 0.f);
  r.z = fmaxf(zv.z*sc[c0+2] + sh[c0+2] + rv.z, 0.f);
  r.w = fmaxf(zv.w*sc[c0+3] + sh[c0+3] + rv.w, 0.f);
  ((float4*)out)[i4] = r;
}

// ---------------- dynamic tail: out[n,c,v] = max_t relu(bn(z)+res) ----------------
__global__ __launch_bounds__(256) void k_maxdyn(
    const float* __restrict__ z, const float* __restrict__ res,
    const float* __restrict__ sc, const float* __restrict__ sh,
    float* __restrict__ outp)
{
  int b = blockIdx.x; int n = b >> 4, v = b & 15;
  int tid = threadIdx.x; int c = tid & 127, h = tid >> 7;
  const float* zb = z   + ((long)n*4096 + v)*128 + c;
  const float* rb = res + ((long)n*4096 + v)*128 + c;
  float s = sc[c], bb = sh[c];
  float m = 0.f;   // relu output >= 0
  for (int t = h; t < 256; t += 2) {
    float val = zb[(long)t*2048] * s + bb + rb[(long)t*2048];
    m = fmaxf(m, val);
  }
  __shared__ float red[256];
  red[tid] = m;
  __syncthreads();
  if (tid < 128)
    outp[(long)n*4096 + c*32 + v] = fmaxf(fmaxf(red[tid], red[tid+128]), 0.f);
}

// ---------------- static tail: out[n,c,16+v] = max_s bn(z[(n,v)][s][c]) ----------------
__global__ __launch_bounds__(256) void k_maxstat(
    const float* __restrict__ z,
    const float* __restrict__ sc, const float* __restrict__ sh,
    float* __restrict__ outp)
{
  int b = blockIdx.x; int n = b >> 4, v = b & 15;
  int tid = threadIdx.x; int c = tid & 127, h = tid >> 7;
  const float* zb = z + (long)b*256*128 + c;
  float s = sc[v*128 + c], bb = sh[v*128 + c];
  float m = -1e30f;
  for (int t = h; t < 256; t += 2)
    m = fmaxf(m, zb[t*128] * s + bb);
  __shared__ float red[256];
  red[tid] = m;
  __syncthreads();
  if (tid < 128)
    outp[(long)n*4096 + c*32 + 16 + v] = fmaxf(red[tid], red[tid+128]);
}

extern "C" void kernel_launch(void* const* d_in, const int* in_sizes, int n_in,
                              void* d_out, int out_size, void* d_ws, size_t ws_size,
                              hipStream_t stream) {
  (void)in_sizes; (void)n_in; (void)out_size; (void)ws_size;
  const float* x     = (const float*)d_in[0];
  const float* nv1   = (const float*)d_in[1];
  const float* nv2   = (const float*)d_in[2];
  const float* d1gw  = (const float*)d_in[3];
  const float* d1gb  = (const float*)d_in[4];
  const float* d1b1g = (const float*)d_in[5];
  const float* d1b1b = (const float*)d_in[6];
  const float* d1tw  = (const float*)d_in[7];
  // d_in[8] = d1tb: constant over BN axes -> cancels in following BN
  const float* d1b2g = (const float*)d_in[9];
  const float* d1b2b = (const float*)d_in[10];
  const float* d2gw  = (const float*)d_in[11];
  const float* d2gb  = (const float*)d_in[12];
  const float* d2b1g = (const float*)d_in[13];
  const float* d2b1b = (const float*)d_in[14];
  const float* d2tw  = (const float*)d_in[15];
  // d_in[16] = d2tb: cancels
  const float* d2b2g = (const float*)d_in[17];
  const float* d2b2b = (const float*)d_in[18];
  const float* s1pw  = (const float*)d_in[19];
  const float* s1pg  = (const float*)d_in[20];
  const float* s1pb  = (const float*)d_in[21];
  const float* s1tw  = (const float*)d_in[22];
  const float* s1tg  = (const float*)d_in[23];
  const float* s1tb  = (const float*)d_in[24];
  const float* s2pw  = (const float*)d_in[25];
  const float* s2pg  = (const float*)d_in[26];
  const float* s2pb  = (const float*)d_in[27];
  const float* s2tw  = (const float*)d_in[28];
  const float* s2tg  = (const float*)d_in[29];
  const float* s2tb  = (const float*)d_in[30];

  // ---- workspace: header (16384 floats) + exactly 3x64MB buffers = round-1-proven footprint ----
  float* W = (float*)d_ws;
  float* Am  = W;            // 256
  float* sAv = W + 256;      // 16
  float* scA = W + 512;  float* shA = W + 640;
  float* scB = W + 768;  float* shB = W + 896;
  float* scC = W + 1024; float* shC = W + 1152;
  float* scD = W + 1280; float* shD = W + 1408;
  float* scE = W + 1536; float* shE = W + 1664;
  float* scG = W + 1792; float* shG = W + 1920;
  float* scF = W + 2048; float* shF = W + 4096;   // 2048 each
  float* scH = W + 6144; float* shH = W + 8192;
  float* A = W + 16384;                  // 3x 16777216 floats; end = 50348032 floats
  float* B = A + 16777216;
  float* C = B + 16777216;
  float* outp = (float*)d_out;

  // dynamic-branch bf16 weights staged in d_out (scratch region fully overwritten
  // by k_maxdyn/k_maxstat afterwards -> deterministic)
  unsigned short* O = (unsigned short*)d_out;
  unsigned short* w_d1g = O;               // 16384 us
  unsigned short* w_d1t = O + 16384;       // 49152 us
  unsigned short* w_d2g = O + 65536;       // 16384 us
  unsigned short* w_d2t = O + 81920;       // 49152 us -> ends 131072 us = 65536 floats
  // static-branch weights staged in dead big buffers
  unsigned short* w_s1p = (unsigned short*)C;          // C dead during s1p
  unsigned short* SW    = (unsigned short*)B;          // B (xS) dead after s1p
  unsigned short* w_s1t = SW;              // 786432 us
  unsigned short* w_s2p = SW + 786432;     // 16384 us
  unsigned short* w_s2t = SW + 802816;     // 786432 us -> ends 1589248 us (3.2 MB of B)
  // BN partial sums (256*512 floats) always placed mid-way into a dead big buffer
  const long PO = 8388608;

  // ======== dynamic branch (A=xP res, ping-pong B/C) ========
  k_adj<<<1, 256, 0, stream>>>(nv1, nv2, Am, sAv);
  k_cvt_cw<<<64, 256, 0, stream>>>(d1gw, w_d1g);
  k_cvt_tw<<<192, 256, 0, stream>>>(d1tw, w_d1t, 128);
  k_cvt_cw<<<64, 256, 0, stream>>>(d2gw, w_d2g);
  k_cvt_tw<<<192, 256, 0, stream>>>(d2tw, w_d2t, 128);

  k_xpose<1,0><<<2048, 256, 0, stream>>>(x, A, nullptr);               // A = xP
  k_aggP<<<2048, 256, 0, stream>>>(A, Am, B);                          // B = agg(x)
  k_conv<0,1,0,0,0,0,1><<<2048, 256, 0, stream>>>(B, w_d1g, C, 4096, nullptr, nullptr, d1gb, sAv);
  k_bnpart<<<512, 256, 0, stream>>>(C, B + PO);                        // B dead
  k_bnfin128<<<1, 128, 0, stream>>>(B + PO, d1b1g, d1b1b, scA, shA, 1.f/131072.f);
  k_conv<16,3,0,1,0,1,0><<<2048, 256, 0, stream>>>(C, w_d1t, B, 4096, scA, shA, nullptr, nullptr);
  k_bnpart<<<512, 256, 0, stream>>>(B, C + PO);                        // C dead
  k_bnfin128<<<1, 128, 0, stream>>>(C + PO, d1b2g, d1b2b, scB, shB, 1.f/131072.f);
  k_combine<<<16384, 256, 0, stream>>>(B, A, scB, shB, C);             // C = r2
  k_aggP<<<2048, 256, 0, stream>>>(C, Am, A);                          // A = agg(r2) (xP dead)
  k_conv<0,1,0,0,0,0,1><<<2048, 256, 0, stream>>>(A, w_d2g, B, 4096, nullptr, nullptr, d2gb, sAv);
  k_bnpart<<<512, 256, 0, stream>>>(B, A + PO);                        // A dead
  k_bnfin128<<<1, 128, 0, stream>>>(A + PO, d2b1g, d2b1b, scC, shC, 1.f/131072.f);
  k_conv<16,3,0,1,0,1,0><<<2048, 256, 0, stream>>>(B, w_d2t, A, 4096, scC, shC, nullptr, nullptr);
  k_bnpart<<<512, 256, 0, stream>>>(A, B + PO);                        // B dead
  k_bnfin128<<<1, 128, 0, stream>>>(B + PO, d2b2g, d2b2b, scD, shD, 1.f/131072.f);
  k_maxdyn<<<512, 256, 0, stream>>>(A, C, scD, shD, outp);             // writes d cols (ends d_out scratch)

  // ======== static branch (B=xS; A/C ping-pong) ========
  k_xpose<0,1><<<2048, 256, 0, stream>>>(x, nullptr, B);               // B = xS
  k_cvt_cw<<<64, 256, 0, stream>>>(s1pw, w_s1p);                       // into C (dead)
  k_conv<0,1,0,0,0,0,0><<<2048, 256, 0, stream>>>(B, w_s1p, A, 256, nullptr, nullptr, nullptr, nullptr);
  k_cvt_tw<<<3072, 256, 0, stream>>>(s1tw, w_s1t, 2048);               // into B (xS dead now)
  k_cvt_cw<<<64, 256, 0, stream>>>(s2pw, w_s2p);
  k_cvt_tw<<<3072, 256, 0, stream>>>(s2tw, w_s2t, 2048);
  k_bnpart<<<512, 256, 0, stream>>>(A, C + PO);
  k_bnfin128<<<1, 128, 0, stream>>>(C + PO, s1pg, s1pb, scE, shE, 1.f/131072.f);
  k_conv<1,3,1,1,0,0,0><<<2048, 256, 0, stream>>>(A, w_s1t, C, 256, scE, shE, nullptr, nullptr);
  k_bnpart<<<512, 256, 0, stream>>>(C, A + PO);                        // A dead
  k_bnfin2048<<<8, 256, 0, stream>>>(A + PO, s1tg, s1tb, scF, shF, 1.f/8192.f);
  k_conv<0,1,0,1,1,0,0><<<2048, 256, 0, stream>>>(C, w_s2p, A, 256, scF, shF, nullptr, nullptr);
  k_bnpart<<<512, 256, 0, stream>>>(A, C + PO);                        // C dead
  k_bnfin128<<<1, 128, 0, stream>>>(C + PO, s2pg, s2pb, scG, shG, 1.f/131072.f);
  k_conv<1,3,1,1,0,0,0><<<2048, 256, 0, stream>>>(A, w_s2t, C, 256, scG, shG, nullptr, nullptr);
  k_bnpart<<<512, 256, 0, stream>>>(C, A + PO);
  k_bnfin2048<<<8, 256, 0, stream>>>(A + PO, s2tg, s2tb, scH, shH, 1.f/8192.f);
  k_maxstat<<<512, 256, 0, stream>>>(C, scH, shH, outp);               // writes s cols
}

// Round 6
// 563.819 us; speedup vs baseline: 4.7255x; 1.6187x over previous
//
#include <hip/hip_runtime.h>

#define EPSBN 1e-5f

typedef __attribute__((ext_vector_type(8))) __bf16 bf16x8;
typedef __attribute__((ext_vector_type(4))) float f32x4;

__device__ inline unsigned short f2bf(float f) {
  unsigned u = __float_as_uint(f);
  u = (u + 0x7fffu + ((u >> 16) & 1u)) >> 16;
  return (unsigned short)u;
}

// ---------------- adjacency: A = adp(nv1,nv2), plus column sums sA ----------------
__global__ void k_adj(const float* __restrict__ nv1, const float* __restrict__ nv2,
                      float* __restrict__ A, float* __restrict__ sA) {
  __shared__ float M[16][16];
  int tid = threadIdx.x;           // 256 threads
  int i = tid >> 4, j = tid & 15;
  float acc = 0.f;
  #pragma unroll
  for (int k = 0; k < 64; ++k) acc += nv1[i*64+k] * nv2[k*16+j];
  M[i][j] = fmaxf(acc, 0.f);
  __syncthreads();
  if (tid < 16) {
    float m = -1e30f;
    for (int c = 0; c < 16; ++c) m = fmaxf(m, M[tid][c]);
    float e[16]; float s = 0.f;
    for (int c = 0; c < 16; ++c) { e[c] = expf(M[tid][c] - m); s += e[c]; }
    float inv = 1.f / s;
    float t1 = -1e30f, t2 = -1e30f;
    for (int c = 0; c < 16; ++c) {
      float a = e[c] * inv; e[c] = a;
      if (a > t1) { t2 = t1; t1 = a; }
      else if (a > t2) t2 = a;
    }
    for (int c = 0; c < 16; ++c) {
      bool keep = (e[c] > (1.0f/16.0f)) && (e[c] > t2);
      M[tid][c] = keep ? e[c] : 0.f;
    }
  }
  __syncthreads();
  A[tid] = M[tid>>4][tid&15];
  if (tid < 16) {
    float s = 0.f;
    for (int v = 0; v < 16; ++v) s += M[v][tid];
    sA[tid] = s;
  }
}

// ---------------- weight converts to bf16 ----------------
__global__ __launch_bounds__(256) void k_cvt_cw(const float* __restrict__ w,
                                                unsigned short* __restrict__ o) {
  int idx = blockIdx.x*256 + threadIdx.x;
  if (idx < 16384) o[idx] = f2bf(w[idx]);
}
// temporal conv weights: in [oo][c][tap] -> out [oo][tap][c]; nOut = 128 or 2048
__global__ __launch_bounds__(256) void k_cvt_tw(const float* __restrict__ w,
                                                unsigned short* __restrict__ o, int nOut) {
  int idx = blockIdx.x*256 + threadIdx.x;
  if (idx >= nOut*384) return;
  int oo = idx / 384;
  int r = idx - oo*384;
  int tap = r >> 7, c = r & 127;
  o[idx] = f2bf(w[(oo*128 + c)*3 + tap]);
}

// ---------------- dyn: transpose x (n,c,t,v) -> xP[n][t][v][c] AND aggX[n][t][w][c] ----------------
__global__ __launch_bounds__(256) void k_xposeAgg(const float* __restrict__ x,
                                                  const float* __restrict__ Am,
                                                  float* __restrict__ xP,
                                                  float* __restrict__ xA) {
  __shared__ float tl[128*65];
  __shared__ float Asm[256];
  int b = blockIdx.x; int n = b >> 6; int t0q = b & 63;   // 64 flat (t,v) per block
  int tid = threadIdx.x;
  Asm[tid] = Am[tid];
  const float* xb = x + (long)n*128*4096 + t0q*64;
  for (int idx = tid; idx < 2048; idx += 256) {
    int c = idx >> 4, q = idx & 15;
    float4 v = *(const float4*)(xb + (long)c*4096 + q*4);
    float* d = &tl[c*65 + q*4];
    d[0]=v.x; d[1]=v.y; d[2]=v.z; d[3]=v.w;
  }
  __syncthreads();
  long obase = ((long)n*4096 + t0q*64)*128;
  for (int idx = tid; idx < 2048; idx += 256) {
    int pos = idx >> 5;
    int c0 = (idx & 31) << 2;
    float4 v;
    v.x = tl[(c0+0)*65 + pos]; v.y = tl[(c0+1)*65 + pos];
    v.z = tl[(c0+2)*65 + pos]; v.w = tl[(c0+3)*65 + pos];
    *(float4*)(xP + obase + (long)pos*128 + c0) = v;
  }
  for (int idx = tid; idx < 2048; idx += 256) {
    int pos = idx >> 5;                    // (tt, w)
    int tt = pos >> 4, w = pos & 15;
    int c0 = (idx & 31) << 2;
    float4 s = {0.f,0.f,0.f,0.f};
    #pragma unroll
    for (int v = 0; v < 16; ++v) {
      float a = Asm[v*16 + w];
      int pv = tt*16 + v;
      s.x += a * tl[(c0+0)*65 + pv];
      s.y += a * tl[(c0+1)*65 + pv];
      s.z += a * tl[(c0+2)*65 + pv];
      s.w += a * tl[(c0+3)*65 + pv];
    }
    *(float4*)(xA + obase + (long)pos*128 + c0) = s;
  }
}

// ---------------- static: transpose x (n,c,t,v) -> xS[(n,v)][t][c] ----------------
__global__ __launch_bounds__(256) void k_xposeS(const float* __restrict__ x,
                                                float* __restrict__ xS) {
  __shared__ float tl[128*65];
  int b = blockIdx.x; int n = b >> 6; int t0q = b & 63;
  int tid = threadIdx.x;
  const float* xb = x + (long)n*128*4096 + t0q*64;
  for (int idx = tid; idx < 2048; idx += 256) {
    int c = idx >> 4, q = idx & 15;
    float4 v = *(const float4*)(xb + (long)c*4096 + q*4);
    float* d = &tl[c*65 + q*4];
    d[0]=v.x; d[1]=v.y; d[2]=v.z; d[3]=v.w;
  }
  __syncthreads();
  for (int idx = tid; idx < 2048; idx += 256) {
    int pos = idx >> 5;
    int c0 = (idx & 31) << 2;
    float4 v;
    v.x = tl[(c0+0)*65 + pos]; v.y = tl[(c0+1)*65 + pos];
    v.z = tl[(c0+2)*65 + pos]; v.w = tl[(c0+3)*65 + pos];
    int vv = pos & 15, tt = pos >> 4;
    *(float4*)(xS + ((long)(n*16+vv)*256 + t0q*4 + tt)*128 + c0) = v;
  }
}

// ---------------- fused: r2 = relu(bn(z)+res) written in-place over res; agg(r2) -> out2 ----------------
__global__ __launch_bounds__(256) void k_combineAgg(
    const float* __restrict__ z, float* __restrict__ res_r2,
    const float* __restrict__ Am,
    const float* __restrict__ sc, const float* __restrict__ sh,
    float* __restrict__ agg_out)
{
  __shared__ float rl[64*128];     // 32 KB
  __shared__ float Asm[256];
  int b = blockIdx.x;              // 2048 blocks, 64 pos each (t-aligned)
  int tid = threadIdx.x;
  Asm[tid] = Am[tid];
  long base = (long)b*2048;        // in float4 units
  #pragma unroll
  for (int k = 0; k < 8; ++k) {
    int idx = tid + k*256;
    int c0 = (idx & 31) << 2;
    float4 zv = ((const float4*)z)[base + idx];
    float4 rv = ((const float4*)res_r2)[base + idx];
    float4 r;
    r.x = fmaxf(zv.x*sc[c0+0] + sh[c0+0] + rv.x, 0.f);
    r.y = fmaxf(zv.y*sc[c0+1] + sh[c0+1] + rv.y, 0.f);
    r.z = fmaxf(zv.z*sc[c0+2] + sh[c0+2] + rv.z, 0.f);
    r.w = fmaxf(zv.w*sc[c0+3] + sh[c0+3] + rv.w, 0.f);
    ((float4*)rl)[idx] = r;
  }
  __syncthreads();
  #pragma unroll
  for (int k = 0; k < 8; ++k) {
    int idx = tid + k*256;
    ((float4*)res_r2)[base + idx] = ((float4*)rl)[idx];
    int tt = idx >> 9, w = (idx >> 5) & 15, c4 = (idx & 31) << 2;
    float4 s = {0.f,0.f,0.f,0.f};
    #pragma unroll
    for (int v = 0; v < 16; ++v) {
      float a = Asm[v*16 + w];
      const float* r = &rl[(tt*16 + v)*128 + c4];
      s.x += a*r[0]; s.y += a*r[1]; s.z += a*r[2]; s.w += a*r[3];
    }
    ((float4*)agg_out)[base + idx] = s;
  }
}

// ---------------- MFMA conv (single-bf16 activations) + fused BN-stats partials ----------------
// BN/ReLU only on in-range positions; zero-padding stays exactly zero.
template<int HALO, int TAPS, int GROUPED_W, int IN_BN, int GROUPED_BN, int RELU_IN, int BIAS>
__global__ __launch_bounds__(256) void k_conv(
    const float* __restrict__ in, const unsigned short* __restrict__ Wb,
    float* __restrict__ out, int L,
    const float* __restrict__ isc, const float* __restrict__ ish,
    const float* __restrict__ gb, const float* __restrict__ sAv,
    float* __restrict__ part)
{
  constexpr int TW = 64 + 2*HALO;
  constexpr int KT = TAPS*128;
  __shared__ __align__(16) unsigned short Th[TW*128];
  int tid = threadIdx.x;
  int bpg = L >> 6;
  int g = blockIdx.x / bpg;
  int pos0 = (blockIdx.x - g*bpg) << 6;
  const float* ing = in + (long)g*L*128;

  int cbase = (IN_BN && GROUPED_BN) ? ((g & 15) << 7) : 0;
  for (int idx = tid; idx < TW*32; idx += 256) {
    int row = idx >> 5;
    int c4 = (idx & 31) << 2;
    int gp = pos0 + row - HALO;
    float4 v = {0.f,0.f,0.f,0.f};
    if (gp >= 0 && gp < L) {
      v = *(const float4*)(ing + (long)gp*128 + c4);
      if (IN_BN) {
        int ci = cbase + c4;
        v.x = v.x*isc[ci+0] + ish[ci+0];
        v.y = v.y*isc[ci+1] + ish[ci+1];
        v.z = v.z*isc[ci+2] + ish[ci+2];
        v.w = v.w*isc[ci+3] + ish[ci+3];
        if (RELU_IN) {
          v.x = fmaxf(v.x,0.f); v.y = fmaxf(v.y,0.f);
          v.z = fmaxf(v.z,0.f); v.w = fmaxf(v.w,0.f);
        }
      }
    }
    ushort4 h;
    h.x = f2bf(v.x); h.y = f2bf(v.y); h.z = f2bf(v.z); h.w = f2bf(v.w);
    int byteoff = (row << 8) + (c4 << 1);
    byteoff ^= ((row & 7) << 4);
    *(ushort4*)((char*)Th + byteoff) = h;
  }
  __syncthreads();

  int wv = tid >> 6;
  int lane = tid & 63;
  int l15 = lane & 15;
  int lhi = lane >> 4;
  int o0 = wv << 5;

  f32x4 zz = {0.f,0.f,0.f,0.f};
  f32x4 acc[2][4];
  #pragma unroll
  for (int i = 0; i < 2; ++i)
    #pragma unroll
    for (int q = 0; q < 4; ++q) acc[i][q] = zz;

  const unsigned short* Wg = Wb + (GROUPED_W ? (long)(g & 15)*128*KT : 0);
  const unsigned short* wr0 = Wg + (long)(o0 + l15)*KT + lhi*8;
  const unsigned short* wr1 = wr0 + 16*KT;

  #pragma unroll
  for (int tap = 0; tap < TAPS; ++tap) {
    #pragma unroll
    for (int kk = 0; kk < 4; ++kk) {
      int kc = kk*32 + lhi*8;
      bf16x8 a0 = *(const bf16x8*)(wr0 + tap*128 + kk*32);
      bf16x8 a1 = *(const bf16x8*)(wr1 + tap*128 + kk*32);
      #pragma unroll
      for (int pf = 0; pf < 4; ++pf) {
        int row = pf*16 + l15 + tap*HALO;
        int byteoff = (row << 8) + (kc << 1);
        byteoff ^= ((row & 7) << 4);
        bf16x8 bh = *(const bf16x8*)((const char*)Th + byteoff);
        acc[0][pf] = __builtin_amdgcn_mfma_f32_16x16x32_bf16(a0, bh, acc[0][pf], 0, 0, 0);
        acc[1][pf] = __builtin_amdgcn_mfma_f32_16x16x32_bf16(a1, bh, acc[1][pf], 0, 0, 0);
      }
    }
  }

  // epilogue: store + accumulate BN partial sums (per-channel over this block's 64 pos)
  float s1a[2][4], s2a[2][4];
  #pragma unroll
  for (int i = 0; i < 2; ++i)
    #pragma unroll
    for (int j = 0; j < 4; ++j) { s1a[i][j] = 0.f; s2a[i][j] = 0.f; }

  float* og = out + ((long)g*L + pos0)*128;
  #pragma unroll
  for (int of = 0; of < 2; ++of) {
    int oc = o0 + of*16 + lhi*4;
    #pragma unroll
    for (int pf = 0; pf < 4; ++pf) {
      int pos = pf*16 + l15;
      f32x4 r = acc[of][pf];
      if (BIAS) {
        float s = sAv[l15];
        r.x += gb[oc+0]*s; r.y += gb[oc+1]*s;
        r.z += gb[oc+2]*s; r.w += gb[oc+3]*s;
      }
      *(f32x4*)(og + (long)pos*128 + oc) = r;
      #pragma unroll
      for (int j = 0; j < 4; ++j) { s1a[of][j] += r[j]; s2a[of][j] += r[j]*r[j]; }
    }
  }
  // reduce over the 16 position-lanes (l15) within each 16-lane group
  #pragma unroll
  for (int of = 0; of < 2; ++of)
    #pragma unroll
    for (int j = 0; j < 4; ++j) {
      float a = s1a[of][j], b = s2a[of][j];
      #pragma unroll
      for (int m = 1; m < 16; m <<= 1) { a += __shfl_xor(a, m); b += __shfl_xor(b, m); }
      s1a[of][j] = a; s2a[of][j] = b;
    }
  __syncthreads();                       // all waves done with Th
  float* red = (float*)Th;               // reuse LDS (256 floats needed)
  if (l15 == 0) {
    #pragma unroll
    for (int of = 0; of < 2; ++of)
      #pragma unroll
      for (int j = 0; j < 4; ++j) {
        int ch = o0 + of*16 + lhi*4 + j;
        red[ch] = s1a[of][j];
        red[128 + ch] = s2a[of][j];
      }
  }
  __syncthreads();
  part[(long)blockIdx.x*256 + tid] = red[tid];
}

// ---------------- BN finalize: 128 channels, sum 2048 block-partials ----------------
__global__ __launch_bounds__(256) void k_bnfin128(const float* __restrict__ part,
                           const float* __restrict__ gamma, const float* __restrict__ beta,
                           float* __restrict__ sc, float* __restrict__ sh, float invN) {
  int c = blockIdx.x, tid = threadIdx.x;
  float s1 = 0.f, s2 = 0.f;
  for (int b = tid; b < 2048; b += 256) {
    s1 += part[b*256 + c];
    s2 += part[b*256 + 128 + c];
  }
  __shared__ float l1[256], l2[256];
  l1[tid] = s1; l2[tid] = s2;
  __syncthreads();
  for (int st = 128; st > 0; st >>= 1) {
    if (tid < st) { l1[tid] += l1[tid+st]; l2[tid] += l2[tid+st]; }
    __syncthreads();
  }
  if (tid == 0) {
    float mean = l1[0]*invN;
    float var  = l2[0]*invN - mean*mean;
    float s = gamma[c] * rsqrtf(var + EPSBN);
    sc[c] = s;
    sh[c] = beta[c] - mean*s;
  }
}

// ---------------- BN finalize: 2048 (v,c) channels, sum 128 block-partials each ----------------
__global__ void k_bnfin2048(const float* __restrict__ part,
                            const float* __restrict__ gamma, const float* __restrict__ beta,
                            float* __restrict__ sc, float* __restrict__ sh, float invN) {
  int ch = blockIdx.x; int v = ch >> 7, c = ch & 127;
  int lane = threadIdx.x;          // 64
  float s1 = 0.f, s2 = 0.f;
  for (int i = lane; i < 128; i += 64) {
    int blk = (((i >> 2)*16 + v) << 2) + (i & 3);    // (n*16+v)*4+bp
    s1 += part[blk*256 + c];
    s2 += part[blk*256 + 128 + c];
  }
  for (int m = 32; m > 0; m >>= 1) { s1 += __shfl_down(s1, m); s2 += __shfl_down(s2, m); }
  if (lane == 0) {
    float mean = s1*invN;
    float var  = s2*invN - mean*mean;
    float s = gamma[ch] * rsqrtf(var + EPSBN);
    sc[ch] = s;
    sh[ch] = beta[ch] - mean*s;
  }
}

// ---------------- dynamic tail: out[n,c,v] = max_t relu(bn(z)+res) ----------------
__global__ __launch_bounds__(256) void k_maxdyn(
    const float* __restrict__ z, const float* __restrict__ res,
    const float* __restrict__ sc, const float* __restrict__ sh,
    float* __restrict__ outp)
{
  int b = blockIdx.x; int n = b >> 4, v = b & 15;
  int tid = threadIdx.x; int c = tid & 127, h = tid >> 7;
  const float* zb = z   + ((long)n*4096 + v)*128 + c;
  const float* rb = res + ((long)n*4096 + v)*128 + c;
  float s = sc[c], bb = sh[c];
  float m = 0.f;   // relu output >= 0
  for (int t = h; t < 256; t += 2) {
    float val = zb[(long)t*2048] * s + bb + rb[(long)t*2048];
    m = fmaxf(m, val);
  }
  __shared__ float red[256];
  red[tid] = m;
  __syncthreads();
  if (tid < 128)
    outp[(long)n*4096 + c*32 + v] = fmaxf(fmaxf(red[tid], red[tid+128]), 0.f);
}

// ---------------- static tail: out[n,c,16+v] = max_s bn(z[(n,v)][s][c]) ----------------
__global__ __launch_bounds__(256) void k_maxstat(
    const float* __restrict__ z,
    const float* __restrict__ sc, const float* __restrict__ sh,
    float* __restrict__ outp)
{
  int b = blockIdx.x; int n = b >> 4, v = b & 15;
  int tid = threadIdx.x; int c = tid & 127, h = tid >> 7;
  const float* zb = z + (long)b*256*128 + c;
  float s = sc[v*128 + c], bb = sh[v*128 + c];
  float m = -1e30f;
  for (int t = h; t < 256; t += 2)
    m = fmaxf(m, zb[t*128] * s + bb);
  __shared__ float red[256];
  red[tid] = m;
  __syncthreads();
  if (tid < 128)
    outp[(long)n*4096 + c*32 + 16 + v] = fmaxf(red[tid], red[tid+128]);
}

extern "C" void kernel_launch(void* const* d_in, const int* in_sizes, int n_in,
                              void* d_out, int out_size, void* d_ws, size_t ws_size,
                              hipStream_t stream) {
  (void)in_sizes; (void)n_in; (void)out_size; (void)ws_size;
  const float* x     = (const float*)d_in[0];
  const float* nv1   = (const float*)d_in[1];
  const float* nv2   = (const float*)d_in[2];
  const float* d1gw  = (const float*)d_in[3];
  const float* d1gb  = (const float*)d_in[4];
  const float* d1b1g = (const float*)d_in[5];
  const float* d1b1b = (const float*)d_in[6];
  const float* d1tw  = (const float*)d_in[7];
  // d_in[8] = d1tb: constant over BN axes -> cancels in following BN
  const float* d1b2g = (const float*)d_in[9];
  const float* d1b2b = (const float*)d_in[10];
  const float* d2gw  = (const float*)d_in[11];
  const float* d2gb  = (const float*)d_in[12];
  const float* d2b1g = (const float*)d_in[13];
  const float* d2b1b = (const float*)d_in[14];
  const float* d2tw  = (const float*)d_in[15];
  // d_in[16] = d2tb: cancels
  const float* d2b2g = (const float*)d_in[17];
  const float* d2b2b = (const float*)d_in[18];
  const float* s1pw  = (const float*)d_in[19];
  const float* s1pg  = (const float*)d_in[20];
  const float* s1pb  = (const float*)d_in[21];
  const float* s1tw  = (const float*)d_in[22];
  const float* s1tg  = (const float*)d_in[23];
  const float* s1tb  = (const float*)d_in[24];
  const float* s2pw  = (const float*)d_in[25];
  const float* s2pg  = (const float*)d_in[26];
  const float* s2pb  = (const float*)d_in[27];
  const float* s2tw  = (const float*)d_in[28];
  const float* s2tg  = (const float*)d_in[29];
  const float* s2tb  = (const float*)d_in[30];

  // ---- workspace: header + 3x64MB + part(2MB) + dyn weights (128KB) = 203.8 MB ----
  float* W = (float*)d_ws;
  float* Am  = W;            // 256
  float* sAv = W + 256;      // 16
  float* scA = W + 512;  float* shA = W + 640;
  float* scB = W + 768;  float* shB = W + 896;
  float* scC = W + 1024; float* shC = W + 1152;
  float* scD = W + 1280; float* shD = W + 1408;
  float* scE = W + 1536; float* shE = W + 1664;
  float* scG = W + 1792; float* shG = W + 1920;
  float* scF = W + 2048; float* shF = W + 4096;   // 2048 each
  float* scH = W + 6144; float* shH = W + 8192;
  float* A = W + 16384;
  float* B = A + 16777216;
  float* C = B + 16777216;
  float* part = C + 16777216;                      // 2048*256 = 524288 floats
  unsigned short* DW = (unsigned short*)(part + 524288);
  unsigned short* w_d1g = DW;               // 16384 us
  unsigned short* w_d1t = DW + 16384;       // 49152 us
  unsigned short* w_d2g = DW + 65536;       // 16384 us
  unsigned short* w_d2t = DW + 81920;       // 49152 us -> end 131072 us
  // static weights staged in dead B (xS consumed by first static conv)
  unsigned short* w_s1p = (unsigned short*)C;   // C dead at that point
  unsigned short* SW    = (unsigned short*)B;
  unsigned short* w_s1t = SW;               // 786432 us
  unsigned short* w_s2p = SW + 786432;      // 16384 us
  unsigned short* w_s2t = SW + 802816;      // 786432 us
  float* outp = (float*)d_out;

  // ======== dynamic branch ========
  k_adj<<<1, 256, 0, stream>>>(nv1, nv2, Am, sAv);
  k_cvt_cw<<<64, 256, 0, stream>>>(d1gw, w_d1g);
  k_cvt_tw<<<192, 256, 0, stream>>>(d1tw, w_d1t, 128);
  k_cvt_cw<<<64, 256, 0, stream>>>(d2gw, w_d2g);
  k_cvt_tw<<<192, 256, 0, stream>>>(d2tw, w_d2t, 128);

  k_xposeAgg<<<2048, 256, 0, stream>>>(x, Am, A, B);                   // A=xP, B=agg(x)
  k_conv<0,1,0,0,0,0,1><<<2048, 256, 0, stream>>>(B, w_d1g, C, 4096, nullptr, nullptr, d1gb, sAv, part);
  k_bnfin128<<<128, 256, 0, stream>>>(part, d1b1g, d1b1b, scA, shA, 1.f/131072.f);
  k_conv<16,3,0,1,0,1,0><<<2048, 256, 0, stream>>>(C, w_d1t, B, 4096, scA, shA, nullptr, nullptr, part);
  k_bnfin128<<<128, 256, 0, stream>>>(part, d1b2g, d1b2b, scB, shB, 1.f/131072.f);
  k_combineAgg<<<2048, 256, 0, stream>>>(B, A, Am, scB, shB, C);       // A=r2 (in-place), C=agg(r2)
  k_conv<0,1,0,0,0,0,1><<<2048, 256, 0, stream>>>(C, w_d2g, B, 4096, nullptr, nullptr, d2gb, sAv, part);
  k_bnfin128<<<128, 256, 0, stream>>>(part, d2b1g, d2b1b, scC, shC, 1.f/131072.f);
  k_conv<16,3,0,1,0,1,0><<<2048, 256, 0, stream>>>(B, w_d2t, C, 4096, scC, shC, nullptr, nullptr, part);
  k_bnfin128<<<128, 256, 0, stream>>>(part, d2b2g, d2b2b, scD, shD, 1.f/131072.f);
  k_maxdyn<<<512, 256, 0, stream>>>(C, A, scD, shD, outp);             // d columns

  // ======== static branch ========
  k_xposeS<<<2048, 256, 0, stream>>>(x, B);                            // B = xS
  k_cvt_cw<<<64, 256, 0, stream>>>(s1pw, w_s1p);                       // into C (dead)
  k_conv<0,1,0,0,0,0,0><<<2048, 256, 0, stream>>>(B, w_s1p, A, 256, nullptr, nullptr, nullptr, nullptr, part);
  k_cvt_tw<<<3072, 256, 0, stream>>>(s1tw, w_s1t, 2048);               // into B (xS dead now)
  k_cvt_cw<<<64, 256, 0, stream>>>(s2pw, w_s2p);
  k_cvt_tw<<<3072, 256, 0, stream>>>(s2tw, w_s2t, 2048);
  k_bnfin128<<<128, 256, 0, stream>>>(part, s1pg, s1pb, scE, shE, 1.f/131072.f);
  k_conv<1,3,1,1,0,0,0><<<2048, 256, 0, stream>>>(A, w_s1t, C, 256, scE, shE, nullptr, nullptr, part);
  k_bnfin2048<<<2048, 64, 0, stream>>>(part, s1tg, s1tb, scF, shF, 1.f/8192.f);
  k_conv<0,1,0,1,1,0,0><<<2048, 256, 0, stream>>>(C, w_s2p, A, 256, scF, shF, nullptr, nullptr, part);
  k_bnfin128<<<128, 256, 0, stream>>>(part, s2pg, s2pb, scG, shG, 1.f/131072.f);
  k_conv<1,3,1,1,0,0,0><<<2048, 256, 0, stream>>>(A, w_s2t, C, 256, scG, shG, nullptr, nullptr, part);
  k_bnfin2048<<<2048, 64, 0, stream>>>(part, s2tg, s2tb, scH, shH, 1.f/8192.f);
  k_maxstat<<<512, 256, 0, stream>>>(C, scH, shH, outp);               // s columns
}

// Round 7
// 447.802 us; speedup vs baseline: 5.9498x; 1.2591x over previous
//
#include <hip/hip_runtime.h>

#define EPSBN 1e-5f

typedef __attribute__((ext_vector_type(8))) __bf16 bf16x8;
typedef __attribute__((ext_vector_type(4))) float f32x4;
typedef __attribute__((ext_vector_type(8))) unsigned short us8;

__device__ inline unsigned short f2bf(float f) {
  unsigned u = __float_as_uint(f);
  u = (u + 0x7fffu + ((u >> 16) & 1u)) >> 16;
  return (unsigned short)u;
}
__device__ inline float bf2f(unsigned short h) {
  return __uint_as_float(((unsigned)h) << 16);
}

// ---------------- adjacency: A = adp(nv1,nv2), plus column sums sA ----------------
__global__ void k_adj(const float* __restrict__ nv1, const float* __restrict__ nv2,
                      float* __restrict__ A, float* __restrict__ sA) {
  __shared__ float M[16][16];
  int tid = threadIdx.x;
  int i = tid >> 4, j = tid & 15;
  float acc = 0.f;
  #pragma unroll
  for (int k = 0; k < 64; ++k) acc += nv1[i*64+k] * nv2[k*16+j];
  M[i][j] = fmaxf(acc, 0.f);
  __syncthreads();
  if (tid < 16) {
    float m = -1e30f;
    for (int c = 0; c < 16; ++c) m = fmaxf(m, M[tid][c]);
    float e[16]; float s = 0.f;
    for (int c = 0; c < 16; ++c) { e[c] = expf(M[tid][c] - m); s += e[c]; }
    float inv = 1.f / s;
    float t1 = -1e30f, t2 = -1e30f;
    for (int c = 0; c < 16; ++c) {
      float a = e[c] * inv; e[c] = a;
      if (a > t1) { t2 = t1; t1 = a; }
      else if (a > t2) t2 = a;
    }
    for (int c = 0; c < 16; ++c) {
      bool keep = (e[c] > (1.0f/16.0f)) && (e[c] > t2);
      M[tid][c] = keep ? e[c] : 0.f;
    }
  }
  __syncthreads();
  A[tid] = M[tid>>4][tid&15];
  if (tid < 16) {
    float s = 0.f;
    for (int v = 0; v < 16; ++v) s += M[v][tid];
    sA[tid] = s;
  }
}

// ---------------- weight converts to bf16 ----------------
__global__ __launch_bounds__(256) void k_cvt_cw(const float* __restrict__ w,
                                                unsigned short* __restrict__ o) {
  int idx = blockIdx.x*256 + threadIdx.x;
  if (idx < 16384) o[idx] = f2bf(w[idx]);
}
__global__ __launch_bounds__(256) void k_cvt_tw(const float* __restrict__ w,
                                                unsigned short* __restrict__ o, int nOut) {
  int idx = blockIdx.x*256 + threadIdx.x;
  if (idx >= nOut*384) return;
  int oo = idx / 384;
  int r = idx - oo*384;
  int tap = r >> 7, c = r & 127;
  o[idx] = f2bf(w[(oo*128 + c)*3 + tap]);
}

// ---------------- dyn: agg(x) -> bf16 [n][t][w][c]  (x read native, no xP) ----------------
__global__ __launch_bounds__(256) void k_aggX(const float* __restrict__ x,
                                              const float* __restrict__ Am,
                                              unsigned short* __restrict__ xA) {
  __shared__ float tl[64*128];      // [pos][c], 16B-block XOR swizzled
  __shared__ float Asm[256];
  int b = blockIdx.x; int n = b >> 6; int off = (b & 63) << 6;   // 64 flat (t,v) pos
  int tid = threadIdx.x;
  Asm[tid] = Am[tid];
  const float* xb = x + (long)n*524288 + off;
  for (int idx = tid; idx < 2048; idx += 256) {
    int c = idx >> 4, q = idx & 15;
    float4 v = *(const float4*)(xb + (long)c*4096 + q*4);
    int cb = c >> 2, cl = c & 3;
    #pragma unroll
    for (int j = 0; j < 4; ++j)
      tl[(4*q+j)*128 + (((cb ^ q) & 31) << 2) + cl] = ((const float*)&v)[j];
  }
  __syncthreads();
  unsigned short* ob = xA + ((long)n*4096 + off)*128;
  for (int idx = tid; idx < 2048; idx += 256) {
    int pos = idx >> 5, cblk = idx & 31;
    int tt = pos >> 4, w = pos & 15;
    f32x4 s = {0.f,0.f,0.f,0.f};
    #pragma unroll
    for (int v = 0; v < 16; ++v) {
      int p = tt*16 + v;
      f32x4 xv = *(const f32x4*)&tl[p*128 + (((cblk ^ (p >> 2)) & 31) << 2)];
      float a = Asm[v*16 + w];
      s.x += a*xv.x; s.y += a*xv.y; s.z += a*xv.z; s.w += a*xv.w;
    }
    ushort4 pk;
    pk.x = f2bf(s.x); pk.y = f2bf(s.y); pk.z = f2bf(s.z); pk.w = f2bf(s.w);
    *(ushort4*)(ob + (long)pos*128 + cblk*4) = pk;
  }
}

// ---------------- static: transpose x -> xS bf16 [(n,v)][t][c] ----------------
__global__ __launch_bounds__(256) void k_xS(const float* __restrict__ x,
                                            unsigned short* __restrict__ xS) {
  __shared__ float tl[64*128];
  int b = blockIdx.x; int n = b >> 6; int t0q = b & 63;
  int tid = threadIdx.x;
  const float* xb = x + (long)n*524288 + t0q*64;
  for (int idx = tid; idx < 2048; idx += 256) {
    int c = idx >> 4, q = idx & 15;
    float4 v = *(const float4*)(xb + (long)c*4096 + q*4);
    int cb = c >> 2, cl = c & 3;
    #pragma unroll
    for (int j = 0; j < 4; ++j)
      tl[(4*q+j)*128 + (((cb ^ q) & 31) << 2) + cl] = ((const float*)&v)[j];
  }
  __syncthreads();
  for (int idx = tid; idx < 2048; idx += 256) {
    int pos = idx >> 5, cblk = idx & 31;
    f32x4 v = *(const f32x4*)&tl[pos*128 + (((cblk ^ (pos >> 2)) & 31) << 2)];
    ushort4 pk;
    pk.x = f2bf(v.x); pk.y = f2bf(v.y); pk.z = f2bf(v.z); pk.w = f2bf(v.w);
    int vv = pos & 15, tt = pos >> 4;
    *(ushort4*)(xS + ((long)(n*16+vv)*256 + t0q*4 + tt)*128 + cblk*4) = pk;
  }
}

// ---------------- fused: r2 = relu(bn(z2)+x) -> bf16; agg(r2) -> bf16 ----------------
__global__ __launch_bounds__(256) void k_combineAgg(
    const unsigned short* __restrict__ z, const float* __restrict__ x,
    const float* __restrict__ Am,
    const float* __restrict__ sc, const float* __restrict__ sh,
    unsigned short* __restrict__ r2, unsigned short* __restrict__ agg_out)
{
  __shared__ float rl[64*128];     // [pos][c] swizzled
  __shared__ float Asm[256];
  int b = blockIdx.x;              // 2048 blocks = (n, 64-pos chunk)
  int n = b >> 6; int off = (b & 63) << 6;
  int tid = threadIdx.x;
  Asm[tid] = Am[tid];
  long zbase = (long)b * 8192;
  // phase 1: bn(z2) into rl
  for (int idx = tid; idx < 1024; idx += 256) {
    int pos = idx >> 4, c8 = (idx & 15) << 3;
    us8 raw = *(const us8*)(z + zbase + (long)pos*128 + c8);
    int qp = pos >> 2;
    #pragma unroll
    for (int half = 0; half < 2; ++half) {
      f32x4 f;
      #pragma unroll
      for (int j = 0; j < 4; ++j) {
        int cc = c8 + half*4 + j;
        f[j] = bf2f(raw[half*4+j]) * sc[cc] + sh[cc];
      }
      int cblk = (c8 >> 2) + half;
      *(f32x4*)&rl[pos*128 + (((cblk ^ qp) & 31) << 2)] = f;
    }
  }
  __syncthreads();
  // phase 2: add residual x (native layout), relu
  const float* xb = x + (long)n*524288 + off;
  for (int idx = tid; idx < 2048; idx += 256) {
    int c = idx >> 4, q = idx & 15;
    float4 v = *(const float4*)(xb + (long)c*4096 + q*4);
    int cb = c >> 2, cl = c & 3;
    #pragma unroll
    for (int j = 0; j < 4; ++j) {
      int a = (4*q+j)*128 + (((cb ^ q) & 31) << 2) + cl;
      rl[a] = fmaxf(rl[a] + ((const float*)&v)[j], 0.f);
    }
  }
  __syncthreads();
  // phase 3: write r2 bf16 + agg(r2) bf16
  for (int idx = tid; idx < 2048; idx += 256) {
    int pos = idx >> 5, cblk = idx & 31;
    int tt = pos >> 4, w = pos & 15;
    f32x4 rv = *(const f32x4*)&rl[pos*128 + (((cblk ^ (pos >> 2)) & 31) << 2)];
    ushort4 pk;
    pk.x = f2bf(rv.x); pk.y = f2bf(rv.y); pk.z = f2bf(rv.z); pk.w = f2bf(rv.w);
    *(ushort4*)(r2 + zbase + (long)pos*128 + cblk*4) = pk;
    f32x4 s = {0.f,0.f,0.f,0.f};
    #pragma unroll
    for (int v = 0; v < 16; ++v) {
      int p = tt*16 + v;
      f32x4 xv = *(const f32x4*)&rl[p*128 + (((cblk ^ (p >> 2)) & 31) << 2)];
      float a = Asm[v*16 + w];
      s.x += a*xv.x; s.y += a*xv.y; s.z += a*xv.z; s.w += a*xv.w;
    }
    ushort4 pa;
    pa.x = f2bf(s.x); pa.y = f2bf(s.y); pa.z = f2bf(s.z); pa.w = f2bf(s.w);
    *(ushort4*)(agg_out + zbase + (long)pos*128 + cblk*4) = pa;
  }
}

// ---------------- MFMA conv, bf16 in / bf16 out, fused BN-stats partials ----------------
// BN/ReLU only on in-range positions; zero-padding stays exactly zero.
template<int HALO, int TAPS, int GROUPED_W, int IN_BN, int GROUPED_BN, int RELU_IN, int BIAS>
__global__ __launch_bounds__(256) void k_conv(
    const unsigned short* __restrict__ in, const unsigned short* __restrict__ Wb,
    unsigned short* __restrict__ out, int L,
    const float* __restrict__ isc, const float* __restrict__ ish,
    const float* __restrict__ gb, const float* __restrict__ sAv,
    float* __restrict__ part)
{
  constexpr int TW = 64 + 2*HALO;
  constexpr int KT = TAPS*128;
  __shared__ __align__(16) unsigned short Th[TW*128];
  int tid = threadIdx.x;
  int bpg = L >> 6;
  int g = blockIdx.x / bpg;
  int pos0 = (blockIdx.x - g*bpg) << 6;
  const unsigned short* ing = in + (long)g*L*128;

  int cbase = (IN_BN && GROUPED_BN) ? ((g & 15) << 7) : 0;
  for (int idx = tid; idx < TW*16; idx += 256) {
    int row = idx >> 4;
    int c8 = (idx & 15) << 3;
    int gp = pos0 + row - HALO;
    us8 h = (us8)0;
    if (gp >= 0 && gp < L) {
      us8 raw = *(const us8*)(ing + (long)gp*128 + c8);
      if (IN_BN) {
        #pragma unroll
        for (int j = 0; j < 8; ++j) {
          int ci = cbase + c8 + j;
          float v = bf2f(raw[j]) * isc[ci] + ish[ci];
          if (RELU_IN) v = fmaxf(v, 0.f);
          h[j] = f2bf(v);
        }
      } else {
        h = raw;
      }
    }
    int byteoff = (row << 8) + (c8 << 1);
    byteoff ^= ((row & 7) << 4);
    *(us8*)((char*)Th + byteoff) = h;
  }
  __syncthreads();

  int wv = tid >> 6;
  int lane = tid & 63;
  int l15 = lane & 15;
  int lhi = lane >> 4;
  int o0 = wv << 5;

  f32x4 zz = {0.f,0.f,0.f,0.f};
  f32x4 acc[2][4];
  #pragma unroll
  for (int i = 0; i < 2; ++i)
    #pragma unroll
    for (int q = 0; q < 4; ++q) acc[i][q] = zz;

  const unsigned short* Wg = Wb + (GROUPED_W ? (long)(g & 15)*128*KT : 0);
  const unsigned short* wr0 = Wg + (long)(o0 + l15)*KT + lhi*8;
  const unsigned short* wr1 = wr0 + 16*KT;

  #pragma unroll
  for (int tap = 0; tap < TAPS; ++tap) {
    #pragma unroll
    for (int kk = 0; kk < 4; ++kk) {
      int kc = kk*32 + lhi*8;
      bf16x8 a0 = *(const bf16x8*)(wr0 + tap*128 + kk*32);
      bf16x8 a1 = *(const bf16x8*)(wr1 + tap*128 + kk*32);
      #pragma unroll
      for (int pf = 0; pf < 4; ++pf) {
        int row = pf*16 + l15 + tap*HALO;
        int byteoff = (row << 8) + (kc << 1);
        byteoff ^= ((row & 7) << 4);
        bf16x8 bh = *(const bf16x8*)((const char*)Th + byteoff);
        acc[0][pf] = __builtin_amdgcn_mfma_f32_16x16x32_bf16(a0, bh, acc[0][pf], 0, 0, 0);
        acc[1][pf] = __builtin_amdgcn_mfma_f32_16x16x32_bf16(a1, bh, acc[1][pf], 0, 0, 0);
      }
    }
  }

  // epilogue: bf16 store + BN partials (fp32, pre-rounding)
  float s1a[2][4], s2a[2][4];
  #pragma unroll
  for (int i = 0; i < 2; ++i)
    #pragma unroll
    for (int j = 0; j < 4; ++j) { s1a[i][j] = 0.f; s2a[i][j] = 0.f; }

  unsigned short* og = out + ((long)g*L + pos0)*128;
  #pragma unroll
  for (int of = 0; of < 2; ++of) {
    int oc = o0 + of*16 + lhi*4;
    #pragma unroll
    for (int pf = 0; pf < 4; ++pf) {
      int pos = pf*16 + l15;
      f32x4 r = acc[of][pf];
      if (BIAS) {
        float s = sAv[l15];
        r.x += gb[oc+0]*s; r.y += gb[oc+1]*s;
        r.z += gb[oc+2]*s; r.w += gb[oc+3]*s;
      }
      ushort4 pk;
      pk.x = f2bf(r.x); pk.y = f2bf(r.y); pk.z = f2bf(r.z); pk.w = f2bf(r.w);
      *(ushort4*)(og + (long)pos*128 + oc) = pk;
      #pragma unroll
      for (int j = 0; j < 4; ++j) { s1a[of][j] += r[j]; s2a[of][j] += r[j]*r[j]; }
    }
  }
  #pragma unroll
  for (int of = 0; of < 2; ++of)
    #pragma unroll
    for (int j = 0; j < 4; ++j) {
      float a = s1a[of][j], b = s2a[of][j];
      #pragma unroll
      for (int m = 1; m < 16; m <<= 1) { a += __shfl_xor(a, m); b += __shfl_xor(b, m); }
      s1a[of][j] = a; s2a[of][j] = b;
    }
  __syncthreads();
  float* red = (float*)Th;
  if (l15 == 0) {
    #pragma unroll
    for (int of = 0; of < 2; ++of)
      #pragma unroll
      for (int j = 0; j < 4; ++j) {
        int ch = o0 + of*16 + lhi*4 + j;
        red[ch] = s1a[of][j];
        red[128 + ch] = s2a[of][j];
      }
  }
  __syncthreads();
  part[(long)blockIdx.x*256 + tid] = red[tid];
}

// ---------------- BN finalize: 128 channels, sum 2048 block-partials ----------------
__global__ __launch_bounds__(256) void k_bnfin128(const float* __restrict__ part,
                           const float* __restrict__ gamma, const float* __restrict__ beta,
                           float* __restrict__ sc, float* __restrict__ sh, float invN) {
  int c = blockIdx.x, tid = threadIdx.x;
  float s1 = 0.f, s2 = 0.f;
  for (int b = tid; b < 2048; b += 256) {
    s1 += part[b*256 + c];
    s2 += part[b*256 + 128 + c];
  }
  __shared__ float l1[256], l2[256];
  l1[tid] = s1; l2[tid] = s2;
  __syncthreads();
  for (int st = 128; st > 0; st >>= 1) {
    if (tid < st) { l1[tid] += l1[tid+st]; l2[tid] += l2[tid+st]; }
    __syncthreads();
  }
  if (tid == 0) {
    float mean = l1[0]*invN;
    float var  = l2[0]*invN - mean*mean;
    float s = gamma[c] * rsqrtf(var + EPSBN);
    sc[c] = s;
    sh[c] = beta[c] - mean*s;
  }
}

// ---------------- BN finalize: 2048 (v,c) channels ----------------
__global__ void k_bnfin2048(const float* __restrict__ part,
                            const float* __restrict__ gamma, const float* __restrict__ beta,
                            float* __restrict__ sc, float* __restrict__ sh, float invN) {
  int ch = blockIdx.x; int v = ch >> 7, c = ch & 127;
  int lane = threadIdx.x;          // 64
  float s1 = 0.f, s2 = 0.f;
  for (int i = lane; i < 128; i += 64) {
    int blk = (((i >> 2)*16 + v) << 2) + (i & 3);
    s1 += part[blk*256 + c];
    s2 += part[blk*256 + 128 + c];
  }
  for (int m = 32; m > 0; m >>= 1) { s1 += __shfl_down(s1, m); s2 += __shfl_down(s2, m); }
  if (lane == 0) {
    float mean = s1*invN;
    float var  = s2*invN - mean*mean;
    float s = gamma[ch] * rsqrtf(var + EPSBN);
    sc[ch] = s;
    sh[ch] = beta[ch] - mean*s;
  }
}

// ---------------- dynamic tail: out[n,c,v] = max_t relu(bn(z)+r2), bf16 inputs ----------------
__global__ __launch_bounds__(256) void k_maxdyn(
    const unsigned short* __restrict__ z, const unsigned short* __restrict__ res,
    const float* __restrict__ sc, const float* __restrict__ sh,
    float* __restrict__ outp)
{
  int b = blockIdx.x; int n = b >> 4, v = b & 15;
  int tid = threadIdx.x; int c = tid & 127, h = tid >> 7;
  const unsigned short* zb = z   + ((long)n*4096 + v)*128 + c;
  const unsigned short* rb = res + ((long)n*4096 + v)*128 + c;
  float s = sc[c], bb = sh[c];
  float m = 0.f;
  for (int t = h; t < 256; t += 2) {
    float val = bf2f(zb[(long)t*2048]) * s + bb + bf2f(rb[(long)t*2048]);
    m = fmaxf(m, val);
  }
  __shared__ float red[256];
  red[tid] = m;
  __syncthreads();
  if (tid < 128)
    outp[(long)n*4096 + c*32 + v] = fmaxf(fmaxf(red[tid], red[tid+128]), 0.f);
}

// ---------------- static tail: out[n,c,16+v] = max_s bn(z[(n,v)][s][c]), bf16 ----------------
__global__ __launch_bounds__(256) void k_maxstat(
    const unsigned short* __restrict__ z,
    const float* __restrict__ sc, const float* __restrict__ sh,
    float* __restrict__ outp)
{
  int b = blockIdx.x; int n = b >> 4, v = b & 15;
  int tid = threadIdx.x; int c = tid & 127, h = tid >> 7;
  const unsigned short* zb = z + (long)b*256*128 + c;
  float s = sc[v*128 + c], bb = sh[v*128 + c];
  float m = -1e30f;
  for (int t = h; t < 256; t += 2)
    m = fmaxf(m, bf2f(zb[t*128]) * s + bb);
  __shared__ float red[256];
  red[tid] = m;
  __syncthreads();
  if (tid < 128)
    outp[(long)n*4096 + c*32 + 16 + v] = fmaxf(red[tid], red[tid+128]);
}

extern "C" void kernel_launch(void* const* d_in, const int* in_sizes, int n_in,
                              void* d_out, int out_size, void* d_ws, size_t ws_size,
                              hipStream_t stream) {
  (void)in_sizes; (void)n_in; (void)out_size; (void)ws_size;
  const float* x     = (const float*)d_in[0];
  const float* nv1   = (const float*)d_in[1];
  const float* nv2   = (const float*)d_in[2];
  const float* d1gw  = (const float*)d_in[3];
  const float* d1gb  = (const float*)d_in[4];
  const float* d1b1g = (const float*)d_in[5];
  const float* d1b1b = (const float*)d_in[6];
  const float* d1tw  = (const float*)d_in[7];
  // d_in[8] = d1tb: constant over BN axes -> cancels in following BN
  const float* d1b2g = (const float*)d_in[9];
  const float* d1b2b = (const float*)d_in[10];
  const float* d2gw  = (const float*)d_in[11];
  const float* d2gb  = (const float*)d_in[12];
  const float* d2b1g = (const float*)d_in[13];
  const float* d2b1b = (const float*)d_in[14];
  const float* d2tw  = (const float*)d_in[15];
  // d_in[16] = d2tb: cancels
  const float* d2b2g = (const float*)d_in[17];
  const float* d2b2b = (const float*)d_in[18];
  const float* s1pw  = (const float*)d_in[19];
  const float* s1pg  = (const float*)d_in[20];
  const float* s1pb  = (const float*)d_in[21];
  const float* s1tw  = (const float*)d_in[22];
  const float* s1tg  = (const float*)d_in[23];
  const float* s1tb  = (const float*)d_in[24];
  const float* s2pw  = (const float*)d_in[25];
  const float* s2pg  = (const float*)d_in[26];
  const float* s2pb  = (const float*)d_in[27];
  const float* s2tw  = (const float*)d_in[28];
  const float* s2tg  = (const float*)d_in[29];
  const float* s2tb  = (const float*)d_in[30];

  // ---- workspace: header + 3x64MB regions + part (round-6-proven footprint) ----
  float* W = (float*)d_ws;
  float* Am  = W;            // 256
  float* sAv = W + 256;      // 16
  float* scA = W + 512;  float* shA = W + 640;
  float* scB = W + 768;  float* shB = W + 896;
  float* scC = W + 1024; float* shC = W + 1152;
  float* scD = W + 1280; float* shD = W + 1408;
  float* scE = W + 1536; float* shE = W + 1664;
  float* scG = W + 1792; float* shG = W + 1920;
  float* scF = W + 2048; float* shF = W + 4096;   // 2048 each
  float* scH = W + 6144; float* shH = W + 8192;
  float* A = W + 16384;
  float* B = A + 16777216;
  float* C = B + 16777216;
  float* part = C + 16777216;                     // 2048*256 floats
  float* outp = (float*)d_out;

  // bf16 tensors occupy the LOWER half (8.4M floats) of each region
  unsigned short* A0 = (unsigned short*)A;
  unsigned short* B0 = (unsigned short*)B;
  unsigned short* C0 = (unsigned short*)C;
  // upper halves hold bf16 weights (never touched by tensors)
  unsigned short* w_d1g = (unsigned short*)(A + 8388608);        // 16384
  unsigned short* w_d1t = w_d1g + 16384;                         // 49152
  unsigned short* w_d2g = w_d1t + 49152;                         // 16384
  unsigned short* w_d2t = w_d2g + 16384;                         // 49152
  unsigned short* w_s1p = (unsigned short*)(C + 8388608);        // 16384
  unsigned short* w_s1t = (unsigned short*)(B + 8388608);        // 786432
  unsigned short* w_s2p = w_s1t + 786432;                        // 16384
  unsigned short* w_s2t = w_s2p + 16384;                         // 786432

  // ---- setup: adjacency + all weight converts ----
  k_adj<<<1, 256, 0, stream>>>(nv1, nv2, Am, sAv);
  k_cvt_cw<<<64, 256, 0, stream>>>(d1gw, w_d1g);
  k_cvt_tw<<<192, 256, 0, stream>>>(d1tw, w_d1t, 128);
  k_cvt_cw<<<64, 256, 0, stream>>>(d2gw, w_d2g);
  k_cvt_tw<<<192, 256, 0, stream>>>(d2tw, w_d2t, 128);
  k_cvt_cw<<<64, 256, 0, stream>>>(s1pw, w_s1p);
  k_cvt_tw<<<3072, 256, 0, stream>>>(s1tw, w_s1t, 2048);
  k_cvt_cw<<<64, 256, 0, stream>>>(s2pw, w_s2p);
  k_cvt_tw<<<3072, 256, 0, stream>>>(s2tw, w_s2t, 2048);

  // ======== dynamic branch ========
  k_aggX<<<2048, 256, 0, stream>>>(x, Am, B0);                        // B0 = agg(x) bf16
  k_conv<0,1,0,0,0,0,1><<<2048, 256, 0, stream>>>(B0, w_d1g, C0, 4096, nullptr, nullptr, d1gb, sAv, part);
  k_bnfin128<<<128, 256, 0, stream>>>(part, d1b1g, d1b1b, scA, shA, 1.f/131072.f);
  k_conv<16,3,0,1,0,1,0><<<2048, 256, 0, stream>>>(C0, w_d1t, B0, 4096, scA, shA, nullptr, nullptr, part);
  k_bnfin128<<<128, 256, 0, stream>>>(part, d1b2g, d1b2b, scB, shB, 1.f/131072.f);
  k_combineAgg<<<2048, 256, 0, stream>>>(B0, x, Am, scB, shB, A0, C0); // A0=r2, C0=agg(r2)
  k_conv<0,1,0,0,0,0,1><<<2048, 256, 0, stream>>>(C0, w_d2g, B0, 4096, nullptr, nullptr, d2gb, sAv, part);
  k_bnfin128<<<128, 256, 0, stream>>>(part, d2b1g, d2b1b, scC, shC, 1.f/131072.f);
  k_conv<16,3,0,1,0,1,0><<<2048, 256, 0, stream>>>(B0, w_d2t, C0, 4096, scC, shC, nullptr, nullptr, part);
  k_bnfin128<<<128, 256, 0, stream>>>(part, d2b2g, d2b2b, scD, shD, 1.f/131072.f);
  k_maxdyn<<<512, 256, 0, stream>>>(C0, A0, scD, shD, outp);          // d columns

  // ======== static branch ========
  k_xS<<<2048, 256, 0, stream>>>(x, B0);                              // B0 = xS bf16
  k_conv<0,1,0,0,0,0,0><<<2048, 256, 0, stream>>>(B0, w_s1p, A0, 256, nullptr, nullptr, nullptr, nullptr, part);
  k_bnfin128<<<128, 256, 0, stream>>>(part, s1pg, s1pb, scE, shE, 1.f/131072.f);
  k_conv<1,3,1,1,0,0,0><<<2048, 256, 0, stream>>>(A0, w_s1t, C0, 256, scE, shE, nullptr, nullptr, part);
  k_bnfin2048<<<2048, 64, 0, stream>>>(part, s1tg, s1tb, scF, shF, 1.f/8192.f);
  k_conv<0,1,0,1,1,0,0><<<2048, 256, 0, stream>>>(C0, w_s2p, A0, 256, scF, shF, nullptr, nullptr, part);
  k_bnfin128<<<128, 256, 0, stream>>>(part, s2pg, s2pb, scG, shG, 1.f/131072.f);
  k_conv<1,3,1,1,0,0,0><<<2048, 256, 0, stream>>>(A0, w_s2t, C0, 256, scG, shG, nullptr, nullptr, part);
  k_bnfin2048<<<2048, 64, 0, stream>>>(part, s2tg, s2tb, scH, shH, 1.f/8192.f);
  k_maxstat<<<512, 256, 0, stream>>>(C0, scH, shH, outp);             // s columns
}

// Round 8
// 382.081 us; speedup vs baseline: 6.9732x; 1.1720x over previous
//
#include <hip/hip_runtime.h>

#define EPSBN 1e-5f

typedef __attribute__((ext_vector_type(8))) __bf16 bf16x8;
typedef __attribute__((ext_vector_type(4))) float f32x4;
typedef __attribute__((ext_vector_type(8))) unsigned short us8;

__device__ inline unsigned short f2bf(float f) {
  unsigned u = __float_as_uint(f);
  u = (u + 0x7fffu + ((u >> 16) & 1u)) >> 16;
  return (unsigned short)u;
}
__device__ inline float bf2f(unsigned short h) {
  return __uint_as_float(((unsigned)h) << 16);
}

// ---------------- adjacency: A = adp(nv1,nv2), plus column sums sA ----------------
__global__ void k_adj(const float* __restrict__ nv1, const float* __restrict__ nv2,
                      float* __restrict__ A, float* __restrict__ sA) {
  __shared__ float M[16][16];
  int tid = threadIdx.x;
  int i = tid >> 4, j = tid & 15;
  float acc = 0.f;
  #pragma unroll
  for (int k = 0; k < 64; ++k) acc += nv1[i*64+k] * nv2[k*16+j];
  M[i][j] = fmaxf(acc, 0.f);
  __syncthreads();
  if (tid < 16) {
    float m = -1e30f;
    for (int c = 0; c < 16; ++c) m = fmaxf(m, M[tid][c]);
    float e[16]; float s = 0.f;
    for (int c = 0; c < 16; ++c) { e[c] = expf(M[tid][c] - m); s += e[c]; }
    float inv = 1.f / s;
    float t1 = -1e30f, t2 = -1e30f;
    for (int c = 0; c < 16; ++c) {
      float a = e[c] * inv; e[c] = a;
      if (a > t1) { t2 = t1; t1 = a; }
      else if (a > t2) t2 = a;
    }
    for (int c = 0; c < 16; ++c) {
      bool keep = (e[c] > (1.0f/16.0f)) && (e[c] > t2);
      M[tid][c] = keep ? e[c] : 0.f;
    }
  }
  __syncthreads();
  A[tid] = M[tid>>4][tid&15];
  if (tid < 16) {
    float s = 0.f;
    for (int v = 0; v < 16; ++v) s += M[v][tid];
    sA[tid] = s;
  }
}

// ---------------- weight converts to bf16 ----------------
__global__ __launch_bounds__(256) void k_cvt_cw(const float* __restrict__ w,
                                                unsigned short* __restrict__ o) {
  int idx = blockIdx.x*256 + threadIdx.x;
  if (idx < 16384) o[idx] = f2bf(w[idx]);
}
__global__ __launch_bounds__(256) void k_cvt_tw(const float* __restrict__ w,
                                                unsigned short* __restrict__ o, int nOut) {
  int idx = blockIdx.x*256 + threadIdx.x;
  if (idx >= nOut*384) return;
  int oo = idx / 384;
  int r = idx - oo*384;
  int tap = r >> 7, c = r & 127;
  o[idx] = f2bf(w[(oo*128 + c)*3 + tap]);
}

// ---------------- static: transpose x -> xS bf16 [(n,v)][t][c] ----------------
__global__ __launch_bounds__(256) void k_xS(const float* __restrict__ x,
                                            unsigned short* __restrict__ xS) {
  __shared__ float tl[64*128];
  int b = blockIdx.x; int n = b >> 6; int t0q = b & 63;
  int tid = threadIdx.x;
  const float* xb = x + (long)n*524288 + t0q*64;
  for (int idx = tid; idx < 2048; idx += 256) {
    int c = idx >> 4, q = idx & 15;
    float4 v = *(const float4*)(xb + (long)c*4096 + q*4);
    int cb = c >> 2, cl = c & 3;
    #pragma unroll
    for (int j = 0; j < 4; ++j)
      tl[(4*q+j)*128 + (((cb ^ q) & 31) << 2) + cl] = ((const float*)&v)[j];
  }
  __syncthreads();
  for (int idx = tid; idx < 2048; idx += 256) {
    int pos = idx >> 5, cblk = idx & 31;
    f32x4 v = *(const f32x4*)&tl[pos*128 + (((cblk ^ (pos >> 2)) & 31) << 2)];
    ushort4 pk;
    pk.x = f2bf(v.x); pk.y = f2bf(v.y); pk.z = f2bf(v.z); pk.w = f2bf(v.w);
    int vv = pos & 15, tt = pos >> 4;
    *(ushort4*)(xS + ((long)(n*16+vv)*256 + t0q*4 + tt)*128 + cblk*4) = pk;
  }
}

// ================= fused: agg(x) in LDS -> MFMA gconv -> z bf16 + BN partials =================
__global__ __launch_bounds__(256) void k_aggGconv(
    const float* __restrict__ x, const float* __restrict__ Am,
    const unsigned short* __restrict__ Wb,
    unsigned short* __restrict__ out,
    const float* __restrict__ gb, const float* __restrict__ sAv,
    float* __restrict__ part)
{
  __shared__ float tl[64*128];                          // x tile fp32, swizzled
  __shared__ __align__(16) unsigned short Th[64*128];   // agg bf16, conv-swizzled
  __shared__ float Asm[256];
  int b = blockIdx.x; int n = b >> 6; int off = (b & 63) << 6;
  int tid = threadIdx.x;
  Asm[tid] = Am[tid];
  const float* xb = x + (long)n*524288 + off;
  for (int idx = tid; idx < 2048; idx += 256) {
    int c = idx >> 4, q = idx & 15;
    float4 v = *(const float4*)(xb + (long)c*4096 + q*4);
    int cb = c >> 2, cl = c & 3;
    #pragma unroll
    for (int j = 0; j < 4; ++j)
      tl[(4*q+j)*128 + (((cb ^ q) & 31) << 2) + cl] = ((const float*)&v)[j];
  }
  __syncthreads();
  // agg -> Th (bf16, conv swizzle)
  for (int idx = tid; idx < 1024; idx += 256) {
    int pos = idx >> 4, c8 = (idx & 15) << 3;
    int tt = pos >> 4, w = pos & 15;
    int cb0 = c8 >> 2, cb1 = cb0 + 1;
    f32x4 s0 = {0.f,0.f,0.f,0.f}, s1 = {0.f,0.f,0.f,0.f};
    #pragma unroll
    for (int v = 0; v < 16; ++v) {
      int p = tt*16 + v;
      int sw = p >> 2;
      float a = Asm[v*16 + w];
      f32x4 x0 = *(const f32x4*)&tl[p*128 + (((cb0 ^ sw) & 31) << 2)];
      f32x4 x1 = *(const f32x4*)&tl[p*128 + (((cb1 ^ sw) & 31) << 2)];
      s0.x += a*x0.x; s0.y += a*x0.y; s0.z += a*x0.z; s0.w += a*x0.w;
      s1.x += a*x1.x; s1.y += a*x1.y; s1.z += a*x1.z; s1.w += a*x1.w;
    }
    us8 pk;
    pk[0]=f2bf(s0.x); pk[1]=f2bf(s0.y); pk[2]=f2bf(s0.z); pk[3]=f2bf(s0.w);
    pk[4]=f2bf(s1.x); pk[5]=f2bf(s1.y); pk[6]=f2bf(s1.z); pk[7]=f2bf(s1.w);
    int byteoff = (pos << 8) + (c8 << 1);
    byteoff ^= ((pos & 7) << 4);
    *(us8*)((char*)Th + byteoff) = pk;
  }
  __syncthreads();
  // gconv MFMA (TAPS=1, HALO=0, 64 pos)
  int wv = tid >> 6, lane = tid & 63, l15 = lane & 15, lhi = lane >> 4;
  int o0 = wv << 5;
  f32x4 zz = {0.f,0.f,0.f,0.f};
  f32x4 acc[2][4];
  #pragma unroll
  for (int i = 0; i < 2; ++i)
    #pragma unroll
    for (int q = 0; q < 4; ++q) acc[i][q] = zz;
  const unsigned short* wr0 = Wb + (long)(o0 + l15)*128 + lhi*8;
  const unsigned short* wr1 = wr0 + 16*128;
  #pragma unroll
  for (int kk = 0; kk < 4; ++kk) {
    int kc = kk*32 + lhi*8;
    bf16x8 a0 = *(const bf16x8*)(wr0 + kk*32);
    bf16x8 a1 = *(const bf16x8*)(wr1 + kk*32);
    #pragma unroll
    for (int pf = 0; pf < 4; ++pf) {
      int row = pf*16 + l15;
      int byteoff = (row << 8) + (kc << 1);
      byteoff ^= ((row & 7) << 4);
      bf16x8 bh = *(const bf16x8*)((const char*)Th + byteoff);
      acc[0][pf] = __builtin_amdgcn_mfma_f32_16x16x32_bf16(a0, bh, acc[0][pf], 0, 0, 0);
      acc[1][pf] = __builtin_amdgcn_mfma_f32_16x16x32_bf16(a1, bh, acc[1][pf], 0, 0, 0);
    }
  }
  // epilogue: bias + bf16 store + BN partials
  float s1a[2][4], s2a[2][4];
  #pragma unroll
  for (int i = 0; i < 2; ++i)
    #pragma unroll
    for (int j = 0; j < 4; ++j) { s1a[i][j] = 0.f; s2a[i][j] = 0.f; }
  unsigned short* og = out + ((long)n*4096 + off)*128;
  #pragma unroll
  for (int of = 0; of < 2; ++of) {
    int oc = o0 + of*16 + lhi*4;
    #pragma unroll
    for (int pf = 0; pf < 4; ++pf) {
      int pos = pf*16 + l15;
      f32x4 r = acc[of][pf];
      float s = sAv[l15];
      r.x += gb[oc+0]*s; r.y += gb[oc+1]*s;
      r.z += gb[oc+2]*s; r.w += gb[oc+3]*s;
      ushort4 pk;
      pk.x = f2bf(r.x); pk.y = f2bf(r.y); pk.z = f2bf(r.z); pk.w = f2bf(r.w);
      *(ushort4*)(og + (long)pos*128 + oc) = pk;
      #pragma unroll
      for (int j = 0; j < 4; ++j) { s1a[of][j] += r[j]; s2a[of][j] += r[j]*r[j]; }
    }
  }
  #pragma unroll
  for (int of = 0; of < 2; ++of)
    #pragma unroll
    for (int j = 0; j < 4; ++j) {
      float a = s1a[of][j], b2 = s2a[of][j];
      #pragma unroll
      for (int m = 1; m < 16; m <<= 1) { a += __shfl_xor(a, m); b2 += __shfl_xor(b2, m); }
      s1a[of][j] = a; s2a[of][j] = b2;
    }
  float* red = tl;   // tl reads finished before MFMA barrier
  if (l15 == 0) {
    #pragma unroll
    for (int of = 0; of < 2; ++of)
      #pragma unroll
      for (int j = 0; j < 4; ++j) {
        int ch = o0 + of*16 + lhi*4 + j;
        red[ch] = s1a[of][j];
        red[128 + ch] = s2a[of][j];
      }
  }
  __syncthreads();
  part[(long)blockIdx.x*256 + tid] = red[tid];
}

// ================= fused: r2=relu(bn(z2)+x) -> bf16 + agg(r2) in LDS -> MFMA gconv -> z3 =================
__global__ __launch_bounds__(256) void k_combineAggGconv(
    const unsigned short* __restrict__ z, const float* __restrict__ x,
    const float* __restrict__ Am,
    const float* __restrict__ sc, const float* __restrict__ sh,
    const unsigned short* __restrict__ Wb,
    unsigned short* __restrict__ r2, unsigned short* __restrict__ out,
    const float* __restrict__ gb, const float* __restrict__ sAv,
    float* __restrict__ part)
{
  __shared__ float rl[64*128];                          // r2 fp32, swizzled
  __shared__ __align__(16) unsigned short Th[64*128];   // agg bf16, conv-swizzled
  __shared__ float Asm[256];
  int b = blockIdx.x; int n = b >> 6; int off = (b & 63) << 6;
  int tid = threadIdx.x;
  Asm[tid] = Am[tid];
  long zbase = (long)b * 8192;
  // phase 1: bn(z2) -> rl
  for (int idx = tid; idx < 1024; idx += 256) {
    int pos = idx >> 4, c8 = (idx & 15) << 3;
    us8 raw = *(const us8*)(z + zbase + (long)pos*128 + c8);
    int qp = pos >> 2;
    #pragma unroll
    for (int half = 0; half < 2; ++half) {
      f32x4 f;
      #pragma unroll
      for (int j = 0; j < 4; ++j) {
        int cc = c8 + half*4 + j;
        f[j] = bf2f(raw[half*4+j]) * sc[cc] + sh[cc];
      }
      int cblk = (c8 >> 2) + half;
      *(f32x4*)&rl[pos*128 + (((cblk ^ qp) & 31) << 2)] = f;
    }
  }
  __syncthreads();
  // phase 2: + residual x, relu
  const float* xb = x + (long)n*524288 + off;
  for (int idx = tid; idx < 2048; idx += 256) {
    int c = idx >> 4, q = idx & 15;
    float4 v = *(const float4*)(xb + (long)c*4096 + q*4);
    int cb = c >> 2, cl = c & 3;
    #pragma unroll
    for (int j = 0; j < 4; ++j) {
      int a = (4*q+j)*128 + (((cb ^ q) & 31) << 2) + cl;
      rl[a] = fmaxf(rl[a] + ((const float*)&v)[j], 0.f);
    }
  }
  __syncthreads();
  // phase 3: write r2 bf16 + agg -> Th
  for (int idx = tid; idx < 1024; idx += 256) {
    int pos = idx >> 4, c8 = (idx & 15) << 3;
    int cb0 = c8 >> 2, cb1 = cb0 + 1;
    int qp = pos >> 2;
    f32x4 r0 = *(const f32x4*)&rl[pos*128 + (((cb0 ^ qp) & 31) << 2)];
    f32x4 r1 = *(const f32x4*)&rl[pos*128 + (((cb1 ^ qp) & 31) << 2)];
    us8 pr;
    pr[0]=f2bf(r0.x); pr[1]=f2bf(r0.y); pr[2]=f2bf(r0.z); pr[3]=f2bf(r0.w);
    pr[4]=f2bf(r1.x); pr[5]=f2bf(r1.y); pr[6]=f2bf(r1.z); pr[7]=f2bf(r1.w);
    *(us8*)(r2 + zbase + (long)pos*128 + c8) = pr;
    int tt = pos >> 4, w = pos & 15;
    f32x4 s0 = {0.f,0.f,0.f,0.f}, s1 = {0.f,0.f,0.f,0.f};
    #pragma unroll
    for (int v = 0; v < 16; ++v) {
      int p = tt*16 + v;
      int sw = p >> 2;
      float a = Asm[v*16 + w];
      f32x4 x0 = *(const f32x4*)&rl[p*128 + (((cb0 ^ sw) & 31) << 2)];
      f32x4 x1 = *(const f32x4*)&rl[p*128 + (((cb1 ^ sw) & 31) << 2)];
      s0.x += a*x0.x; s0.y += a*x0.y; s0.z += a*x0.z; s0.w += a*x0.w;
      s1.x += a*x1.x; s1.y += a*x1.y; s1.z += a*x1.z; s1.w += a*x1.w;
    }
    us8 pk;
    pk[0]=f2bf(s0.x); pk[1]=f2bf(s0.y); pk[2]=f2bf(s0.z); pk[3]=f2bf(s0.w);
    pk[4]=f2bf(s1.x); pk[5]=f2bf(s1.y); pk[6]=f2bf(s1.z); pk[7]=f2bf(s1.w);
    int byteoff = (pos << 8) + (c8 << 1);
    byteoff ^= ((pos & 7) << 4);
    *(us8*)((char*)Th + byteoff) = pk;
  }
  __syncthreads();
  // gconv2 MFMA
  int wv = tid >> 6, lane = tid & 63, l15 = lane & 15, lhi = lane >> 4;
  int o0 = wv << 5;
  f32x4 zz = {0.f,0.f,0.f,0.f};
  f32x4 acc[2][4];
  #pragma unroll
  for (int i = 0; i < 2; ++i)
    #pragma unroll
    for (int q = 0; q < 4; ++q) acc[i][q] = zz;
  const unsigned short* wr0 = Wb + (long)(o0 + l15)*128 + lhi*8;
  const unsigned short* wr1 = wr0 + 16*128;
  #pragma unroll
  for (int kk = 0; kk < 4; ++kk) {
    int kc = kk*32 + lhi*8;
    bf16x8 a0 = *(const bf16x8*)(wr0 + kk*32);
    bf16x8 a1 = *(const bf16x8*)(wr1 + kk*32);
    #pragma unroll
    for (int pf = 0; pf < 4; ++pf) {
      int row = pf*16 + l15;
      int byteoff = (row << 8) + (kc << 1);
      byteoff ^= ((row & 7) << 4);
      bf16x8 bh = *(const bf16x8*)((const char*)Th + byteoff);
      acc[0][pf] = __builtin_amdgcn_mfma_f32_16x16x32_bf16(a0, bh, acc[0][pf], 0, 0, 0);
      acc[1][pf] = __builtin_amdgcn_mfma_f32_16x16x32_bf16(a1, bh, acc[1][pf], 0, 0, 0);
    }
  }
  float s1a[2][4], s2a[2][4];
  #pragma unroll
  for (int i = 0; i < 2; ++i)
    #pragma unroll
    for (int j = 0; j < 4; ++j) { s1a[i][j] = 0.f; s2a[i][j] = 0.f; }
  unsigned short* og = out + zbase;
  #pragma unroll
  for (int of = 0; of < 2; ++of) {
    int oc = o0 + of*16 + lhi*4;
    #pragma unroll
    for (int pf = 0; pf < 4; ++pf) {
      int pos = pf*16 + l15;
      f32x4 r = acc[of][pf];
      float s = sAv[l15];
      r.x += gb[oc+0]*s; r.y += gb[oc+1]*s;
      r.z += gb[oc+2]*s; r.w += gb[oc+3]*s;
      ushort4 pk;
      pk.x = f2bf(r.x); pk.y = f2bf(r.y); pk.z = f2bf(r.z); pk.w = f2bf(r.w);
      *(ushort4*)(og + (long)pos*128 + oc) = pk;
      #pragma unroll
      for (int j = 0; j < 4; ++j) { s1a[of][j] += r[j]; s2a[of][j] += r[j]*r[j]; }
    }
  }
  #pragma unroll
  for (int of = 0; of < 2; ++of)
    #pragma unroll
    for (int j = 0; j < 4; ++j) {
      float a = s1a[of][j], b2 = s2a[of][j];
      #pragma unroll
      for (int m = 1; m < 16; m <<= 1) { a += __shfl_xor(a, m); b2 += __shfl_xor(b2, m); }
      s1a[of][j] = a; s2a[of][j] = b2;
    }
  float* red = rl;
  __syncthreads();                 // rl still read in phase-3 agg by other waves
  if (l15 == 0) {
    #pragma unroll
    for (int of = 0; of < 2; ++of)
      #pragma unroll
      for (int j = 0; j < 4; ++j) {
        int ch = o0 + of*16 + lhi*4 + j;
        red[ch] = s1a[of][j];
        red[128 + ch] = s2a[of][j];
      }
  }
  __syncthreads();
  part[(long)blockIdx.x*256 + tid] = red[tid];
}

// ================= MFMA conv, bf16 in/out, POSB-wide tiles, fused BN partials =================
template<int POSB, int HALO, int TAPS, int GROUPED_W, int IN_BN, int GROUPED_BN, int RELU_IN>
__global__ __launch_bounds__(256) void k_conv(
    const unsigned short* __restrict__ in, const unsigned short* __restrict__ Wb,
    unsigned short* __restrict__ out, int L,
    const float* __restrict__ isc, const float* __restrict__ ish,
    float* __restrict__ part)
{
  constexpr int TW = POSB + 2*HALO;
  constexpr int PF = POSB / 16;
  constexpr int KT = TAPS*128;
  __shared__ __align__(16) unsigned short Th[TW*128];
  int tid = threadIdx.x;
  int bpg = L / POSB;
  int g = blockIdx.x / bpg;
  int pos0 = (blockIdx.x - g*bpg) * POSB;
  const unsigned short* ing = in + (long)g*L*128;

  int cbase = (IN_BN && GROUPED_BN) ? ((g & 15) << 7) : 0;
  for (int idx = tid; idx < TW*16; idx += 256) {
    int row = idx >> 4;
    int c8 = (idx & 15) << 3;
    int gp = pos0 + row - HALO;
    us8 h = (us8)0;
    if (gp >= 0 && gp < L) {
      us8 raw = *(const us8*)(ing + (long)gp*128 + c8);
      if (IN_BN) {
        #pragma unroll
        for (int j = 0; j < 8; ++j) {
          int ci = cbase + c8 + j;
          float v = bf2f(raw[j]) * isc[ci] + ish[ci];
          if (RELU_IN) v = fmaxf(v, 0.f);
          h[j] = f2bf(v);
        }
      } else {
        h = raw;
      }
    }
    int byteoff = (row << 8) + (c8 << 1);
    byteoff ^= ((row & 7) << 4);
    *(us8*)((char*)Th + byteoff) = h;
  }
  __syncthreads();

  int wv = tid >> 6, lane = tid & 63, l15 = lane & 15, lhi = lane >> 4;
  int o0 = wv << 5;

  f32x4 zz = {0.f,0.f,0.f,0.f};
  f32x4 acc[2][PF];
  #pragma unroll
  for (int i = 0; i < 2; ++i)
    #pragma unroll
    for (int q = 0; q < PF; ++q) acc[i][q] = zz;

  const unsigned short* Wg = Wb + (GROUPED_W ? (long)(g & 15)*128*KT : 0);
  const unsigned short* wr0 = Wg + (long)(o0 + l15)*KT + lhi*8;
  const unsigned short* wr1 = wr0 + 16*KT;

  #pragma unroll
  for (int tap = 0; tap < TAPS; ++tap) {
    #pragma unroll
    for (int kk = 0; kk < 4; ++kk) {
      int kc = kk*32 + lhi*8;
      bf16x8 a0 = *(const bf16x8*)(wr0 + tap*128 + kk*32);
      bf16x8 a1 = *(const bf16x8*)(wr1 + tap*128 + kk*32);
      #pragma unroll
      for (int pf = 0; pf < PF; ++pf) {
        int row = pf*16 + l15 + tap*HALO;
        int byteoff = (row << 8) + (kc << 1);
        byteoff ^= ((row & 7) << 4);
        bf16x8 bh = *(const bf16x8*)((const char*)Th + byteoff);
        acc[0][pf] = __builtin_amdgcn_mfma_f32_16x16x32_bf16(a0, bh, acc[0][pf], 0, 0, 0);
        acc[1][pf] = __builtin_amdgcn_mfma_f32_16x16x32_bf16(a1, bh, acc[1][pf], 0, 0, 0);
      }
    }
  }

  float s1a[2][4], s2a[2][4];
  #pragma unroll
  for (int i = 0; i < 2; ++i)
    #pragma unroll
    for (int j = 0; j < 4; ++j) { s1a[i][j] = 0.f; s2a[i][j] = 0.f; }

  unsigned short* og = out + ((long)g*L + pos0)*128;
  #pragma unroll
  for (int of = 0; of < 2; ++of) {
    int oc = o0 + of*16 + lhi*4;
    #pragma unroll
    for (int pf = 0; pf < PF; ++pf) {
      int pos = pf*16 + l15;
      f32x4 r = acc[of][pf];
      ushort4 pk;
      pk.x = f2bf(r.x); pk.y = f2bf(r.y); pk.z = f2bf(r.z); pk.w = f2bf(r.w);
      *(ushort4*)(og + (long)pos*128 + oc) = pk;
      #pragma unroll
      for (int j = 0; j < 4; ++j) { s1a[of][j] += r[j]; s2a[of][j] += r[j]*r[j]; }
    }
  }
  #pragma unroll
  for (int of = 0; of < 2; ++of)
    #pragma unroll
    for (int j = 0; j < 4; ++j) {
      float a = s1a[of][j], b2 = s2a[of][j];
      #pragma unroll
      for (int m = 1; m < 16; m <<= 1) { a += __shfl_xor(a, m); b2 += __shfl_xor(b2, m); }
      s1a[of][j] = a; s2a[of][j] = b2;
    }
  __syncthreads();                 // waves must finish reading Th
  float* red = (float*)Th;
  if (l15 == 0) {
    #pragma unroll
    for (int of = 0; of < 2; ++of)
      #pragma unroll
      for (int j = 0; j < 4; ++j) {
        int ch = o0 + of*16 + lhi*4 + j;
        red[ch] = s1a[of][j];
        red[128 + ch] = s2a[of][j];
      }
  }
  __syncthreads();
  part[(long)blockIdx.x*256 + tid] = red[tid];
}

// ---------------- BN finalize: 128 channels, nblk block-partials ----------------
__global__ __launch_bounds__(256) void k_bnfin128(const float* __restrict__ part,
                           const float* __restrict__ gamma, const float* __restrict__ beta,
                           float* __restrict__ sc, float* __restrict__ sh,
                           float invN, int nblk) {
  int c = blockIdx.x, tid = threadIdx.x;
  float s1 = 0.f, s2 = 0.f;
  for (int b = tid; b < nblk; b += 256) {
    s1 += part[b*256 + c];
    s2 += part[b*256 + 128 + c];
  }
  __shared__ float l1[256], l2[256];
  l1[tid] = s1; l2[tid] = s2;
  __syncthreads();
  for (int st = 128; st > 0; st >>= 1) {
    if (tid < st) { l1[tid] += l1[tid+st]; l2[tid] += l2[tid+st]; }
    __syncthreads();
  }
  if (tid == 0) {
    float mean = l1[0]*invN;
    float var  = l2[0]*invN - mean*mean;
    float s = gamma[c] * rsqrtf(var + EPSBN);
    sc[c] = s;
    sh[c] = beta[c] - mean*s;
  }
}

// ---------------- BN finalize: 2048 (v,c) channels; 2 blocks per g, g=n*16+v ----------------
__global__ void k_bnfin2048(const float* __restrict__ part,
                            const float* __restrict__ gamma, const float* __restrict__ beta,
                            float* __restrict__ sc, float* __restrict__ sh, float invN) {
  int ch = blockIdx.x; int v = ch >> 7, c = ch & 127;
  int lane = threadIdx.x;          // 64 = 32 n x 2 bp
  int n = lane >> 1, bp = lane & 1;
  int blk = ((n*16 + v) << 1) + bp;
  float s1 = part[blk*256 + c];
  float s2 = part[blk*256 + 128 + c];
  for (int m = 32; m > 0; m >>= 1) { s1 += __shfl_down(s1, m); s2 += __shfl_down(s2, m); }
  if (lane == 0) {
    float mean = s1*invN;
    float var  = s2*invN - mean*mean;
    float s = gamma[ch] * rsqrtf(var + EPSBN);
    sc[ch] = s;
    sh[ch] = beta[ch] - mean*s;
  }
}

// ---------------- dynamic tail: out[n,c,v] = max_t relu(bn(z)+r2), bf16 inputs ----------------
__global__ __launch_bounds__(256) void k_maxdyn(
    const unsigned short* __restrict__ z, const unsigned short* __restrict__ res,
    const float* __restrict__ sc, const float* __restrict__ sh,
    float* __restrict__ outp)
{
  int b = blockIdx.x; int n = b >> 4, v = b & 15;
  int tid = threadIdx.x; int c = tid & 127, h = tid >> 7;
  const unsigned short* zb = z   + ((long)n*4096 + v)*128 + c;
  const unsigned short* rb = res + ((long)n*4096 + v)*128 + c;
  float s = sc[c], bb = sh[c];
  float m = 0.f;
  for (int t = h; t < 256; t += 2) {
    float val = bf2f(zb[(long)t*2048]) * s + bb + bf2f(rb[(long)t*2048]);
    m = fmaxf(m, val);
  }
  __shared__ float red[256];
  red[tid] = m;
  __syncthreads();
  if (tid < 128)
    outp[(long)n*4096 + c*32 + v] = fmaxf(fmaxf(red[tid], red[tid+128]), 0.f);
}

// ---------------- static tail: out[n,c,16+v] = max_s bn(z[(n,v)][s][c]), bf16 ----------------
__global__ __launch_bounds__(256) void k_maxstat(
    const unsigned short* __restrict__ z,
    const float* __restrict__ sc, const float* __restrict__ sh,
    float* __restrict__ outp)
{
  int b = blockIdx.x; int n = b >> 4, v = b & 15;
  int tid = threadIdx.x; int c = tid & 127, h = tid >> 7;
  const unsigned short* zb = z + (long)b*256*128 + c;
  float s = sc[v*128 + c], bb = sh[v*128 + c];
  float m = -1e30f;
  for (int t = h; t < 256; t += 2)
    m = fmaxf(m, bf2f(zb[t*128]) * s + bb);
  __shared__ float red[256];
  red[tid] = m;
  __syncthreads();
  if (tid < 128)
    outp[(long)n*4096 + c*32 + 16 + v] = fmaxf(red[tid], red[tid+128]);
}

extern "C" void kernel_launch(void* const* d_in, const int* in_sizes, int n_in,
                              void* d_out, int out_size, void* d_ws, size_t ws_size,
                              hipStream_t stream) {
  (void)in_sizes; (void)n_in; (void)out_size; (void)ws_size;
  const float* x     = (const float*)d_in[0];
  const float* nv1   = (const float*)d_in[1];
  const float* nv2   = (const float*)d_in[2];
  const float* d1gw  = (const float*)d_in[3];
  const float* d1gb  = (const float*)d_in[4];
  const float* d1b1g = (const float*)d_in[5];
  const float* d1b1b = (const float*)d_in[6];
  const float* d1tw  = (const float*)d_in[7];
  const float* d1b2g = (const float*)d_in[9];
  const float* d1b2b = (const float*)d_in[10];
  const float* d2gw  = (const float*)d_in[11];
  const float* d2gb  = (const float*)d_in[12];
  const float* d2b1g = (const float*)d_in[13];
  const float* d2b1b = (const float*)d_in[14];
  const float* d2tw  = (const float*)d_in[15];
  const float* d2b2g = (const float*)d_in[17];
  const float* d2b2b = (const float*)d_in[18];
  const float* s1pw  = (const float*)d_in[19];
  const float* s1pg  = (const float*)d_in[20];
  const float* s1pb  = (const float*)d_in[21];
  const float* s1tw  = (const float*)d_in[22];
  const float* s1tg  = (const float*)d_in[23];
  const float* s1tb  = (const float*)d_in[24];
  const float* s2pw  = (const float*)d_in[25];
  const float* s2pg  = (const float*)d_in[26];
  const float* s2pb  = (const float*)d_in[27];
  const float* s2tw  = (const float*)d_in[28];
  const float* s2tg  = (const float*)d_in[29];
  const float* s2tb  = (const float*)d_in[30];

  float* W = (float*)d_ws;
  float* Am  = W;            // 256
  float* sAv = W + 256;      // 16
  float* scA = W + 512;  float* shA = W + 640;
  float* scB = W + 768;  float* shB = W + 896;
  float* scC = W + 1024; float* shC = W + 1152;
  float* scD = W + 1280; float* shD = W + 1408;
  float* scE = W + 1536; float* shE = W + 1664;
  float* scG = W + 1792; float* shG = W + 1920;
  float* scF = W + 2048; float* shF = W + 4096;   // 2048 each
  float* scH = W + 6144; float* shH = W + 8192;
  float* A = W + 16384;
  float* B = A + 16777216;
  float* C = B + 16777216;
  float* part = C + 16777216;                     // up to 2048*256 floats
  float* outp = (float*)d_out;

  unsigned short* A0 = (unsigned short*)A;
  unsigned short* B0 = (unsigned short*)B;
  unsigned short* C0 = (unsigned short*)C;
  unsigned short* w_d1g = (unsigned short*)(A + 8388608);
  unsigned short* w_d1t = w_d1g + 16384;
  unsigned short* w_d2g = w_d1t + 49152;
  unsigned short* w_d2t = w_d2g + 16384;
  unsigned short* w_s1p = (unsigned short*)(C + 8388608);
  unsigned short* w_s1t = (unsigned short*)(B + 8388608);
  unsigned short* w_s2p = w_s1t + 786432;
  unsigned short* w_s2t = w_s2p + 16384;

  // ---- setup ----
  k_adj<<<1, 256, 0, stream>>>(nv1, nv2, Am, sAv);
  k_cvt_cw<<<64, 256, 0, stream>>>(d1gw, w_d1g);
  k_cvt_tw<<<192, 256, 0, stream>>>(d1tw, w_d1t, 128);
  k_cvt_cw<<<64, 256, 0, stream>>>(d2gw, w_d2g);
  k_cvt_tw<<<192, 256, 0, stream>>>(d2tw, w_d2t, 128);
  k_cvt_cw<<<64, 256, 0, stream>>>(s1pw, w_s1p);
  k_cvt_tw<<<3072, 256, 0, stream>>>(s1tw, w_s1t, 2048);
  k_cvt_cw<<<64, 256, 0, stream>>>(s2pw, w_s2p);
  k_cvt_tw<<<3072, 256, 0, stream>>>(s2tw, w_s2t, 2048);

  // ======== dynamic branch ========
  k_aggGconv<<<2048, 256, 0, stream>>>(x, Am, w_d1g, B0, d1gb, sAv, part);      // B0 = z1
  k_bnfin128<<<128, 256, 0, stream>>>(part, d1b1g, d1b1b, scA, shA, 1.f/131072.f, 2048);
  k_conv<128,16,3,0,1,0,1><<<1024, 256, 0, stream>>>(B0, w_d1t, C0, 4096, scA, shA, part);  // C0 = z2
  k_bnfin128<<<128, 256, 0, stream>>>(part, d1b2g, d1b2b, scB, shB, 1.f/131072.f, 1024);
  k_combineAggGconv<<<2048, 256, 0, stream>>>(C0, x, Am, scB, shB, w_d2g, A0, B0, d2gb, sAv, part); // A0=r2, B0=z3
  k_bnfin128<<<128, 256, 0, stream>>>(part, d2b1g, d2b1b, scC, shC, 1.f/131072.f, 2048);
  k_conv<128,16,3,0,1,0,1><<<1024, 256, 0, stream>>>(B0, w_d2t, C0, 4096, scC, shC, part);  // C0 = z4
  k_bnfin128<<<128, 256, 0, stream>>>(part, d2b2g, d2b2b, scD, shD, 1.f/131072.f, 1024);
  k_maxdyn<<<512, 256, 0, stream>>>(C0, A0, scD, shD, outp);

  // ======== static branch ========
  k_xS<<<2048, 256, 0, stream>>>(x, B0);                                        // B0 = xS
  k_conv<128,0,1,0,0,0,0><<<1024, 256, 0, stream>>>(B0, w_s1p, A0, 256, nullptr, nullptr, part);
  k_bnfin128<<<128, 256, 0, stream>>>(part, s1pg, s1pb, scE, shE, 1.f/131072.f, 1024);
  k_conv<128,1,3,1,1,0,0><<<1024, 256, 0, stream>>>(A0, w_s1t, C0, 256, scE, shE, part);
  k_bnfin2048<<<2048, 64, 0, stream>>>(part, s1tg, s1tb, scF, shF, 1.f/8192.f);
  k_conv<128,0,1,0,1,1,0><<<1024, 256, 0, stream>>>(C0, w_s2p, A0, 256, scF, shF, part);
  k_bnfin128<<<128, 256, 0, stream>>>(part, s2pg, s2pb, scG, shG, 1.f/131072.f, 1024);
  k_conv<128,1,3,1,1,0,0><<<1024, 256, 0, stream>>>(A0, w_s2t, C0, 256, scG, shG, part);
  k_bnfin2048<<<2048, 64, 0, stream>>>(part, s2tg, s2tb, scH, shH, 1.f/8192.f);
  k_maxstat<<<512, 256, 0, stream>>>(C0, scH, shH, outp);
}

// Round 9
// 372.334 us; speedup vs baseline: 7.1558x; 1.0262x over previous
//
#include <hip/hip_runtime.h>

#define EPSBN 1e-5f

typedef __attribute__((ext_vector_type(8))) __bf16 bf16x8;
typedef __attribute__((ext_vector_type(4))) float f32x4;
typedef __attribute__((ext_vector_type(8))) unsigned short us8;

__device__ inline unsigned short f2bf(float f) {
  unsigned u = __float_as_uint(f);
  u = (u + 0x7fffu + ((u >> 16) & 1u)) >> 16;
  return (unsigned short)u;
}
__device__ inline float bf2f(unsigned short h) {
  return __uint_as_float(((unsigned)h) << 16);
}

// ---------------- adjacency: A = adp(nv1,nv2); column sums sA; per-column sparse lists ----------------
__global__ void k_adj(const float* __restrict__ nv1, const float* __restrict__ nv2,
                      float* __restrict__ A, float* __restrict__ sA,
                      int* __restrict__ cntA, int* __restrict__ lvA, float* __restrict__ lvalA) {
  __shared__ float M[16][16];
  int tid = threadIdx.x;
  int i = tid >> 4, j = tid & 15;
  float acc = 0.f;
  #pragma unroll
  for (int k = 0; k < 64; ++k) acc += nv1[i*64+k] * nv2[k*16+j];
  M[i][j] = fmaxf(acc, 0.f);
  __syncthreads();
  if (tid < 16) {
    float m = -1e30f;
    for (int c = 0; c < 16; ++c) m = fmaxf(m, M[tid][c]);
    float e[16]; float s = 0.f;
    for (int c = 0; c < 16; ++c) { e[c] = expf(M[tid][c] - m); s += e[c]; }
    float inv = 1.f / s;
    float t1 = -1e30f, t2 = -1e30f;
    for (int c = 0; c < 16; ++c) {
      float a = e[c] * inv; e[c] = a;
      if (a > t1) { t2 = t1; t1 = a; }
      else if (a > t2) t2 = a;
    }
    for (int c = 0; c < 16; ++c) {
      bool keep = (e[c] > (1.0f/16.0f)) && (e[c] > t2);
      M[tid][c] = keep ? e[c] : 0.f;
    }
  }
  __syncthreads();
  A[tid] = M[tid>>4][tid&15];
  if (tid < 16) {           // tid = w (column)
    float s = 0.f;
    int cnt = 0;
    for (int v = 0; v < 16; ++v) {
      float a = M[v][tid];
      s += a;
      if (a != 0.f) { lvA[tid*16 + cnt] = v; lvalA[tid*16 + cnt] = a; ++cnt; }
    }
    sA[tid] = s;
    cntA[tid] = cnt;
  }
}

// ---------------- weight converts to bf16 ----------------
__global__ __launch_bounds__(256) void k_cvt_cw(const float* __restrict__ w,
                                                unsigned short* __restrict__ o) {
  int idx = blockIdx.x*256 + threadIdx.x;
  if (idx < 16384) o[idx] = f2bf(w[idx]);
}
__global__ __launch_bounds__(256) void k_cvt_tw(const float* __restrict__ w,
                                                unsigned short* __restrict__ o, int nOut) {
  int idx = blockIdx.x*256 + threadIdx.x;
  if (idx >= nOut*384) return;
  int oo = idx / 384;
  int r = idx - oo*384;
  int tap = r >> 7, c = r & 127;
  o[idx] = f2bf(w[(oo*128 + c)*3 + tap]);
}

// ---------------- static: transpose x -> xS bf16 [(n,v)][t][c] ----------------
__global__ __launch_bounds__(256) void k_xS(const float* __restrict__ x,
                                            unsigned short* __restrict__ xS) {
  __shared__ float tl[64*128];
  int b = blockIdx.x; int n = b >> 6; int t0q = b & 63;
  int tid = threadIdx.x;
  const float* xb = x + (long)n*524288 + t0q*64;
  for (int idx = tid; idx < 2048; idx += 256) {
    int c = idx >> 4, q = idx & 15;
    float4 v = *(const float4*)(xb + (long)c*4096 + q*4);
    int cb = c >> 2, cl = c & 3;
    #pragma unroll
    for (int j = 0; j < 4; ++j)
      tl[(4*q+j)*128 + (((cb ^ q) & 31) << 2) + cl] = ((const float*)&v)[j];
  }
  __syncthreads();
  for (int idx = tid; idx < 2048; idx += 256) {
    int pos = idx >> 5, cblk = idx & 31;
    f32x4 v = *(const f32x4*)&tl[pos*128 + (((cblk ^ (pos >> 2)) & 31) << 2)];
    ushort4 pk;
    pk.x = f2bf(v.x); pk.y = f2bf(v.y); pk.z = f2bf(v.z); pk.w = f2bf(v.w);
    int vv = pos & 15, tt = pos >> 4;
    *(ushort4*)(xS + ((long)(n*16+vv)*256 + t0q*4 + tt)*128 + cblk*4) = pk;
  }
}

// ================= fused: sparse-agg(x) in LDS -> MFMA gconv -> z bf16 + BN partials =================
__global__ __launch_bounds__(256) void k_aggGconv(
    const float* __restrict__ x,
    const int* __restrict__ cntA, const int* __restrict__ lvA, const float* __restrict__ lvalA,
    const unsigned short* __restrict__ Wb,
    unsigned short* __restrict__ out,
    const float* __restrict__ gb, const float* __restrict__ sAv,
    float* __restrict__ part)
{
  __shared__ float tl[64*128];                          // x tile fp32, swizzled
  __shared__ __align__(16) unsigned short Th[64*128];   // agg bf16, conv-swizzled
  __shared__ int cntS[16];
  __shared__ int lvS[256];
  __shared__ float lvalS[256];
  int b = blockIdx.x; int n = b >> 6; int off = (b & 63) << 6;
  int tid = threadIdx.x;
  if (tid < 16) cntS[tid] = cntA[tid];
  lvS[tid] = lvA[tid];
  lvalS[tid] = lvalA[tid];
  const float* xb = x + (long)n*524288 + off;
  for (int idx = tid; idx < 2048; idx += 256) {
    int c = idx >> 4, q = idx & 15;
    float4 v = *(const float4*)(xb + (long)c*4096 + q*4);
    int cb = c >> 2, cl = c & 3;
    #pragma unroll
    for (int j = 0; j < 4; ++j)
      tl[(4*q+j)*128 + (((cb ^ q) & 31) << 2) + cl] = ((const float*)&v)[j];
  }
  __syncthreads();
  // sparse agg -> Th (bf16, conv swizzle)
  for (int idx = tid; idx < 1024; idx += 256) {
    int pos = idx >> 4, c8 = (idx & 15) << 3;
    int tt = pos >> 4, w = pos & 15;
    int cb0 = c8 >> 2, cb1 = cb0 + 1;
    f32x4 s0 = {0.f,0.f,0.f,0.f}, s1 = {0.f,0.f,0.f,0.f};
    int cw = cntS[w];
    for (int j = 0; j < cw; ++j) {
      int p = tt*16 + lvS[w*16 + j];
      float a = lvalS[w*16 + j];
      int sw = p >> 2;
      f32x4 x0 = *(const f32x4*)&tl[p*128 + (((cb0 ^ sw) & 31) << 2)];
      f32x4 x1 = *(const f32x4*)&tl[p*128 + (((cb1 ^ sw) & 31) << 2)];
      s0.x += a*x0.x; s0.y += a*x0.y; s0.z += a*x0.z; s0.w += a*x0.w;
      s1.x += a*x1.x; s1.y += a*x1.y; s1.z += a*x1.z; s1.w += a*x1.w;
    }
    us8 pk;
    pk[0]=f2bf(s0.x); pk[1]=f2bf(s0.y); pk[2]=f2bf(s0.z); pk[3]=f2bf(s0.w);
    pk[4]=f2bf(s1.x); pk[5]=f2bf(s1.y); pk[6]=f2bf(s1.z); pk[7]=f2bf(s1.w);
    int byteoff = (pos << 8) + (c8 << 1);
    byteoff ^= ((pos & 7) << 4);
    *(us8*)((char*)Th + byteoff) = pk;
  }
  __syncthreads();
  // gconv MFMA (TAPS=1, HALO=0, 64 pos)
  int wv = tid >> 6, lane = tid & 63, l15 = lane & 15, lhi = lane >> 4;
  int o0 = wv << 5;
  f32x4 zz = {0.f,0.f,0.f,0.f};
  f32x4 acc[2][4];
  #pragma unroll
  for (int i = 0; i < 2; ++i)
    #pragma unroll
    for (int q = 0; q < 4; ++q) acc[i][q] = zz;
  const unsigned short* wr0 = Wb + (long)(o0 + l15)*128 + lhi*8;
  const unsigned short* wr1 = wr0 + 16*128;
  #pragma unroll
  for (int kk = 0; kk < 4; ++kk) {
    int kc = kk*32 + lhi*8;
    bf16x8 a0 = *(const bf16x8*)(wr0 + kk*32);
    bf16x8 a1 = *(const bf16x8*)(wr1 + kk*32);
    #pragma unroll
    for (int pf = 0; pf < 4; ++pf) {
      int row = pf*16 + l15;
      int byteoff = (row << 8) + (kc << 1);
      byteoff ^= ((row & 7) << 4);
      bf16x8 bh = *(const bf16x8*)((const char*)Th + byteoff);
      acc[0][pf] = __builtin_amdgcn_mfma_f32_16x16x32_bf16(a0, bh, acc[0][pf], 0, 0, 0);
      acc[1][pf] = __builtin_amdgcn_mfma_f32_16x16x32_bf16(a1, bh, acc[1][pf], 0, 0, 0);
    }
  }
  // epilogue: bias + bf16 store + BN partials
  float s1a[2][4], s2a[2][4];
  #pragma unroll
  for (int i = 0; i < 2; ++i)
    #pragma unroll
    for (int j = 0; j < 4; ++j) { s1a[i][j] = 0.f; s2a[i][j] = 0.f; }
  unsigned short* og = out + ((long)n*4096 + off)*128;
  #pragma unroll
  for (int of = 0; of < 2; ++of) {
    int oc = o0 + of*16 + lhi*4;
    #pragma unroll
    for (int pf = 0; pf < 4; ++pf) {
      int pos = pf*16 + l15;
      f32x4 r = acc[of][pf];
      float s = sAv[l15];
      r.x += gb[oc+0]*s; r.y += gb[oc+1]*s;
      r.z += gb[oc+2]*s; r.w += gb[oc+3]*s;
      ushort4 pk;
      pk.x = f2bf(r.x); pk.y = f2bf(r.y); pk.z = f2bf(r.z); pk.w = f2bf(r.w);
      *(ushort4*)(og + (long)pos*128 + oc) = pk;
      #pragma unroll
      for (int j = 0; j < 4; ++j) { s1a[of][j] += r[j]; s2a[of][j] += r[j]*r[j]; }
    }
  }
  #pragma unroll
  for (int of = 0; of < 2; ++of)
    #pragma unroll
    for (int j = 0; j < 4; ++j) {
      float a = s1a[of][j], b2 = s2a[of][j];
      #pragma unroll
      for (int m = 1; m < 16; m <<= 1) { a += __shfl_xor(a, m); b2 += __shfl_xor(b2, m); }
      s1a[of][j] = a; s2a[of][j] = b2;
    }
  float* red = tl;   // tl reads complete before the pre-MFMA barrier
  if (l15 == 0) {
    #pragma unroll
    for (int of = 0; of < 2; ++of)
      #pragma unroll
      for (int j = 0; j < 4; ++j) {
        int ch = o0 + of*16 + lhi*4 + j;
        red[ch] = s1a[of][j];
        red[128 + ch] = s2a[of][j];
      }
  }
  __syncthreads();
  part[(long)blockIdx.x*256 + tid] = red[tid];
}

// ======== fused: r2=relu(bn(z2)+x) -> bf16 + sparse-agg(r2) in LDS -> MFMA gconv -> z3 ========
__global__ __launch_bounds__(256) void k_combineAggGconv(
    const unsigned short* __restrict__ z, const float* __restrict__ x,
    const int* __restrict__ cntA, const int* __restrict__ lvA, const float* __restrict__ lvalA,
    const float* __restrict__ sc, const float* __restrict__ sh,
    const unsigned short* __restrict__ Wb,
    unsigned short* __restrict__ r2, unsigned short* __restrict__ out,
    const float* __restrict__ gb, const float* __restrict__ sAv,
    float* __restrict__ part)
{
  __shared__ float rl[64*128];                          // r2 fp32, swizzled
  __shared__ __align__(16) unsigned short Th[64*128];   // agg bf16, conv-swizzled
  __shared__ int cntS[16];
  __shared__ int lvS[256];
  __shared__ float lvalS[256];
  int b = blockIdx.x; int n = b >> 6; int off = (b & 63) << 6;
  int tid = threadIdx.x;
  if (tid < 16) cntS[tid] = cntA[tid];
  lvS[tid] = lvA[tid];
  lvalS[tid] = lvalA[tid];
  long zbase = (long)b * 8192;
  // phase 1: bn(z2) -> rl
  for (int idx = tid; idx < 1024; idx += 256) {
    int pos = idx >> 4, c8 = (idx & 15) << 3;
    us8 raw = *(const us8*)(z + zbase + (long)pos*128 + c8);
    int qp = pos >> 2;
    #pragma unroll
    for (int half = 0; half < 2; ++half) {
      f32x4 f;
      #pragma unroll
      for (int j = 0; j < 4; ++j) {
        int cc = c8 + half*4 + j;
        f[j] = bf2f(raw[half*4+j]) * sc[cc] + sh[cc];
      }
      int cblk = (c8 >> 2) + half;
      *(f32x4*)&rl[pos*128 + (((cblk ^ qp) & 31) << 2)] = f;
    }
  }
  __syncthreads();
  // phase 2: + residual x, relu
  const float* xb = x + (long)n*524288 + off;
  for (int idx = tid; idx < 2048; idx += 256) {
    int c = idx >> 4, q = idx & 15;
    float4 v = *(const float4*)(xb + (long)c*4096 + q*4);
    int cb = c >> 2, cl = c & 3;
    #pragma unroll
    for (int j = 0; j < 4; ++j) {
      int a = (4*q+j)*128 + (((cb ^ q) & 31) << 2) + cl;
      rl[a] = fmaxf(rl[a] + ((const float*)&v)[j], 0.f);
    }
  }
  __syncthreads();
  // phase 3: write r2 bf16 + sparse agg -> Th
  for (int idx = tid; idx < 1024; idx += 256) {
    int pos = idx >> 4, c8 = (idx & 15) << 3;
    int cb0 = c8 >> 2, cb1 = cb0 + 1;
    int qp = pos >> 2;
    f32x4 r0 = *(const f32x4*)&rl[pos*128 + (((cb0 ^ qp) & 31) << 2)];
    f32x4 r1 = *(const f32x4*)&rl[pos*128 + (((cb1 ^ qp) & 31) << 2)];
    us8 pr;
    pr[0]=f2bf(r0.x); pr[1]=f2bf(r0.y); pr[2]=f2bf(r0.z); pr[3]=f2bf(r0.w);
    pr[4]=f2bf(r1.x); pr[5]=f2bf(r1.y); pr[6]=f2bf(r1.z); pr[7]=f2bf(r1.w);
    *(us8*)(r2 + zbase + (long)pos*128 + c8) = pr;
    int tt = pos >> 4, w = pos & 15;
    f32x4 s0 = {0.f,0.f,0.f,0.f}, s1 = {0.f,0.f,0.f,0.f};
    int cw = cntS[w];
    for (int j = 0; j < cw; ++j) {
      int p = tt*16 + lvS[w*16 + j];
      float a = lvalS[w*16 + j];
      int sw = p >> 2;
      f32x4 x0 = *(const f32x4*)&rl[p*128 + (((cb0 ^ sw) & 31) << 2)];
      f32x4 x1 = *(const f32x4*)&rl[p*128 + (((cb1 ^ sw) & 31) << 2)];
      s0.x += a*x0.x; s0.y += a*x0.y; s0.z += a*x0.z; s0.w += a*x0.w;
      s1.x += a*x1.x; s1.y += a*x1.y; s1.z += a*x1.z; s1.w += a*x1.w;
    }
    us8 pk;
    pk[0]=f2bf(s0.x); pk[1]=f2bf(s0.y); pk[2]=f2bf(s0.z); pk[3]=f2bf(s0.w);
    pk[4]=f2bf(s1.x); pk[5]=f2bf(s1.y); pk[6]=f2bf(s1.z); pk[7]=f2bf(s1.w);
    int byteoff = (pos << 8) + (c8 << 1);
    byteoff ^= ((pos & 7) << 4);
    *(us8*)((char*)Th + byteoff) = pk;
  }
  __syncthreads();
  // gconv2 MFMA
  int wv = tid >> 6, lane = tid & 63, l15 = lane & 15, lhi = lane >> 4;
  int o0 = wv << 5;
  f32x4 zz = {0.f,0.f,0.f,0.f};
  f32x4 acc[2][4];
  #pragma unroll
  for (int i = 0; i < 2; ++i)
    #pragma unroll
    for (int q = 0; q < 4; ++q) acc[i][q] = zz;
  const unsigned short* wr0 = Wb + (long)(o0 + l15)*128 + lhi*8;
  const unsigned short* wr1 = wr0 + 16*128;
  #pragma unroll
  for (int kk = 0; kk < 4; ++kk) {
    int kc = kk*32 + lhi*8;
    bf16x8 a0 = *(const bf16x8*)(wr0 + kk*32);
    bf16x8 a1 = *(const bf16x8*)(wr1 + kk*32);
    #pragma unroll
    for (int pf = 0; pf < 4; ++pf) {
      int row = pf*16 + l15;
      int byteoff = (row << 8) + (kc << 1);
      byteoff ^= ((row & 7) << 4);
      bf16x8 bh = *(const bf16x8*)((const char*)Th + byteoff);
      acc[0][pf] = __builtin_amdgcn_mfma_f32_16x16x32_bf16(a0, bh, acc[0][pf], 0, 0, 0);
      acc[1][pf] = __builtin_amdgcn_mfma_f32_16x16x32_bf16(a1, bh, acc[1][pf], 0, 0, 0);
    }
  }
  float s1a[2][4], s2a[2][4];
  #pragma unroll
  for (int i = 0; i < 2; ++i)
    #pragma unroll
    for (int j = 0; j < 4; ++j) { s1a[i][j] = 0.f; s2a[i][j] = 0.f; }
  unsigned short* og = out + zbase;
  #pragma unroll
  for (int of = 0; of < 2; ++of) {
    int oc = o0 + of*16 + lhi*4;
    #pragma unroll
    for (int pf = 0; pf < 4; ++pf) {
      int pos = pf*16 + l15;
      f32x4 r = acc[of][pf];
      float s = sAv[l15];
      r.x += gb[oc+0]*s; r.y += gb[oc+1]*s;
      r.z += gb[oc+2]*s; r.w += gb[oc+3]*s;
      ushort4 pk;
      pk.x = f2bf(r.x); pk.y = f2bf(r.y); pk.z = f2bf(r.z); pk.w = f2bf(r.w);
      *(ushort4*)(og + (long)pos*128 + oc) = pk;
      #pragma unroll
      for (int j = 0; j < 4; ++j) { s1a[of][j] += r[j]; s2a[of][j] += r[j]*r[j]; }
    }
  }
  #pragma unroll
  for (int of = 0; of < 2; ++of)
    #pragma unroll
    for (int j = 0; j < 4; ++j) {
      float a = s1a[of][j], b2 = s2a[of][j];
      #pragma unroll
      for (int m = 1; m < 16; m <<= 1) { a += __shfl_xor(a, m); b2 += __shfl_xor(b2, m); }
      s1a[of][j] = a; s2a[of][j] = b2;
    }
  float* red = rl;
  __syncthreads();                 // rl still read in phase-3 agg by other waves
  if (l15 == 0) {
    #pragma unroll
    for (int of = 0; of < 2; ++of)
      #pragma unroll
      for (int j = 0; j < 4; ++j) {
        int ch = o0 + of*16 + lhi*4 + j;
        red[ch] = s1a[of][j];
        red[128 + ch] = s2a[of][j];
      }
  }
  __syncthreads();
  part[(long)blockIdx.x*256 + tid] = red[tid];
}

// ================= MFMA conv, bf16 in/out, POSB-wide tiles, fused BN partials =================
template<int POSB, int HALO, int TAPS, int GROUPED_W, int IN_BN, int GROUPED_BN, int RELU_IN>
__global__ __launch_bounds__(256) void k_conv(
    const unsigned short* __restrict__ in, const unsigned short* __restrict__ Wb,
    unsigned short* __restrict__ out, int L,
    const float* __restrict__ isc, const float* __restrict__ ish,
    float* __restrict__ part)
{
  constexpr int TW = POSB + 2*HALO;
  constexpr int PF = POSB / 16;
  constexpr int KT = TAPS*128;
  __shared__ __align__(16) unsigned short Th[TW*128];
  int tid = threadIdx.x;
  int bpg = L / POSB;
  int g = blockIdx.x / bpg;
  int pos0 = (blockIdx.x - g*bpg) * POSB;
  const unsigned short* ing = in + (long)g*L*128;

  int cbase = (IN_BN && GROUPED_BN) ? ((g & 15) << 7) : 0;
  for (int idx = tid; idx < TW*16; idx += 256) {
    int row = idx >> 4;
    int c8 = (idx & 15) << 3;
    int gp = pos0 + row - HALO;
    us8 h = (us8)0;
    if (gp >= 0 && gp < L) {
      us8 raw = *(const us8*)(ing + (long)gp*128 + c8);
      if (IN_BN) {
        #pragma unroll
        for (int j = 0; j < 8; ++j) {
          int ci = cbase + c8 + j;
          float v = bf2f(raw[j]) * isc[ci] + ish[ci];
          if (RELU_IN) v = fmaxf(v, 0.f);
          h[j] = f2bf(v);
        }
      } else {
        h = raw;
      }
    }
    int byteoff = (row << 8) + (c8 << 1);
    byteoff ^= ((row & 7) << 4);
    *(us8*)((char*)Th + byteoff) = h;
  }
  __syncthreads();

  int wv = tid >> 6, lane = tid & 63, l15 = lane & 15, lhi = lane >> 4;
  int o0 = wv << 5;

  f32x4 zz = {0.f,0.f,0.f,0.f};
  f32x4 acc[2][PF];
  #pragma unroll
  for (int i = 0; i < 2; ++i)
    #pragma unroll
    for (int q = 0; q < PF; ++q) acc[i][q] = zz;

  const unsigned short* Wg = Wb + (GROUPED_W ? (long)(g & 15)*128*KT : 0);
  const unsigned short* wr0 = Wg + (long)(o0 + l15)*KT + lhi*8;
  const unsigned short* wr1 = wr0 + 16*KT;

  #pragma unroll
  for (int tap = 0; tap < TAPS; ++tap) {
    #pragma unroll
    for (int kk = 0; kk < 4; ++kk) {
      int kc = kk*32 + lhi*8;
      bf16x8 a0 = *(const bf16x8*)(wr0 + tap*128 + kk*32);
      bf16x8 a1 = *(const bf16x8*)(wr1 + tap*128 + kk*32);
      #pragma unroll
      for (int pf = 0; pf < PF; ++pf) {
        int row = pf*16 + l15 + tap*HALO;
        int byteoff = (row << 8) + (kc << 1);
        byteoff ^= ((row & 7) << 4);
        bf16x8 bh = *(const bf16x8*)((const char*)Th + byteoff);
        acc[0][pf] = __builtin_amdgcn_mfma_f32_16x16x32_bf16(a0, bh, acc[0][pf], 0, 0, 0);
        acc[1][pf] = __builtin_amdgcn_mfma_f32_16x16x32_bf16(a1, bh, acc[1][pf], 0, 0, 0);
      }
    }
  }

  float s1a[2][4], s2a[2][4];
  #pragma unroll
  for (int i = 0; i < 2; ++i)
    #pragma unroll
    for (int j = 0; j < 4; ++j) { s1a[i][j] = 0.f; s2a[i][j] = 0.f; }

  unsigned short* og = out + ((long)g*L + pos0)*128;
  #pragma unroll
  for (int of = 0; of < 2; ++of) {
    int oc = o0 + of*16 + lhi*4;
    #pragma unroll
    for (int pf = 0; pf < PF; ++pf) {
      int pos = pf*16 + l15;
      f32x4 r = acc[of][pf];
      ushort4 pk;
      pk.x = f2bf(r.x); pk.y = f2bf(r.y); pk.z = f2bf(r.z); pk.w = f2bf(r.w);
      *(ushort4*)(og + (long)pos*128 + oc) = pk;
      #pragma unroll
      for (int j = 0; j < 4; ++j) { s1a[of][j] += r[j]; s2a[of][j] += r[j]*r[j]; }
    }
  }
  #pragma unroll
  for (int of = 0; of < 2; ++of)
    #pragma unroll
    for (int j = 0; j < 4; ++j) {
      float a = s1a[of][j], b2 = s2a[of][j];
      #pragma unroll
      for (int m = 1; m < 16; m <<= 1) { a += __shfl_xor(a, m); b2 += __shfl_xor(b2, m); }
      s1a[of][j] = a; s2a[of][j] = b2;
    }
  __syncthreads();                 // waves must finish reading Th
  float* red = (float*)Th;
  if (l15 == 0) {
    #pragma unroll
    for (int of = 0; of < 2; ++of)
      #pragma unroll
      for (int j = 0; j < 4; ++j) {
        int ch = o0 + of*16 + lhi*4 + j;
        red[ch] = s1a[of][j];
        red[128 + ch] = s2a[of][j];
      }
  }
  __syncthreads();
  part[(long)blockIdx.x*256 + tid] = red[tid];
}

// ---------------- BN finalize: 128 channels, nblk block-partials ----------------
__global__ __launch_bounds__(256) void k_bnfin128(const float* __restrict__ part,
                           const float* __restrict__ gamma, const float* __restrict__ beta,
                           float* __restrict__ sc, float* __restrict__ sh,
                           float invN, int nblk) {
  int c = blockIdx.x, tid = threadIdx.x;
  float s1 = 0.f, s2 = 0.f;
  for (int b = tid; b < nblk; b += 256) {
    s1 += part[b*256 + c];
    s2 += part[b*256 + 128 + c];
  }
  __shared__ float l1[256], l2[256];
  l1[tid] = s1; l2[tid] = s2;
  __syncthreads();
  for (int st = 128; st > 0; st >>= 1) {
    if (tid < st) { l1[tid] += l1[tid+st]; l2[tid] += l2[tid+st]; }
    __syncthreads();
  }
  if (tid == 0) {
    float mean = l1[0]*invN;
    float var  = l2[0]*invN - mean*mean;
    float s = gamma[c] * rsqrtf(var + EPSBN);
    sc[c] = s;
    sh[c] = beta[c] - mean*s;
  }
}

// ---------------- BN finalize: 2048 (v,c) channels; 2 blocks per g, g=n*16+v ----------------
__global__ void k_bnfin2048(const float* __restrict__ part,
                            const float* __restrict__ gamma, const float* __restrict__ beta,
                            float* __restrict__ sc, float* __restrict__ sh, float invN) {
  int ch = blockIdx.x; int v = ch >> 7, c = ch & 127;
  int lane = threadIdx.x;          // 64 = 32 n x 2 bp
  int n = lane >> 1, bp = lane & 1;
  int blk = ((n*16 + v) << 1) + bp;
  float s1 = part[blk*256 + c];
  float s2 = part[blk*256 + 128 + c];
  for (int m = 32; m > 0; m >>= 1) { s1 += __shfl_down(s1, m); s2 += __shfl_down(s2, m); }
  if (lane == 0) {
    float mean = s1*invN;
    float var  = s2*invN - mean*mean;
    float s = gamma[ch] * rsqrtf(var + EPSBN);
    sc[ch] = s;
    sh[ch] = beta[ch] - mean*s;
  }
}

// ---------------- dynamic tail: out[n,c,v] = max_t relu(bn(z)+r2), bf16 inputs ----------------
__global__ __launch_bounds__(256) void k_maxdyn(
    const unsigned short* __restrict__ z, const unsigned short* __restrict__ res,
    const float* __restrict__ sc, const float* __restrict__ sh,
    float* __restrict__ outp)
{
  int b = blockIdx.x; int n = b >> 4, v = b & 15;
  int tid = threadIdx.x; int c = tid & 127, h = tid >> 7;
  const unsigned short* zb = z   + ((long)n*4096 + v)*128 + c;
  const unsigned short* rb = res + ((long)n*4096 + v)*128 + c;
  float s = sc[c], bb = sh[c];
  float m = 0.f;
  for (int t = h; t < 256; t += 2) {
    float val = bf2f(zb[(long)t*2048]) * s + bb + bf2f(rb[(long)t*2048]);
    m = fmaxf(m, val);
  }
  __shared__ float red[256];
  red[tid] = m;
  __syncthreads();
  if (tid < 128)
    outp[(long)n*4096 + c*32 + v] = fmaxf(fmaxf(red[tid], red[tid+128]), 0.f);
}

// ---------------- static tail: out[n,c,16+v] = max_s bn(z[(n,v)][s][c]), bf16 ----------------
__global__ __launch_bounds__(256) void k_maxstat(
    const unsigned short* __restrict__ z,
    const float* __restrict__ sc, const float* __restrict__ sh,
    float* __restrict__ outp)
{
  int b = blockIdx.x; int n = b >> 4, v = b & 15;
  int tid = threadIdx.x; int c = tid & 127, h = tid >> 7;
  const unsigned short* zb = z + (long)b*256*128 + c;
  float s = sc[v*128 + c], bb = sh[v*128 + c];
  float m = -1e30f;
  for (int t = h; t < 256; t += 2)
    m = fmaxf(m, bf2f(zb[t*128]) * s + bb);
  __shared__ float red[256];
  red[tid] = m;
  __syncthreads();
  if (tid < 128)
    outp[(long)n*4096 + c*32 + 16 + v] = fmaxf(red[tid], red[tid+128]);
}

extern "C" void kernel_launch(void* const* d_in, const int* in_sizes, int n_in,
                              void* d_out, int out_size, void* d_ws, size_t ws_size,
                              hipStream_t stream) {
  (void)in_sizes; (void)n_in; (void)out_size; (void)ws_size;
  const float* x     = (const float*)d_in[0];
  const float* nv1   = (const float*)d_in[1];
  const float* nv2   = (const float*)d_in[2];
  const float* d1gw  = (const float*)d_in[3];
  const float* d1gb  = (const float*)d_in[4];
  const float* d1b1g = (const float*)d_in[5];
  const float* d1b1b = (const float*)d_in[6];
  const float* d1tw  = (const float*)d_in[7];
  const float* d1b2g = (const float*)d_in[9];
  const float* d1b2b = (const float*)d_in[10];
  const float* d2gw  = (const float*)d_in[11];
  const float* d2gb  = (const float*)d_in[12];
  const float* d2b1g = (const float*)d_in[13];
  const float* d2b1b = (const float*)d_in[14];
  const float* d2tw  = (const float*)d_in[15];
  const float* d2b2g = (const float*)d_in[17];
  const float* d2b2b = (const float*)d_in[18];
  const float* s1pw  = (const float*)d_in[19];
  const float* s1pg  = (const float*)d_in[20];
  const float* s1pb  = (const float*)d_in[21];
  const float* s1tw  = (const float*)d_in[22];
  const float* s1tg  = (const float*)d_in[23];
  const float* s1tb  = (const float*)d_in[24];
  const float* s2pw  = (const float*)d_in[25];
  const float* s2pg  = (const float*)d_in[26];
  const float* s2pb  = (const float*)d_in[27];
  const float* s2tw  = (const float*)d_in[28];
  const float* s2tg  = (const float*)d_in[29];
  const float* s2tb  = (const float*)d_in[30];

  float* W = (float*)d_ws;
  float* Am  = W;            // 256
  float* sAv = W + 256;      // 16
  float* scA = W + 512;  float* shA = W + 640;
  float* scB = W + 768;  float* shB = W + 896;
  float* scC = W + 1024; float* shC = W + 1152;
  float* scD = W + 1280; float* shD = W + 1408;
  float* scE = W + 1536; float* shE = W + 1664;
  float* scG = W + 1792; float* shG = W + 1920;
  float* scF = W + 2048; float* shF = W + 4096;   // 2048 each
  float* scH = W + 6144; float* shH = W + 8192;
  int*   cntA  = (int*)(W + 10240);               // 16
  int*   lvA   = (int*)(W + 10496);               // 256
  float* lvalA = W + 10752;                       // 256
  float* A = W + 16384;
  float* B = A + 16777216;
  float* C = B + 16777216;
  float* part = C + 16777216;                     // up to 2048*256 floats
  float* outp = (float*)d_out;

  unsigned short* A0 = (unsigned short*)A;
  unsigned short* B0 = (unsigned short*)B;
  unsigned short* C0 = (unsigned short*)C;
  unsigned short* w_d1g = (unsigned short*)(A + 8388608);
  unsigned short* w_d1t = w_d1g + 16384;
  unsigned short* w_d2g = w_d1t + 49152;
  unsigned short* w_d2t = w_d2g + 16384;
  unsigned short* w_s1p = (unsigned short*)(C + 8388608);
  unsigned short* w_s1t = (unsigned short*)(B + 8388608);
  unsigned short* w_s2p = w_s1t + 786432;
  unsigned short* w_s2t = w_s2p + 16384;

  // ---- setup ----
  k_adj<<<1, 256, 0, stream>>>(nv1, nv2, Am, sAv, cntA, lvA, lvalA);
  k_cvt_cw<<<64, 256, 0, stream>>>(d1gw, w_d1g);
  k_cvt_tw<<<192, 256, 0, stream>>>(d1tw, w_d1t, 128);
  k_cvt_cw<<<64, 256, 0, stream>>>(d2gw, w_d2g);
  k_cvt_tw<<<192, 256, 0, stream>>>(d2tw, w_d2t, 128);
  k_cvt_cw<<<64, 256, 0, stream>>>(s1pw, w_s1p);
  k_cvt_tw<<<3072, 256, 0, stream>>>(s1tw, w_s1t, 2048);
  k_cvt_cw<<<64, 256, 0, stream>>>(s2pw, w_s2p);
  k_cvt_tw<<<3072, 256, 0, stream>>>(s2tw, w_s2t, 2048);

  // ======== dynamic branch ========
  k_aggGconv<<<2048, 256, 0, stream>>>(x, cntA, lvA, lvalA, w_d1g, B0, d1gb, sAv, part);   // B0 = z1
  k_bnfin128<<<128, 256, 0, stream>>>(part, d1b1g, d1b1b, scA, shA, 1.f/131072.f, 2048);
  k_conv<128,16,3,0,1,0,1><<<1024, 256, 0, stream>>>(B0, w_d1t, C0, 4096, scA, shA, part); // C0 = z2
  k_bnfin128<<<128, 256, 0, stream>>>(part, d1b2g, d1b2b, scB, shB, 1.f/131072.f, 1024);
  k_combineAggGconv<<<2048, 256, 0, stream>>>(C0, x, cntA, lvA, lvalA, scB, shB, w_d2g, A0, B0, d2gb, sAv, part); // A0=r2, B0=z3
  k_bnfin128<<<128, 256, 0, stream>>>(part, d2b1g, d2b1b, scC, shC, 1.f/131072.f, 2048);
  k_conv<128,16,3,0,1,0,1><<<1024, 256, 0, stream>>>(B0, w_d2t, C0, 4096, scC, shC, part); // C0 = z4
  k_bnfin128<<<128, 256, 0, stream>>>(part, d2b2g, d2b2b, scD, shD, 1.f/131072.f, 1024);
  k_maxdyn<<<512, 256, 0, stream>>>(C0, A0, scD, shD, outp);

  // ======== static branch ========
  k_xS<<<2048, 256, 0, stream>>>(x, B0);                                        // B0 = xS
  k_conv<128,0,1,0,0,0,0><<<1024, 256, 0, stream>>>(B0, w_s1p, A0, 256, nullptr, nullptr, part);
  k_bnfin128<<<128, 256, 0, stream>>>(part, s1pg, s1pb, scE, shE, 1.f/131072.f, 1024);
  k_conv<128,1,3,1,1,0,0><<<1024, 256, 0, stream>>>(A0, w_s1t, C0, 256, scE, shE, part);
  k_bnfin2048<<<2048, 64, 0, stream>>>(part, s1tg, s1tb, scF, shF, 1.f/8192.f);
  k_conv<128,0,1,0,1,1,0><<<1024, 256, 0, stream>>>(C0, w_s2p, A0, 256, scF, shF, part);
  k_bnfin128<<<128, 256, 0, stream>>>(part, s2pg, s2pb, scG, shG, 1.f/131072.f, 1024);
  k_conv<128,1,3,1,1,0,0><<<1024, 256, 0, stream>>>(A0, w_s2t, C0, 256, scG, shG, part);
  k_bnfin2048<<<2048, 64, 0, stream>>>(part, s2tg, s2tb, scH, shH, 1.f/8192.f);
  k_maxstat<<<512, 256, 0, stream>>>(C0, scH, shH, outp);
}

// Round 10
// 361.024 us; speedup vs baseline: 7.3799x; 1.0313x over previous
//
#include <hip/hip_runtime.h>

#define EPSBN 1e-5f

typedef __attribute__((ext_vector_type(8))) __bf16 bf16x8;
typedef __attribute__((ext_vector_type(4))) float f32x4;
typedef __attribute__((ext_vector_type(8))) unsigned short us8;

__device__ inline unsigned short f2bf(float f) {
  unsigned u = __float_as_uint(f);
  u = (u + 0x7fffu + ((u >> 16) & 1u)) >> 16;
  return (unsigned short)u;
}
__device__ inline float bf2f(unsigned short h) {
  return __uint_as_float(((unsigned)h) << 16);
}

// ---------------- adjacency: A = adp(nv1,nv2); column sums sA; per-column sparse lists ----------------
__global__ void k_adj(const float* __restrict__ nv1, const float* __restrict__ nv2,
                      float* __restrict__ A, float* __restrict__ sA,
                      int* __restrict__ cntA, int* __restrict__ lvA, float* __restrict__ lvalA) {
  __shared__ float M[16][16];
  int tid = threadIdx.x;
  int i = tid >> 4, j = tid & 15;
  float acc = 0.f;
  #pragma unroll
  for (int k = 0; k < 64; ++k) acc += nv1[i*64+k] * nv2[k*16+j];
  M[i][j] = fmaxf(acc, 0.f);
  __syncthreads();
  if (tid < 16) {
    float m = -1e30f;
    for (int c = 0; c < 16; ++c) m = fmaxf(m, M[tid][c]);
    float e[16]; float s = 0.f;
    for (int c = 0; c < 16; ++c) { e[c] = expf(M[tid][c] - m); s += e[c]; }
    float inv = 1.f / s;
    float t1 = -1e30f, t2 = -1e30f;
    for (int c = 0; c < 16; ++c) {
      float a = e[c] * inv; e[c] = a;
      if (a > t1) { t2 = t1; t1 = a; }
      else if (a > t2) t2 = a;
    }
    for (int c = 0; c < 16; ++c) {
      bool keep = (e[c] > (1.0f/16.0f)) && (e[c] > t2);
      M[tid][c] = keep ? e[c] : 0.f;
    }
  }
  __syncthreads();
  A[tid] = M[tid>>4][tid&15];
  if (tid < 16) {           // tid = w (column)
    float s = 0.f;
    int cnt = 0;
    for (int v = 0; v < 16; ++v) {
      float a = M[v][tid];
      s += a;
      if (a != 0.f) { lvA[tid*16 + cnt] = v; lvalA[tid*16 + cnt] = a; ++cnt; }
    }
    sA[tid] = s;
    cntA[tid] = cnt;
  }
}

// ---------------- merged weight converts ----------------
__device__ inline void cvt_cw_seg(const float* w, unsigned short* o, int lidx) {
  o[lidx] = f2bf(w[lidx]);
}
__device__ inline void cvt_tw_seg(const float* w, unsigned short* o, int lidx) {
  int oo = lidx / 384;
  int r = lidx - oo*384;
  int tap = r >> 7, c = r & 127;
  o[lidx] = f2bf(w[(oo*128 + c)*3 + tap]);
}
__global__ __launch_bounds__(256) void k_cvt_dyn(
    const float* __restrict__ d1g, const float* __restrict__ d1t,
    const float* __restrict__ d2g, const float* __restrict__ d2t,
    unsigned short* __restrict__ O) {
  int b = blockIdx.x, tid = threadIdx.x;
  if (b < 64)        cvt_cw_seg(d1g, O,          b*256 + tid);
  else if (b < 256)  cvt_tw_seg(d1t, O + 16384, (b-64)*256 + tid);
  else if (b < 320)  cvt_cw_seg(d2g, O + 65536, (b-256)*256 + tid);
  else               cvt_tw_seg(d2t, O + 81920, (b-320)*256 + tid);
}
__global__ __launch_bounds__(256) void k_cvt_stat(
    const float* __restrict__ s1p, const float* __restrict__ s1t,
    const float* __restrict__ s2p, const float* __restrict__ s2t,
    unsigned short* __restrict__ S) {
  int b = blockIdx.x, tid = threadIdx.x;
  if (b < 64)        cvt_cw_seg(s1p, S,           b*256 + tid);
  else if (b < 3136) cvt_tw_seg(s1t, S + 16384,  (b-64)*256 + tid);
  else if (b < 3200) cvt_cw_seg(s2p, S + 802816, (b-3136)*256 + tid);
  else               cvt_tw_seg(s2t, S + 819200, (b-3200)*256 + tid);
}

// ---------------- x -> xB (pos-major bf16) + xS (static-layout bf16), one pass ----------------
__global__ __launch_bounds__(256) void k_xcvt(const float* __restrict__ x,
                                              unsigned short* __restrict__ xB,
                                              unsigned short* __restrict__ xS) {
  __shared__ float tl[64*128];
  int b = blockIdx.x; int n = b >> 6; int t0q = b & 63;
  int tid = threadIdx.x;
  const float* xb = x + (long)n*524288 + t0q*64;
  for (int idx = tid; idx < 2048; idx += 256) {
    int c = idx >> 4, q = idx & 15;
    float4 v = *(const float4*)(xb + (long)c*4096 + q*4);
    int cb = c >> 2, cl = c & 3;
    #pragma unroll
    for (int j = 0; j < 4; ++j)
      tl[(4*q+j)*128 + (((cb ^ q) & 31) << 2) + cl] = ((const float*)&v)[j];
  }
  __syncthreads();
  for (int idx = tid; idx < 1024; idx += 256) {
    int pos = idx >> 4, c8 = (idx & 15) << 3;
    int cb0 = c8 >> 2, cb1 = cb0 + 1, qp = pos >> 2;
    f32x4 v0 = *(const f32x4*)&tl[pos*128 + (((cb0 ^ qp) & 31) << 2)];
    f32x4 v1 = *(const f32x4*)&tl[pos*128 + (((cb1 ^ qp) & 31) << 2)];
    us8 pk;
    pk[0]=f2bf(v0.x); pk[1]=f2bf(v0.y); pk[2]=f2bf(v0.z); pk[3]=f2bf(v0.w);
    pk[4]=f2bf(v1.x); pk[5]=f2bf(v1.y); pk[6]=f2bf(v1.z); pk[7]=f2bf(v1.w);
    *(us8*)(xB + ((long)n*4096 + t0q*64 + pos)*128 + c8) = pk;
    int vv = pos & 15, tt = pos >> 4;
    *(us8*)(xS + ((long)(n*16+vv)*256 + t0q*4 + tt)*128 + c8) = pk;
  }
}

// ========== fused: sparse-agg(xB) via direct global gather -> MFMA gconv -> z1 + BN partials ==========
__global__ __launch_bounds__(256) void k_aggGconv(
    const unsigned short* __restrict__ xB,
    const int* __restrict__ cntA, const int* __restrict__ lvA, const float* __restrict__ lvalA,
    const unsigned short* __restrict__ Wb,
    unsigned short* __restrict__ out,
    const float* __restrict__ gb, const float* __restrict__ sAv,
    float* __restrict__ part)
{
  __shared__ __align__(16) unsigned short Th[64*128];   // agg bf16, conv-swizzled
  __shared__ int cntS[16];
  __shared__ int lvS[256];
  __shared__ float lvalS[256];
  int b = blockIdx.x; int n = b >> 6; int off = (b & 63) << 6;
  int tid = threadIdx.x;
  if (tid < 16) cntS[tid] = cntA[tid];
  lvS[tid] = lvA[tid];
  lvalS[tid] = lvalA[tid];
  __syncthreads();
  const unsigned short* xbase = xB + ((long)n*4096 + off)*128;
  for (int idx = tid; idx < 1024; idx += 256) {
    int pos = idx >> 4, c8 = (idx & 15) << 3;
    int tt = pos >> 4, w = pos & 15;
    float s[8];
    #pragma unroll
    for (int k = 0; k < 8; ++k) s[k] = 0.f;
    int cw = cntS[w];
    for (int j = 0; j < cw; ++j) {
      int p = tt*16 + lvS[w*16 + j];
      float a = lvalS[w*16 + j];
      us8 raw = *(const us8*)(xbase + (long)p*128 + c8);
      #pragma unroll
      for (int k = 0; k < 8; ++k) s[k] += a * bf2f(raw[k]);
    }
    us8 pk;
    #pragma unroll
    for (int k = 0; k < 8; ++k) pk[k] = f2bf(s[k]);
    int byteoff = (pos << 8) + (c8 << 1);
    byteoff ^= ((pos & 7) << 4);
    *(us8*)((char*)Th + byteoff) = pk;
  }
  __syncthreads();
  int wv = tid >> 6, lane = tid & 63, l15 = lane & 15, lhi = lane >> 4;
  int o0 = wv << 5;
  f32x4 zz = {0.f,0.f,0.f,0.f};
  f32x4 acc[2][4];
  #pragma unroll
  for (int i = 0; i < 2; ++i)
    #pragma unroll
    for (int q = 0; q < 4; ++q) acc[i][q] = zz;
  const unsigned short* wr0 = Wb + (long)(o0 + l15)*128 + lhi*8;
  const unsigned short* wr1 = wr0 + 16*128;
  #pragma unroll
  for (int kk = 0; kk < 4; ++kk) {
    int kc = kk*32 + lhi*8;
    bf16x8 a0 = *(const bf16x8*)(wr0 + kk*32);
    bf16x8 a1 = *(const bf16x8*)(wr1 + kk*32);
    #pragma unroll
    for (int pf = 0; pf < 4; ++pf) {
      int row = pf*16 + l15;
      int byteoff = (row << 8) + (kc << 1);
      byteoff ^= ((row & 7) << 4);
      bf16x8 bh = *(const bf16x8*)((const char*)Th + byteoff);
      acc[0][pf] = __builtin_amdgcn_mfma_f32_16x16x32_bf16(a0, bh, acc[0][pf], 0, 0, 0);
      acc[1][pf] = __builtin_amdgcn_mfma_f32_16x16x32_bf16(a1, bh, acc[1][pf], 0, 0, 0);
    }
  }
  float s1a[2][4], s2a[2][4];
  #pragma unroll
  for (int i = 0; i < 2; ++i)
    #pragma unroll
    for (int j = 0; j < 4; ++j) { s1a[i][j] = 0.f; s2a[i][j] = 0.f; }
  unsigned short* og = out + ((long)n*4096 + off)*128;
  #pragma unroll
  for (int of = 0; of < 2; ++of) {
    int oc = o0 + of*16 + lhi*4;
    #pragma unroll
    for (int pf = 0; pf < 4; ++pf) {
      int pos = pf*16 + l15;
      f32x4 r = acc[of][pf];
      float s = sAv[l15];
      r.x += gb[oc+0]*s; r.y += gb[oc+1]*s;
      r.z += gb[oc+2]*s; r.w += gb[oc+3]*s;
      ushort4 pk;
      pk.x = f2bf(r.x); pk.y = f2bf(r.y); pk.z = f2bf(r.z); pk.w = f2bf(r.w);
      *(ushort4*)(og + (long)pos*128 + oc) = pk;
      #pragma unroll
      for (int j = 0; j < 4; ++j) { s1a[of][j] += r[j]; s2a[of][j] += r[j]*r[j]; }
    }
  }
  #pragma unroll
  for (int of = 0; of < 2; ++of)
    #pragma unroll
    for (int j = 0; j < 4; ++j) {
      float a = s1a[of][j], b2 = s2a[of][j];
      #pragma unroll
      for (int m = 1; m < 16; m <<= 1) { a += __shfl_xor(a, m); b2 += __shfl_xor(b2, m); }
      s1a[of][j] = a; s2a[of][j] = b2;
    }
  __syncthreads();
  float* red = (float*)Th;
  if (l15 == 0) {
    #pragma unroll
    for (int of = 0; of < 2; ++of)
      #pragma unroll
      for (int j = 0; j < 4; ++j) {
        int ch = o0 + of*16 + lhi*4 + j;
        red[ch] = s1a[of][j];
        red[128 + ch] = s2a[of][j];
      }
  }
  __syncthreads();
  part[(long)blockIdx.x*256 + tid] = red[tid];
}

// ========== fused: r2=relu(bn(z2)+xB) elementwise -> bf16 (LDS+global); sparse-agg; gconv2 ==========
__global__ __launch_bounds__(256) void k_combineAggGconv(
    const unsigned short* __restrict__ z, const unsigned short* __restrict__ xB,
    const int* __restrict__ cntA, const int* __restrict__ lvA, const float* __restrict__ lvalA,
    const float* __restrict__ sc, const float* __restrict__ sh,
    const unsigned short* __restrict__ Wb,
    unsigned short* __restrict__ r2, unsigned short* __restrict__ out,
    const float* __restrict__ gb, const float* __restrict__ sAv,
    float* __restrict__ part)
{
  __shared__ __align__(16) unsigned short rl[64*128];   // r2 bf16, linear rows
  __shared__ __align__(16) unsigned short Th[64*128];   // agg bf16, conv-swizzled
  __shared__ int cntS[16];
  __shared__ int lvS[256];
  __shared__ float lvalS[256];
  int b = blockIdx.x;
  int tid = threadIdx.x;
  if (tid < 16) cntS[tid] = cntA[tid];
  lvS[tid] = lvA[tid];
  lvalS[tid] = lvalA[tid];
  long zbase = (long)b * 8192;
  // phase 1: elementwise r2 = relu(bn(z2) + x)
  for (int idx = tid; idx < 1024; idx += 256) {
    int pos = idx >> 4, c8 = (idx & 15) << 3;
    us8 zr = *(const us8*)(z  + zbase + (long)pos*128 + c8);
    us8 xr = *(const us8*)(xB + zbase + (long)pos*128 + c8);
    us8 pr;
    #pragma unroll
    for (int k = 0; k < 8; ++k) {
      int cc = c8 + k;
      float v = bf2f(zr[k]) * sc[cc] + sh[cc] + bf2f(xr[k]);
      pr[k] = f2bf(fmaxf(v, 0.f));
    }
    *(us8*)(rl + pos*128 + c8) = pr;
    *(us8*)(r2 + zbase + (long)pos*128 + c8) = pr;
  }
  __syncthreads();
  // phase 2: sparse agg from rl -> Th
  for (int idx = tid; idx < 1024; idx += 256) {
    int pos = idx >> 4, c8 = (idx & 15) << 3;
    int tt = pos >> 4, w = pos & 15;
    float s[8];
    #pragma unroll
    for (int k = 0; k < 8; ++k) s[k] = 0.f;
    int cw = cntS[w];
    for (int j = 0; j < cw; ++j) {
      int p = tt*16 + lvS[w*16 + j];
      float a = lvalS[w*16 + j];
      us8 raw = *(const us8*)(rl + p*128 + c8);
      #pragma unroll
      for (int k = 0; k < 8; ++k) s[k] += a * bf2f(raw[k]);
    }
    us8 pk;
    #pragma unroll
    for (int k = 0; k < 8; ++k) pk[k] = f2bf(s[k]);
    int byteoff = (pos << 8) + (c8 << 1);
    byteoff ^= ((pos & 7) << 4);
    *(us8*)((char*)Th + byteoff) = pk;
  }
  __syncthreads();
  // phase 3: gconv2 MFMA + epilogue
  int wv = tid >> 6, lane = tid & 63, l15 = lane & 15, lhi = lane >> 4;
  int o0 = wv << 5;
  f32x4 zz = {0.f,0.f,0.f,0.f};
  f32x4 acc[2][4];
  #pragma unroll
  for (int i = 0; i < 2; ++i)
    #pragma unroll
    for (int q = 0; q < 4; ++q) acc[i][q] = zz;
  const unsigned short* wr0 = Wb + (long)(o0 + l15)*128 + lhi*8;
  const unsigned short* wr1 = wr0 + 16*128;
  #pragma unroll
  for (int kk = 0; kk < 4; ++kk) {
    int kc = kk*32 + lhi*8;
    bf16x8 a0 = *(const bf16x8*)(wr0 + kk*32);
    bf16x8 a1 = *(const bf16x8*)(wr1 + kk*32);
    #pragma unroll
    for (int pf = 0; pf < 4; ++pf) {
      int row = pf*16 + l15;
      int byteoff = (row << 8) + (kc << 1);
      byteoff ^= ((row & 7) << 4);
      bf16x8 bh = *(const bf16x8*)((const char*)Th + byteoff);
      acc[0][pf] = __builtin_amdgcn_mfma_f32_16x16x32_bf16(a0, bh, acc[0][pf], 0, 0, 0);
      acc[1][pf] = __builtin_amdgcn_mfma_f32_16x16x32_bf16(a1, bh, acc[1][pf], 0, 0, 0);
    }
  }
  float s1a[2][4], s2a[2][4];
  #pragma unroll
  for (int i = 0; i < 2; ++i)
    #pragma unroll
    for (int j = 0; j < 4; ++j) { s1a[i][j] = 0.f; s2a[i][j] = 0.f; }
  unsigned short* og = out + zbase;
  #pragma unroll
  for (int of = 0; of < 2; ++of) {
    int oc = o0 + of*16 + lhi*4;
    #pragma unroll
    for (int pf = 0; pf < 4; ++pf) {
      int pos = pf*16 + l15;
      f32x4 r = acc[of][pf];
      float s = sAv[l15];
      r.x += gb[oc+0]*s; r.y += gb[oc+1]*s;
      r.z += gb[oc+2]*s; r.w += gb[oc+3]*s;
      ushort4 pk;
      pk.x = f2bf(r.x); pk.y = f2bf(r.y); pk.z = f2bf(r.z); pk.w = f2bf(r.w);
      *(ushort4*)(og + (long)pos*128 + oc) = pk;
      #pragma unroll
      for (int j = 0; j < 4; ++j) { s1a[of][j] += r[j]; s2a[of][j] += r[j]*r[j]; }
    }
  }
  #pragma unroll
  for (int of = 0; of < 2; ++of)
    #pragma unroll
    for (int j = 0; j < 4; ++j) {
      float a = s1a[of][j], b2 = s2a[of][j];
      #pragma unroll
      for (int m = 1; m < 16; m <<= 1) { a += __shfl_xor(a, m); b2 += __shfl_xor(b2, m); }
      s1a[of][j] = a; s2a[of][j] = b2;
    }
  __syncthreads();
  float* red = (float*)rl;
  if (l15 == 0) {
    #pragma unroll
    for (int of = 0; of < 2; ++of)
      #pragma unroll
      for (int j = 0; j < 4; ++j) {
        int ch = o0 + of*16 + lhi*4 + j;
        red[ch] = s1a[of][j];
        red[128 + ch] = s2a[of][j];
      }
  }
  __syncthreads();
  part[(long)blockIdx.x*256 + tid] = red[tid];
}

// ================= MFMA conv, bf16 in/out, POSB-wide tiles, fused BN partials =================
template<int POSB, int HALO, int TAPS, int GROUPED_W, int IN_BN, int GROUPED_BN, int RELU_IN>
__global__ __launch_bounds__(256) void k_conv(
    const unsigned short* __restrict__ in, const unsigned short* __restrict__ Wb,
    unsigned short* __restrict__ out, int L,
    const float* __restrict__ isc, const float* __restrict__ ish,
    float* __restrict__ part)
{
  constexpr int TW = POSB + 2*HALO;
  constexpr int PF = POSB / 16;
  constexpr int KT = TAPS*128;
  __shared__ __align__(16) unsigned short Th[TW*128];
  int tid = threadIdx.x;
  int bpg = L / POSB;
  int g = blockIdx.x / bpg;
  int pos0 = (blockIdx.x - g*bpg) * POSB;
  const unsigned short* ing = in + (long)g*L*128;

  int cbase = (IN_BN && GROUPED_BN) ? ((g & 15) << 7) : 0;
  for (int idx = tid; idx < TW*16; idx += 256) {
    int row = idx >> 4;
    int c8 = (idx & 15) << 3;
    int gp = pos0 + row - HALO;
    us8 h = (us8)0;
    if (gp >= 0 && gp < L) {
      us8 raw = *(const us8*)(ing + (long)gp*128 + c8);
      if (IN_BN) {
        #pragma unroll
        for (int j = 0; j < 8; ++j) {
          int ci = cbase + c8 + j;
          float v = bf2f(raw[j]) * isc[ci] + ish[ci];
          if (RELU_IN) v = fmaxf(v, 0.f);
          h[j] = f2bf(v);
        }
      } else {
        h = raw;
      }
    }
    int byteoff = (row << 8) + (c8 << 1);
    byteoff ^= ((row & 7) << 4);
    *(us8*)((char*)Th + byteoff) = h;
  }
  __syncthreads();

  int wv = tid >> 6, lane = tid & 63, l15 = lane & 15, lhi = lane >> 4;
  int o0 = wv << 5;

  f32x4 zz = {0.f,0.f,0.f,0.f};
  f32x4 acc[2][PF];
  #pragma unroll
  for (int i = 0; i < 2; ++i)
    #pragma unroll
    for (int q = 0; q < PF; ++q) acc[i][q] = zz;

  const unsigned short* Wg = Wb + (GROUPED_W ? (long)(g & 15)*128*KT : 0);
  const unsigned short* wr0 = Wg + (long)(o0 + l15)*KT + lhi*8;
  const unsigned short* wr1 = wr0 + 16*KT;

  #pragma unroll
  for (int tap = 0; tap < TAPS; ++tap) {
    #pragma unroll
    for (int kk = 0; kk < 4; ++kk) {
      int kc = kk*32 + lhi*8;
      bf16x8 a0 = *(const bf16x8*)(wr0 + tap*128 + kk*32);
      bf16x8 a1 = *(const bf16x8*)(wr1 + tap*128 + kk*32);
      #pragma unroll
      for (int pf = 0; pf < PF; ++pf) {
        int row = pf*16 + l15 + tap*HALO;
        int byteoff = (row << 8) + (kc << 1);
        byteoff ^= ((row & 7) << 4);
        bf16x8 bh = *(const bf16x8*)((const char*)Th + byteoff);
        acc[0][pf] = __builtin_amdgcn_mfma_f32_16x16x32_bf16(a0, bh, acc[0][pf], 0, 0, 0);
        acc[1][pf] = __builtin_amdgcn_mfma_f32_16x16x32_bf16(a1, bh, acc[1][pf], 0, 0, 0);
      }
    }
  }

  float s1a[2][4], s2a[2][4];
  #pragma unroll
  for (int i = 0; i < 2; ++i)
    #pragma unroll
    for (int j = 0; j < 4; ++j) { s1a[i][j] = 0.f; s2a[i][j] = 0.f; }

  unsigned short* og = out + ((long)g*L + pos0)*128;
  #pragma unroll
  for (int of = 0; of < 2; ++of) {
    int oc = o0 + of*16 + lhi*4;
    #pragma unroll
    for (int pf = 0; pf < PF; ++pf) {
      int pos = pf*16 + l15;
      f32x4 r = acc[of][pf];
      ushort4 pk;
      pk.x = f2bf(r.x); pk.y = f2bf(r.y); pk.z = f2bf(r.z); pk.w = f2bf(r.w);
      *(ushort4*)(og + (long)pos*128 + oc) = pk;
      #pragma unroll
      for (int j = 0; j < 4; ++j) { s1a[of][j] += r[j]; s2a[of][j] += r[j]*r[j]; }
    }
  }
  #pragma unroll
  for (int of = 0; of < 2; ++of)
    #pragma unroll
    for (int j = 0; j < 4; ++j) {
      float a = s1a[of][j], b2 = s2a[of][j];
      #pragma unroll
      for (int m = 1; m < 16; m <<= 1) { a += __shfl_xor(a, m); b2 += __shfl_xor(b2, m); }
      s1a[of][j] = a; s2a[of][j] = b2;
    }
  __syncthreads();
  float* red = (float*)Th;
  if (l15 == 0) {
    #pragma unroll
    for (int of = 0; of < 2; ++of)
      #pragma unroll
      for (int j = 0; j < 4; ++j) {
        int ch = o0 + of*16 + lhi*4 + j;
        red[ch] = s1a[of][j];
        red[128 + ch] = s2a[of][j];
      }
  }
  __syncthreads();
  part[(long)blockIdx.x*256 + tid] = red[tid];
}

// ---------------- BN finalize: 128 channels, nblk block-partials ----------------
__global__ __launch_bounds__(256) void k_bnfin128(const float* __restrict__ part,
                           const float* __restrict__ gamma, const float* __restrict__ beta,
                           float* __restrict__ sc, float* __restrict__ sh,
                           float invN, int nblk) {
  int c = blockIdx.x, tid = threadIdx.x;
  float s1 = 0.f, s2 = 0.f;
  for (int b = tid; b < nblk; b += 256) {
    s1 += part[b*256 + c];
    s2 += part[b*256 + 128 + c];
  }
  __shared__ float l1[256], l2[256];
  l1[tid] = s1; l2[tid] = s2;
  __syncthreads();
  for (int st = 128; st > 0; st >>= 1) {
    if (tid < st) { l1[tid] += l1[tid+st]; l2[tid] += l2[tid+st]; }
    __syncthreads();
  }
  if (tid == 0) {
    float mean = l1[0]*invN;
    float var  = l2[0]*invN - mean*mean;
    float s = gamma[c] * rsqrtf(var + EPSBN);
    sc[c] = s;
    sh[c] = beta[c] - mean*s;
  }
}

// ---------------- BN finalize: 2048 (v,c) channels; 2 blocks per g, g=n*16+v ----------------
__global__ void k_bnfin2048(const float* __restrict__ part,
                            const float* __restrict__ gamma, const float* __restrict__ beta,
                            float* __restrict__ sc, float* __restrict__ sh, float invN) {
  int ch = blockIdx.x; int v = ch >> 7, c = ch & 127;
  int lane = threadIdx.x;          // 64 = 32 n x 2 bp
  int n = lane >> 1, bp = lane & 1;
  int blk = ((n*16 + v) << 1) + bp;
  float s1 = part[blk*256 + c];
  float s2 = part[blk*256 + 128 + c];
  for (int m = 32; m > 0; m >>= 1) { s1 += __shfl_down(s1, m); s2 += __shfl_down(s2, m); }
  if (lane == 0) {
    float mean = s1*invN;
    float var  = s2*invN - mean*mean;
    float s = gamma[ch] * rsqrtf(var + EPSBN);
    sc[ch] = s;
    sh[ch] = beta[ch] - mean*s;
  }
}

// ---------------- dynamic tail: out[n,c,v] = max_t relu(bn(z)+r2), bf16 inputs ----------------
__global__ __launch_bounds__(256) void k_maxdyn(
    const unsigned short* __restrict__ z, const unsigned short* __restrict__ res,
    const float* __restrict__ sc, const float* __restrict__ sh,
    float* __restrict__ outp)
{
  int b = blockIdx.x; int n = b >> 4, v = b & 15;
  int tid = threadIdx.x; int c = tid & 127, h = tid >> 7;
  const unsigned short* zb = z   + ((long)n*4096 + v)*128 + c;
  const unsigned short* rb = res + ((long)n*4096 + v)*128 + c;
  float s = sc[c], bb = sh[c];
  float m = 0.f;
  for (int t = h; t < 256; t += 2) {
    float val = bf2f(zb[(long)t*2048]) * s + bb + bf2f(rb[(long)t*2048]);
    m = fmaxf(m, val);
  }
  __shared__ float red[256];
  red[tid] = m;
  __syncthreads();
  if (tid < 128)
    outp[(long)n*4096 + c*32 + v] = fmaxf(fmaxf(red[tid], red[tid+128]), 0.f);
}

// ---------------- static tail: out[n,c,16+v] = max_s bn(z[(n,v)][s][c]), bf16 ----------------
__global__ __launch_bounds__(256) void k_maxstat(
    const unsigned short* __restrict__ z,
    const float* __restrict__ sc, const float* __restrict__ sh,
    float* __restrict__ outp)
{
  int b = blockIdx.x; int n = b >> 4, v = b & 15;
  int tid = threadIdx.x; int c = tid & 127, h = tid >> 7;
  const unsigned short* zb = z + (long)b*256*128 + c;
  float s = sc[v*128 + c], bb = sh[v*128 + c];
  float m = -1e30f;
  for (int t = h; t < 256; t += 2)
    m = fmaxf(m, bf2f(zb[t*128]) * s + bb);
  __shared__ float red[256];
  red[tid] = m;
  __syncthreads();
  if (tid < 128)
    outp[(long)n*4096 + c*32 + 16 + v] = fmaxf(red[tid], red[tid+128]);
}

extern "C" void kernel_launch(void* const* d_in, const int* in_sizes, int n_in,
                              void* d_out, int out_size, void* d_ws, size_t ws_size,
                              hipStream_t stream) {
  (void)in_sizes; (void)n_in; (void)out_size; (void)ws_size;
  const float* x     = (const float*)d_in[0];
  const float* nv1   = (const float*)d_in[1];
  const float* nv2   = (const float*)d_in[2];
  const float* d1gw  = (const float*)d_in[3];
  const float* d1gb  = (const float*)d_in[4];
  const float* d1b1g = (const float*)d_in[5];
  const float* d1b1b = (const float*)d_in[6];
  const float* d1tw  = (const float*)d_in[7];
  const float* d1b2g = (const float*)d_in[9];
  const float* d1b2b = (const float*)d_in[10];
  const float* d2gw  = (const float*)d_in[11];
  const float* d2gb  = (const float*)d_in[12];
  const float* d2b1g = (const float*)d_in[13];
  const float* d2b1b = (const float*)d_in[14];
  const float* d2tw  = (const float*)d_in[15];
  const float* d2b2g = (const float*)d_in[17];
  const float* d2b2b = (const float*)d_in[18];
  const float* s1pw  = (const float*)d_in[19];
  const float* s1pg  = (const float*)d_in[20];
  const float* s1pb  = (const float*)d_in[21];
  const float* s1tw  = (const float*)d_in[22];
  const float* s1tg  = (const float*)d_in[23];
  const float* s1tb  = (const float*)d_in[24];
  const float* s2pw  = (const float*)d_in[25];
  const float* s2pg  = (const float*)d_in[26];
  const float* s2pb  = (const float*)d_in[27];
  const float* s2tw  = (const float*)d_in[28];
  const float* s2tg  = (const float*)d_in[29];
  const float* s2tb  = (const float*)d_in[30];

  float* W = (float*)d_ws;
  float* Am  = W;            // 256
  float* sAv = W + 256;      // 16
  float* scA = W + 512;  float* shA = W + 640;
  float* scB = W + 768;  float* shB = W + 896;
  float* scC = W + 1024; float* shC = W + 1152;
  float* scD = W + 1280; float* shD = W + 1408;
  float* scE = W + 1536; float* shE = W + 1664;
  float* scG = W + 1792; float* shG = W + 1920;
  float* scF = W + 2048; float* shF = W + 4096;   // 2048 each
  float* scH = W + 6144; float* shH = W + 8192;
  int*   cntA  = (int*)(W + 10240);               // 16
  int*   lvA   = (int*)(W + 10496);               // 256
  float* lvalA = W + 10752;                       // 256
  float* A = W + 16384;
  float* B = A + 16777216;
  float* C = B + 16777216;
  float* part = C + 16777216;                     // up to 2048*256 floats
  float* outp = (float*)d_out;

  // six 32MB bf16 half-regions
  unsigned short* A0 = (unsigned short*)A;
  unsigned short* A1 = (unsigned short*)(A + 8388608);
  unsigned short* B0 = (unsigned short*)B;
  unsigned short* B1 = (unsigned short*)(B + 8388608);
  unsigned short* C0 = (unsigned short*)C;
  unsigned short* C1 = (unsigned short*)(C + 8388608);

  // dynamic weights staged in d_out scratch (fully overwritten by maxdyn/maxstat later)
  unsigned short* OW = (unsigned short*)d_out;
  unsigned short* w_d1g = OW;               // 16384
  unsigned short* w_d1t = OW + 16384;       // 49152
  unsigned short* w_d2g = OW + 65536;       // 16384
  unsigned short* w_d2t = OW + 81920;       // 49152 -> end 131072 us (within out buffer)
  // static weights staged in B1 (dead after maxdyn)
  unsigned short* SW    = B1;
  unsigned short* w_s1p = SW;               // 16384
  unsigned short* w_s1t = SW + 16384;       // 786432
  unsigned short* w_s2p = SW + 802816;      // 16384
  unsigned short* w_s2t = SW + 819200;      // 786432 -> end 1605632 us (3.2 MB)

  // ---- setup ----
  k_adj<<<1, 256, 0, stream>>>(nv1, nv2, Am, sAv, cntA, lvA, lvalA);
  k_cvt_dyn<<<512, 256, 0, stream>>>(d1gw, d1tw, d2gw, d2tw, OW);
  k_xcvt<<<2048, 256, 0, stream>>>(x, A0, A1);                         // A0=xB, A1=xS

  // ======== dynamic branch ========
  k_aggGconv<<<2048, 256, 0, stream>>>(A0, cntA, lvA, lvalA, w_d1g, B0, d1gb, sAv, part);  // B0=z1
  k_bnfin128<<<128, 256, 0, stream>>>(part, d1b1g, d1b1b, scA, shA, 1.f/131072.f, 2048);
  k_conv<128,16,3,0,1,0,1><<<1024, 256, 0, stream>>>(B0, w_d1t, C0, 4096, scA, shA, part); // C0=z2
  k_bnfin128<<<128, 256, 0, stream>>>(part, d1b2g, d1b2b, scB, shB, 1.f/131072.f, 1024);
  k_combineAggGconv<<<2048, 256, 0, stream>>>(C0, A0, cntA, lvA, lvalA, scB, shB, w_d2g,
                                              B0, C1, d2gb, sAv, part);  // B0=r2, C1=z3
  k_bnfin128<<<128, 256, 0, stream>>>(part, d2b1g, d2b1b, scC, shC, 1.f/131072.f, 2048);
  k_conv<128,16,3,0,1,0,1><<<1024, 256, 0, stream>>>(C1, w_d2t, B1, 4096, scC, shC, part); // B1=z4
  k_bnfin128<<<128, 256, 0, stream>>>(part, d2b2g, d2b2b, scD, shD, 1.f/131072.f, 1024);
  k_maxdyn<<<512, 256, 0, stream>>>(B1, B0, scD, shD, outp);

  // ======== static branch (xS=A1; B1 now holds static weights) ========
  k_cvt_stat<<<6272, 256, 0, stream>>>(s1pw, s1tw, s2pw, s2tw, SW);
  k_conv<128,0,1,0,0,0,0><<<1024, 256, 0, stream>>>(A1, w_s1p, C0, 256, nullptr, nullptr, part);
  k_bnfin128<<<128, 256, 0, stream>>>(part, s1pg, s1pb, scE, shE, 1.f/131072.f, 1024);
  k_conv<128,1,3,1,1,0,0><<<1024, 256, 0, stream>>>(C0, w_s1t, A0, 256, scE, shE, part);
  k_bnfin2048<<<2048, 64, 0, stream>>>(part, s1tg, s1tb, scF, shF, 1.f/8192.f);
  k_conv<128,0,1,0,1,1,0><<<1024, 256, 0, stream>>>(A0, w_s2p, C0, 256, scF, shF, part);
  k_bnfin128<<<128, 256, 0, stream>>>(part, s2pg, s2pb, scG, shG, 1.f/131072.f, 1024);
  k_conv<128,1,3,1,1,0,0><<<1024, 256, 0, stream>>>(C0, w_s2t, A0, 256, scG, shG, part);
  k_bnfin2048<<<2048, 64, 0, stream>>>(part, s2tg, s2tb, scH, shH, 1.f/8192.f);
  k_maxstat<<<512, 256, 0, stream>>>(A0, scH, shH, outp);
}

// Round 11
// 354.279 us; speedup vs baseline: 7.5204x; 1.0190x over previous
//
#include <hip/hip_runtime.h>

#define EPSBN 1e-5f

typedef __attribute__((ext_vector_type(8))) __bf16 bf16x8;
typedef __attribute__((ext_vector_type(4))) float f32x4;
typedef __attribute__((ext_vector_type(8))) unsigned short us8;

__device__ inline unsigned short f2bf(float f) {
  __bf16 h = (__bf16)f;
  return __builtin_bit_cast(unsigned short, h);
}
__device__ inline float bf2f(unsigned short u) {
  __bf16 h = __builtin_bit_cast(__bf16, u);
  return (float)h;
}

// ---------------- adjacency: A = adp(nv1,nv2); column sums sA; per-column sparse lists ----------------
__global__ void k_adj(const float* __restrict__ nv1, const float* __restrict__ nv2,
                      float* __restrict__ A, float* __restrict__ sA,
                      int* __restrict__ cntA, int* __restrict__ lvA, float* __restrict__ lvalA) {
  __shared__ float M[16][16];
  int tid = threadIdx.x;
  int i = tid >> 4, j = tid & 15;
  float acc = 0.f;
  #pragma unroll
  for (int k = 0; k < 64; ++k) acc += nv1[i*64+k] * nv2[k*16+j];
  M[i][j] = fmaxf(acc, 0.f);
  __syncthreads();
  if (tid < 16) {
    float m = -1e30f;
    for (int c = 0; c < 16; ++c) m = fmaxf(m, M[tid][c]);
    float e[16]; float s = 0.f;
    for (int c = 0; c < 16; ++c) { e[c] = expf(M[tid][c] - m); s += e[c]; }
    float inv = 1.f / s;
    float t1 = -1e30f, t2 = -1e30f;
    for (int c = 0; c < 16; ++c) {
      float a = e[c] * inv; e[c] = a;
      if (a > t1) { t2 = t1; t1 = a; }
      else if (a > t2) t2 = a;
    }
    for (int c = 0; c < 16; ++c) {
      bool keep = (e[c] > (1.0f/16.0f)) && (e[c] > t2);
      M[tid][c] = keep ? e[c] : 0.f;
    }
  }
  __syncthreads();
  A[tid] = M[tid>>4][tid&15];
  if (tid < 16) {           // tid = w (column)
    float s = 0.f;
    int cnt = 0;
    for (int v = 0; v < 16; ++v) {
      float a = M[v][tid];
      s += a;
      if (a != 0.f) { lvA[tid*16 + cnt] = v; lvalA[tid*16 + cnt] = a; ++cnt; }
    }
    sA[tid] = s;
    cntA[tid] = cnt;
  }
}

// ---------------- merged weight converts ----------------
__device__ inline void cvt_cw_seg(const float* w, unsigned short* o, int lidx) {
  o[lidx] = f2bf(w[lidx]);
}
__device__ inline void cvt_tw_seg(const float* w, unsigned short* o, int lidx) {
  int oo = lidx / 384;
  int r = lidx - oo*384;
  int tap = r >> 7, c = r & 127;
  o[lidx] = f2bf(w[(oo*128 + c)*3 + tap]);
}
__global__ __launch_bounds__(256) void k_cvt_dyn(
    const float* __restrict__ d1g, const float* __restrict__ d1t,
    const float* __restrict__ d2g, const float* __restrict__ d2t,
    unsigned short* __restrict__ O) {
  int b = blockIdx.x, tid = threadIdx.x;
  if (b < 64)        cvt_cw_seg(d1g, O,          b*256 + tid);
  else if (b < 256)  cvt_tw_seg(d1t, O + 16384, (b-64)*256 + tid);
  else if (b < 320)  cvt_cw_seg(d2g, O + 65536, (b-256)*256 + tid);
  else               cvt_tw_seg(d2t, O + 81920, (b-320)*256 + tid);
}
__global__ __launch_bounds__(256) void k_cvt_stat(
    const float* __restrict__ s1p, const float* __restrict__ s1t,
    const float* __restrict__ s2p, const float* __restrict__ s2t,
    unsigned short* __restrict__ S) {
  int b = blockIdx.x, tid = threadIdx.x;
  if (b < 64)        cvt_cw_seg(s1p, S,           b*256 + tid);
  else if (b < 3136) cvt_tw_seg(s1t, S + 16384,  (b-64)*256 + tid);
  else if (b < 3200) cvt_cw_seg(s2p, S + 802816, (b-3136)*256 + tid);
  else               cvt_tw_seg(s2t, S + 819200, (b-3200)*256 + tid);
}

// ---------------- x -> xB (pos-major bf16) + xS (static-layout bf16), one pass ----------------
__global__ __launch_bounds__(256) void k_xcvt(const float* __restrict__ x,
                                              unsigned short* __restrict__ xB,
                                              unsigned short* __restrict__ xS) {
  __shared__ float tl[64*128];
  int b = blockIdx.x; int n = b >> 6; int t0q = b & 63;
  int tid = threadIdx.x;
  const float* xb = x + (long)n*524288 + t0q*64;
  for (int idx = tid; idx < 2048; idx += 256) {
    int c = idx >> 4, q = idx & 15;
    float4 v = *(const float4*)(xb + (long)c*4096 + q*4);
    int cb = c >> 2, cl = c & 3;
    #pragma unroll
    for (int j = 0; j < 4; ++j)
      tl[(4*q+j)*128 + (((cb ^ q) & 31) << 2) + cl] = ((const float*)&v)[j];
  }
  __syncthreads();
  for (int idx = tid; idx < 1024; idx += 256) {
    int pos = idx >> 4, c8 = (idx & 15) << 3;
    int cb0 = c8 >> 2, cb1 = cb0 + 1, qp = pos >> 2;
    f32x4 v0 = *(const f32x4*)&tl[pos*128 + (((cb0 ^ qp) & 31) << 2)];
    f32x4 v1 = *(const f32x4*)&tl[pos*128 + (((cb1 ^ qp) & 31) << 2)];
    us8 pk;
    pk[0]=f2bf(v0.x); pk[1]=f2bf(v0.y); pk[2]=f2bf(v0.z); pk[3]=f2bf(v0.w);
    pk[4]=f2bf(v1.x); pk[5]=f2bf(v1.y); pk[6]=f2bf(v1.z); pk[7]=f2bf(v1.w);
    *(us8*)(xB + ((long)n*4096 + t0q*64 + pos)*128 + c8) = pk;
    int vv = pos & 15, tt = pos >> 4;
    *(us8*)(xS + ((long)(n*16+vv)*256 + t0q*4 + tt)*128 + c8) = pk;
  }
}

// ========== fused: sparse-agg(xB) via direct global gather -> MFMA gconv -> z1 + BN partials ==========
__global__ __launch_bounds__(256) void k_aggGconv(
    const unsigned short* __restrict__ xB,
    const int* __restrict__ cntA, const int* __restrict__ lvA, const float* __restrict__ lvalA,
    const unsigned short* __restrict__ Wb,
    unsigned short* __restrict__ out,
    const float* __restrict__ gb, const float* __restrict__ sAv,
    float* __restrict__ part)
{
  __shared__ __align__(16) unsigned short Th[64*128];   // agg bf16, conv-swizzled
  __shared__ int cntS[16];
  __shared__ int lvS[256];
  __shared__ float lvalS[256];
  int b = blockIdx.x; int n = b >> 6; int off = (b & 63) << 6;
  int tid = threadIdx.x;
  if (tid < 16) cntS[tid] = cntA[tid];
  lvS[tid] = lvA[tid];
  lvalS[tid] = lvalA[tid];
  __syncthreads();
  const unsigned short* xbase = xB + ((long)n*4096 + off)*128;
  for (int idx = tid; idx < 1024; idx += 256) {
    int pos = idx >> 4, c8 = (idx & 15) << 3;
    int tt = pos >> 4, w = pos & 15;
    float s[8];
    #pragma unroll
    for (int k = 0; k < 8; ++k) s[k] = 0.f;
    int cw = cntS[w];
    for (int j = 0; j < cw; ++j) {
      int p = tt*16 + lvS[w*16 + j];
      float a = lvalS[w*16 + j];
      us8 raw = *(const us8*)(xbase + (long)p*128 + c8);
      #pragma unroll
      for (int k = 0; k < 8; ++k) s[k] += a * bf2f(raw[k]);
    }
    us8 pk;
    #pragma unroll
    for (int k = 0; k < 8; ++k) pk[k] = f2bf(s[k]);
    int byteoff = (pos << 8) + (c8 << 1);
    byteoff ^= ((pos & 7) << 4);
    *(us8*)((char*)Th + byteoff) = pk;
  }
  __syncthreads();
  int wv = tid >> 6, lane = tid & 63, l15 = lane & 15, lhi = lane >> 4;
  int o0 = wv << 5;
  f32x4 zz = {0.f,0.f,0.f,0.f};
  f32x4 acc[2][4];
  #pragma unroll
  for (int i = 0; i < 2; ++i)
    #pragma unroll
    for (int q = 0; q < 4; ++q) acc[i][q] = zz;
  const unsigned short* wr0 = Wb + (long)(o0 + l15)*128 + lhi*8;
  const unsigned short* wr1 = wr0 + 16*128;
  #pragma unroll
  for (int kk = 0; kk < 4; ++kk) {
    int kc = kk*32 + lhi*8;
    bf16x8 a0 = *(const bf16x8*)(wr0 + kk*32);
    bf16x8 a1 = *(const bf16x8*)(wr1 + kk*32);
    #pragma unroll
    for (int pf = 0; pf < 4; ++pf) {
      int row = pf*16 + l15;
      int byteoff = (row << 8) + (kc << 1);
      byteoff ^= ((row & 7) << 4);
      bf16x8 bh = *(const bf16x8*)((const char*)Th + byteoff);
      acc[0][pf] = __builtin_amdgcn_mfma_f32_16x16x32_bf16(a0, bh, acc[0][pf], 0, 0, 0);
      acc[1][pf] = __builtin_amdgcn_mfma_f32_16x16x32_bf16(a1, bh, acc[1][pf], 0, 0, 0);
    }
  }
  float s1a[2][4], s2a[2][4];
  #pragma unroll
  for (int i = 0; i < 2; ++i)
    #pragma unroll
    for (int j = 0; j < 4; ++j) { s1a[i][j] = 0.f; s2a[i][j] = 0.f; }
  unsigned short* og = out + ((long)n*4096 + off)*128;
  #pragma unroll
  for (int of = 0; of < 2; ++of) {
    int oc = o0 + of*16 + lhi*4;
    #pragma unroll
    for (int pf = 0; pf < 4; ++pf) {
      int pos = pf*16 + l15;
      f32x4 r = acc[of][pf];
      float s = sAv[l15];
      r.x += gb[oc+0]*s; r.y += gb[oc+1]*s;
      r.z += gb[oc+2]*s; r.w += gb[oc+3]*s;
      ushort4 pk;
      pk.x = f2bf(r.x); pk.y = f2bf(r.y); pk.z = f2bf(r.z); pk.w = f2bf(r.w);
      *(ushort4*)(og + (long)pos*128 + oc) = pk;
      #pragma unroll
      for (int j = 0; j < 4; ++j) { s1a[of][j] += r[j]; s2a[of][j] += r[j]*r[j]; }
    }
  }
  #pragma unroll
  for (int of = 0; of < 2; ++of)
    #pragma unroll
    for (int j = 0; j < 4; ++j) {
      float a = s1a[of][j], b2 = s2a[of][j];
      #pragma unroll
      for (int m = 1; m < 16; m <<= 1) { a += __shfl_xor(a, m); b2 += __shfl_xor(b2, m); }
      s1a[of][j] = a; s2a[of][j] = b2;
    }
  if (l15 == 0) {
    #pragma unroll
    for (int of = 0; of < 2; ++of) {
      int ch = o0 + of*16 + lhi*4;
      f32x4 w1 = {s1a[of][0], s1a[of][1], s1a[of][2], s1a[of][3]};
      f32x4 w2 = {s2a[of][0], s2a[of][1], s2a[of][2], s2a[of][3]};
      *(f32x4*)&part[(long)blockIdx.x*256 + ch] = w1;
      *(f32x4*)&part[(long)blockIdx.x*256 + 128 + ch] = w2;
    }
  }
}

// ========== fused: r2=relu(bn(z2)+xB) elementwise -> bf16 (LDS+global); sparse-agg; gconv2 ==========
__global__ __launch_bounds__(256) void k_combineAggGconv(
    const unsigned short* __restrict__ z, const unsigned short* __restrict__ xB,
    const int* __restrict__ cntA, const int* __restrict__ lvA, const float* __restrict__ lvalA,
    const float* __restrict__ sc, const float* __restrict__ sh,
    const unsigned short* __restrict__ Wb,
    unsigned short* __restrict__ r2, unsigned short* __restrict__ out,
    const float* __restrict__ gb, const float* __restrict__ sAv,
    float* __restrict__ part)
{
  __shared__ __align__(16) unsigned short rl[64*128];   // r2 bf16, linear rows
  __shared__ __align__(16) unsigned short Th[64*128];   // agg bf16, conv-swizzled
  __shared__ int cntS[16];
  __shared__ int lvS[256];
  __shared__ float lvalS[256];
  int b = blockIdx.x;
  int tid = threadIdx.x;
  if (tid < 16) cntS[tid] = cntA[tid];
  lvS[tid] = lvA[tid];
  lvalS[tid] = lvalA[tid];
  long zbase = (long)b * 8192;
  // phase 1: elementwise r2 = relu(bn(z2) + x)
  for (int idx = tid; idx < 1024; idx += 256) {
    int pos = idx >> 4, c8 = (idx & 15) << 3;
    us8 zr = *(const us8*)(z  + zbase + (long)pos*128 + c8);
    us8 xr = *(const us8*)(xB + zbase + (long)pos*128 + c8);
    us8 pr;
    #pragma unroll
    for (int k = 0; k < 8; ++k) {
      int cc = c8 + k;
      float v = bf2f(zr[k]) * sc[cc] + sh[cc] + bf2f(xr[k]);
      pr[k] = f2bf(fmaxf(v, 0.f));
    }
    *(us8*)(rl + pos*128 + c8) = pr;
    *(us8*)(r2 + zbase + (long)pos*128 + c8) = pr;
  }
  __syncthreads();
  // phase 2: sparse agg from rl -> Th
  for (int idx = tid; idx < 1024; idx += 256) {
    int pos = idx >> 4, c8 = (idx & 15) << 3;
    int tt = pos >> 4, w = pos & 15;
    float s[8];
    #pragma unroll
    for (int k = 0; k < 8; ++k) s[k] = 0.f;
    int cw = cntS[w];
    for (int j = 0; j < cw; ++j) {
      int p = tt*16 + lvS[w*16 + j];
      float a = lvalS[w*16 + j];
      us8 raw = *(const us8*)(rl + p*128 + c8);
      #pragma unroll
      for (int k = 0; k < 8; ++k) s[k] += a * bf2f(raw[k]);
    }
    us8 pk;
    #pragma unroll
    for (int k = 0; k < 8; ++k) pk[k] = f2bf(s[k]);
    int byteoff = (pos << 8) + (c8 << 1);
    byteoff ^= ((pos & 7) << 4);
    *(us8*)((char*)Th + byteoff) = pk;
  }
  __syncthreads();
  // phase 3: gconv2 MFMA + epilogue
  int wv = tid >> 6, lane = tid & 63, l15 = lane & 15, lhi = lane >> 4;
  int o0 = wv << 5;
  f32x4 zz = {0.f,0.f,0.f,0.f};
  f32x4 acc[2][4];
  #pragma unroll
  for (int i = 0; i < 2; ++i)
    #pragma unroll
    for (int q = 0; q < 4; ++q) acc[i][q] = zz;
  const unsigned short* wr0 = Wb + (long)(o0 + l15)*128 + lhi*8;
  const unsigned short* wr1 = wr0 + 16*128;
  #pragma unroll
  for (int kk = 0; kk < 4; ++kk) {
    int kc = kk*32 + lhi*8;
    bf16x8 a0 = *(const bf16x8*)(wr0 + kk*32);
    bf16x8 a1 = *(const bf16x8*)(wr1 + kk*32);
    #pragma unroll
    for (int pf = 0; pf < 4; ++pf) {
      int row = pf*16 + l15;
      int byteoff = (row << 8) + (kc << 1);
      byteoff ^= ((row & 7) << 4);
      bf16x8 bh = *(const bf16x8*)((const char*)Th + byteoff);
      acc[0][pf] = __builtin_amdgcn_mfma_f32_16x16x32_bf16(a0, bh, acc[0][pf], 0, 0, 0);
      acc[1][pf] = __builtin_amdgcn_mfma_f32_16x16x32_bf16(a1, bh, acc[1][pf], 0, 0, 0);
    }
  }
  float s1a[2][4], s2a[2][4];
  #pragma unroll
  for (int i = 0; i < 2; ++i)
    #pragma unroll
    for (int j = 0; j < 4; ++j) { s1a[i][j] = 0.f; s2a[i][j] = 0.f; }
  unsigned short* og = out + zbase;
  #pragma unroll
  for (int of = 0; of < 2; ++of) {
    int oc = o0 + of*16 + lhi*4;
    #pragma unroll
    for (int pf = 0; pf < 4; ++pf) {
      int pos = pf*16 + l15;
      f32x4 r = acc[of][pf];
      float s = sAv[l15];
      r.x += gb[oc+0]*s; r.y += gb[oc+1]*s;
      r.z += gb[oc+2]*s; r.w += gb[oc+3]*s;
      ushort4 pk;
      pk.x = f2bf(r.x); pk.y = f2bf(r.y); pk.z = f2bf(r.z); pk.w = f2bf(r.w);
      *(ushort4*)(og + (long)pos*128 + oc) = pk;
      #pragma unroll
      for (int j = 0; j < 4; ++j) { s1a[of][j] += r[j]; s2a[of][j] += r[j]*r[j]; }
    }
  }
  #pragma unroll
  for (int of = 0; of < 2; ++of)
    #pragma unroll
    for (int j = 0; j < 4; ++j) {
      float a = s1a[of][j], b2 = s2a[of][j];
      #pragma unroll
      for (int m = 1; m < 16; m <<= 1) { a += __shfl_xor(a, m); b2 += __shfl_xor(b2, m); }
      s1a[of][j] = a; s2a[of][j] = b2;
    }
  if (l15 == 0) {
    #pragma unroll
    for (int of = 0; of < 2; ++of) {
      int ch = o0 + of*16 + lhi*4;
      f32x4 w1 = {s1a[of][0], s1a[of][1], s1a[of][2], s1a[of][3]};
      f32x4 w2 = {s2a[of][0], s2a[of][1], s2a[of][2], s2a[of][3]};
      *(f32x4*)&part[(long)blockIdx.x*256 + ch] = w1;
      *(f32x4*)&part[(long)blockIdx.x*256 + 128 + ch] = w2;
    }
  }
}

// ================= MFMA conv, bf16 in/out, coalesced stores via LDS round-trip =================
template<int POSB, int HALO, int TAPS, int GROUPED_W, int IN_BN, int GROUPED_BN, int RELU_IN>
__global__ __launch_bounds__(256) void k_conv(
    const unsigned short* __restrict__ in, const unsigned short* __restrict__ Wb,
    unsigned short* __restrict__ out, int L,
    const float* __restrict__ isc, const float* __restrict__ ish,
    float* __restrict__ part)
{
  constexpr int TW = POSB + 2*HALO;
  constexpr int PF = POSB / 16;
  constexpr int KT = TAPS*128;
  __shared__ __align__(16) unsigned short Th[TW*128];
  int tid = threadIdx.x;
  int bpg = L / POSB;
  int g = blockIdx.x / bpg;
  int pos0 = (blockIdx.x - g*bpg) * POSB;
  const unsigned short* ing = in + (long)g*L*128;

  int cbase = (IN_BN && GROUPED_BN) ? ((g & 15) << 7) : 0;
  for (int idx = tid; idx < TW*16; idx += 256) {
    int row = idx >> 4;
    int c8 = (idx & 15) << 3;
    int gp = pos0 + row - HALO;
    us8 h = (us8)0;
    if (gp >= 0 && gp < L) {
      us8 raw = *(const us8*)(ing + (long)gp*128 + c8);
      if (IN_BN) {
        #pragma unroll
        for (int j = 0; j < 8; ++j) {
          int ci = cbase + c8 + j;
          float v = bf2f(raw[j]) * isc[ci] + ish[ci];
          if (RELU_IN) v = fmaxf(v, 0.f);
          h[j] = f2bf(v);
        }
      } else {
        h = raw;
      }
    }
    int byteoff = (row << 8) + (c8 << 1);
    byteoff ^= ((row & 7) << 4);
    *(us8*)((char*)Th + byteoff) = h;
  }
  __syncthreads();

  int wv = tid >> 6, lane = tid & 63, l15 = lane & 15, lhi = lane >> 4;
  int o0 = wv << 5;

  f32x4 zz = {0.f,0.f,0.f,0.f};
  f32x4 acc[2][PF];
  #pragma unroll
  for (int i = 0; i < 2; ++i)
    #pragma unroll
    for (int q = 0; q < PF; ++q) acc[i][q] = zz;

  const unsigned short* Wg = Wb + (GROUPED_W ? (long)(g & 15)*128*KT : 0);
  const unsigned short* wr0 = Wg + (long)(o0 + l15)*KT + lhi*8;
  const unsigned short* wr1 = wr0 + 16*KT;

  #pragma unroll
  for (int tap = 0; tap < TAPS; ++tap) {
    #pragma unroll
    for (int kk = 0; kk < 4; ++kk) {
      int kc = kk*32 + lhi*8;
      bf16x8 a0 = *(const bf16x8*)(wr0 + tap*128 + kk*32);
      bf16x8 a1 = *(const bf16x8*)(wr1 + tap*128 + kk*32);
      #pragma unroll
      for (int pf = 0; pf < PF; ++pf) {
        int row = pf*16 + l15 + tap*HALO;
        int byteoff = (row << 8) + (kc << 1);
        byteoff ^= ((row & 7) << 4);
        bf16x8 bh = *(const bf16x8*)((const char*)Th + byteoff);
        acc[0][pf] = __builtin_amdgcn_mfma_f32_16x16x32_bf16(a0, bh, acc[0][pf], 0, 0, 0);
        acc[1][pf] = __builtin_amdgcn_mfma_f32_16x16x32_bf16(a1, bh, acc[1][pf], 0, 0, 0);
      }
    }
  }

  // BN partial sums from accumulators (fp32, pre-rounding), direct to part
  float s1a[2][4], s2a[2][4];
  #pragma unroll
  for (int i = 0; i < 2; ++i)
    #pragma unroll
    for (int j = 0; j < 4; ++j) { s1a[i][j] = 0.f; s2a[i][j] = 0.f; }
  #pragma unroll
  for (int of = 0; of < 2; ++of)
    #pragma unroll
    for (int pf = 0; pf < PF; ++pf) {
      f32x4 r = acc[of][pf];
      #pragma unroll
      for (int j = 0; j < 4; ++j) { s1a[of][j] += r[j]; s2a[of][j] += r[j]*r[j]; }
    }
  #pragma unroll
  for (int of = 0; of < 2; ++of)
    #pragma unroll
    for (int j = 0; j < 4; ++j) {
      float a = s1a[of][j], b2 = s2a[of][j];
      #pragma unroll
      for (int m = 1; m < 16; m <<= 1) { a += __shfl_xor(a, m); b2 += __shfl_xor(b2, m); }
      s1a[of][j] = a; s2a[of][j] = b2;
    }
  if (l15 == 0) {
    #pragma unroll
    for (int of = 0; of < 2; ++of) {
      int ch = o0 + of*16 + lhi*4;
      f32x4 w1 = {s1a[of][0], s1a[of][1], s1a[of][2], s1a[of][3]};
      f32x4 w2 = {s2a[of][0], s2a[of][1], s2a[of][2], s2a[of][3]};
      *(f32x4*)&part[(long)blockIdx.x*256 + ch] = w1;
      *(f32x4*)&part[(long)blockIdx.x*256 + 128 + ch] = w2;
    }
  }

  // write output tile into Th (bf16, swizzled), then coalesced global store
  __syncthreads();                    // all Th B-reads complete
  #pragma unroll
  for (int of = 0; of < 2; ++of) {
    int oc = o0 + of*16 + lhi*4;
    #pragma unroll
    for (int pf = 0; pf < PF; ++pf) {
      int pos = pf*16 + l15;
      f32x4 r = acc[of][pf];
      ushort4 pk;
      pk.x = f2bf(r.x); pk.y = f2bf(r.y); pk.z = f2bf(r.z); pk.w = f2bf(r.w);
      int byteoff = (pos << 8) + (oc << 1);
      byteoff ^= ((pos & 7) << 4);
      *(ushort4*)((char*)Th + byteoff) = pk;
    }
  }
  __syncthreads();
  unsigned short* og = out + ((long)g*L + pos0)*128;
  for (int idx = tid; idx < POSB*16; idx += 256) {
    int row = idx >> 4, c8 = (idx & 15) << 3;
    int byteoff = (row << 8) + (c8 << 1);
    byteoff ^= ((row & 7) << 4);
    us8 v = *(const us8*)((const char*)Th + byteoff);
    *(us8*)(og + (long)row*128 + c8) = v;
  }
}

// ---------------- BN finalize: 128 channels, nblk block-partials ----------------
__global__ __launch_bounds__(256) void k_bnfin128(const float* __restrict__ part,
                           const float* __restrict__ gamma, const float* __restrict__ beta,
                           float* __restrict__ sc, float* __restrict__ sh,
                           float invN, int nblk) {
  int c = blockIdx.x, tid = threadIdx.x;
  float s1 = 0.f, s2 = 0.f;
  for (int b = tid; b < nblk; b += 256) {
    s1 += part[b*256 + c];
    s2 += part[b*256 + 128 + c];
  }
  __shared__ float l1[256], l2[256];
  l1[tid] = s1; l2[tid] = s2;
  __syncthreads();
  for (int st = 128; st > 0; st >>= 1) {
    if (tid < st) { l1[tid] += l1[tid+st]; l2[tid] += l2[tid+st]; }
    __syncthreads();
  }
  if (tid == 0) {
    float mean = l1[0]*invN;
    float var  = l2[0]*invN - mean*mean;
    float s = gamma[c] * rsqrtf(var + EPSBN);
    sc[c] = s;
    sh[c] = beta[c] - mean*s;
  }
}

// ---------------- BN finalize: 2048 (v,c) channels; 2 blocks per g, g=n*16+v ----------------
__global__ void k_bnfin2048(const float* __restrict__ part,
                            const float* __restrict__ gamma, const float* __restrict__ beta,
                            float* __restrict__ sc, float* __restrict__ sh, float invN) {
  int ch = blockIdx.x; int v = ch >> 7, c = ch & 127;
  int lane = threadIdx.x;          // 64 = 32 n x 2 bp
  int n = lane >> 1, bp = lane & 1;
  int blk = ((n*16 + v) << 1) + bp;
  float s1 = part[blk*256 + c];
  float s2 = part[blk*256 + 128 + c];
  for (int m = 32; m > 0; m >>= 1) { s1 += __shfl_down(s1, m); s2 += __shfl_down(s2, m); }
  if (lane == 0) {
    float mean = s1*invN;
    float var  = s2*invN - mean*mean;
    float s = gamma[ch] * rsqrtf(var + EPSBN);
    sc[ch] = s;
    sh[ch] = beta[ch] - mean*s;
  }
}

// ---------------- dynamic tail: out[n,c,v] = max_t relu(bn(z)+r2), bf16 inputs ----------------
__global__ __launch_bounds__(256) void k_maxdyn(
    const unsigned short* __restrict__ z, const unsigned short* __restrict__ res,
    const float* __restrict__ sc, const float* __restrict__ sh,
    float* __restrict__ outp)
{
  int b = blockIdx.x; int n = b >> 4, v = b & 15;
  int tid = threadIdx.x; int c = tid & 127, h = tid >> 7;
  const unsigned short* zb = z   + ((long)n*4096 + v)*128 + c;
  const unsigned short* rb = res + ((long)n*4096 + v)*128 + c;
  float s = sc[c], bb = sh[c];
  float m = 0.f;
  for (int t = h; t < 256; t += 2) {
    float val = bf2f(zb[(long)t*2048]) * s + bb + bf2f(rb[(long)t*2048]);
    m = fmaxf(m, val);
  }
  __shared__ float red[256];
  red[tid] = m;
  __syncthreads();
  if (tid < 128)
    outp[(long)n*4096 + c*32 + v] = fmaxf(fmaxf(red[tid], red[tid+128]), 0.f);
}

// ---------------- static tail: out[n,c,16+v] = max_s bn(z[(n,v)][s][c]), bf16 ----------------
__global__ __launch_bounds__(256) void k_maxstat(
    const unsigned short* __restrict__ z,
    const float* __restrict__ sc, const float* __restrict__ sh,
    float* __restrict__ outp)
{
  int b = blockIdx.x; int n = b >> 4, v = b & 15;
  int tid = threadIdx.x; int c = tid & 127, h = tid >> 7;
  const unsigned short* zb = z + (long)b*256*128 + c;
  float s = sc[v*128 + c], bb = sh[v*128 + c];
  float m = -1e30f;
  for (int t = h; t < 256; t += 2)
    m = fmaxf(m, bf2f(zb[t*128]) * s + bb);
  __shared__ float red[256];
  red[tid] = m;
  __syncthreads();
  if (tid < 128)
    outp[(long)n*4096 + c*32 + 16 + v] = fmaxf(red[tid], red[tid+128]);
}

extern "C" void kernel_launch(void* const* d_in, const int* in_sizes, int n_in,
                              void* d_out, int out_size, void* d_ws, size_t ws_size,
                              hipStream_t stream) {
  (void)in_sizes; (void)n_in; (void)out_size; (void)ws_size;
  const float* x     = (const float*)d_in[0];
  const float* nv1   = (const float*)d_in[1];
  const float* nv2   = (const float*)d_in[2];
  const float* d1gw  = (const float*)d_in[3];
  const float* d1gb  = (const float*)d_in[4];
  const float* d1b1g = (const float*)d_in[5];
  const float* d1b1b = (const float*)d_in[6];
  const float* d1tw  = (const float*)d_in[7];
  const float* d1b2g = (const float*)d_in[9];
  const float* d1b2b = (const float*)d_in[10];
  const float* d2gw  = (const float*)d_in[11];
  const float* d2gb  = (const float*)d_in[12];
  const float* d2b1g = (const float*)d_in[13];
  const float* d2b1b = (const float*)d_in[14];
  const float* d2tw  = (const float*)d_in[15];
  const float* d2b2g = (const float*)d_in[17];
  const float* d2b2b = (const float*)d_in[18];
  const float* s1pw  = (const float*)d_in[19];
  const float* s1pg  = (const float*)d_in[20];
  const float* s1pb  = (const float*)d_in[21];
  const float* s1tw  = (const float*)d_in[22];
  const float* s1tg  = (const float*)d_in[23];
  const float* s1tb  = (const float*)d_in[24];
  const float* s2pw  = (const float*)d_in[25];
  const float* s2pg  = (const float*)d_in[26];
  const float* s2pb  = (const float*)d_in[27];
  const float* s2tw  = (const float*)d_in[28];
  const float* s2tg  = (const float*)d_in[29];
  const float* s2tb  = (const float*)d_in[30];

  float* W = (float*)d_ws;
  float* Am  = W;            // 256
  float* sAv = W + 256;      // 16
  float* scA = W + 512;  float* shA = W + 640;
  float* scB = W + 768;  float* shB = W + 896;
  float* scC = W + 1024; float* shC = W + 1152;
  float* scD = W + 1280; float* shD = W + 1408;
  float* scE = W + 1536; float* shE = W + 1664;
  float* scG = W + 1792; float* shG = W + 1920;
  float* scF = W + 2048; float* shF = W + 4096;   // 2048 each
  float* scH = W + 6144; float* shH = W + 8192;
  int*   cntA  = (int*)(W + 10240);               // 16
  int*   lvA   = (int*)(W + 10496);               // 256
  float* lvalA = W + 10752;                       // 256
  float* A = W + 16384;
  float* B = A + 16777216;
  float* C = B + 16777216;
  float* part = C + 16777216;                     // up to 2048*256 floats
  float* outp = (float*)d_out;

  // six 32MB bf16 half-regions
  unsigned short* A0 = (unsigned short*)A;
  unsigned short* A1 = (unsigned short*)(A + 8388608);
  unsigned short* B0 = (unsigned short*)B;
  unsigned short* B1 = (unsigned short*)(B + 8388608);
  unsigned short* C0 = (unsigned short*)C;
  unsigned short* C1 = (unsigned short*)(C + 8388608);

  // dynamic weights staged in d_out scratch (fully overwritten by maxdyn/maxstat later)
  unsigned short* OW = (unsigned short*)d_out;
  unsigned short* w_d1g = OW;               // 16384
  unsigned short* w_d1t = OW + 16384;       // 49152
  unsigned short* w_d2g = OW + 65536;       // 16384
  unsigned short* w_d2t = OW + 81920;       // 49152 -> end 131072 us (within out buffer)
  // static weights staged in B1 (dead after maxdyn)
  unsigned short* SW    = B1;
  unsigned short* w_s1p = SW;               // 16384
  unsigned short* w_s1t = SW + 16384;       // 786432
  unsigned short* w_s2p = SW + 802816;      // 16384
  unsigned short* w_s2t = SW + 819200;      // 786432 -> end 1605632 us (3.2 MB)

  // ---- setup ----
  k_adj<<<1, 256, 0, stream>>>(nv1, nv2, Am, sAv, cntA, lvA, lvalA);
  k_cvt_dyn<<<512, 256, 0, stream>>>(d1gw, d1tw, d2gw, d2tw, OW);
  k_xcvt<<<2048, 256, 0, stream>>>(x, A0, A1);                         // A0=xB, A1=xS

  // ======== dynamic branch ========
  k_aggGconv<<<2048, 256, 0, stream>>>(A0, cntA, lvA, lvalA, w_d1g, B0, d1gb, sAv, part);  // B0=z1
  k_bnfin128<<<128, 256, 0, stream>>>(part, d1b1g, d1b1b, scA, shA, 1.f/131072.f, 2048);
  k_conv<128,16,3,0,1,0,1><<<1024, 256, 0, stream>>>(B0, w_d1t, C0, 4096, scA, shA, part); // C0=z2
  k_bnfin128<<<128, 256, 0, stream>>>(part, d1b2g, d1b2b, scB, shB, 1.f/131072.f, 1024);
  k_combineAggGconv<<<2048, 256, 0, stream>>>(C0, A0, cntA, lvA, lvalA, scB, shB, w_d2g,
                                              B0, C1, d2gb, sAv, part);  // B0=r2, C1=z3
  k_bnfin128<<<128, 256, 0, stream>>>(part, d2b1g, d2b1b, scC, shC, 1.f/131072.f, 2048);
  k_conv<128,16,3,0,1,0,1><<<1024, 256, 0, stream>>>(C1, w_d2t, B1, 4096, scC, shC, part); // B1=z4
  k_bnfin128<<<128, 256, 0, stream>>>(part, d2b2g, d2b2b, scD, shD, 1.f/131072.f, 1024);
  k_maxdyn<<<512, 256, 0, stream>>>(B1, B0, scD, shD, outp);

  // ======== static branch (xS=A1; B1 now holds static weights) ========
  k_cvt_stat<<<6272, 256, 0, stream>>>(s1pw, s1tw, s2pw, s2tw, SW);
  k_conv<128,0,1,0,0,0,0><<<1024, 256, 0, stream>>>(A1, w_s1p, C0, 256, nullptr, nullptr, part);
  k_bnfin128<<<128, 256, 0, stream>>>(part, s1pg, s1pb, scE, shE, 1.f/131072.f, 1024);
  k_conv<128,1,3,1,1,0,0><<<1024, 256, 0, stream>>>(C0, w_s1t, A0, 256, scE, shE, part);
  k_bnfin2048<<<2048, 64, 0, stream>>>(part, s1tg, s1tb, scF, shF, 1.f/8192.f);
  k_conv<128,0,1,0,1,1,0><<<1024, 256, 0, stream>>>(A0, w_s2p, C0, 256, scF, shF, part);
  k_bnfin128<<<128, 256, 0, stream>>>(part, s2pg, s2pb, scG, shG, 1.f/131072.f, 1024);
  k_conv<128,1,3,1,1,0,0><<<1024, 256, 0, stream>>>(C0, w_s2t, A0, 256, scG, shG, part);
  k_bnfin2048<<<2048, 64, 0, stream>>>(part, s2tg, s2tb, scH, shH, 1.f/8192.f);
  k_maxstat<<<512, 256, 0, stream>>>(A0, scH, shH, outp);
}